// Round 4
// baseline (1046.808 us; speedup 1.0000x reference)
//
#include <hip/hip_runtime.h>

#define B_SZ 16
#define L_SZ 2048
#define DIN 64
#define H_SZ 256
#define NH 32
#define NL 4
#define TC 64
#define NTC 32

typedef __attribute__((ext_vector_type(8))) __bf16 bf16x8;
typedef __attribute__((ext_vector_type(4))) float f32x4;

__device__ __forceinline__ unsigned short f2b(float f) {
  unsigned int u = __builtin_bit_cast(unsigned int, f);
  unsigned int r = u + 0x7fffu + ((u >> 16) & 1u);  // RNE (no NaN inputs here)
  return (unsigned short)(r >> 16);
}
__device__ __forceinline__ float b2f(unsigned short u) {
  unsigned int v = ((unsigned int)u) << 16;
  return __builtin_bit_cast(float, v);
}

// ---------------- encoder: h[b][hh][l] = x[b][l][:] @ enc_w[:,hh] + enc_b ----------------
__global__ void k_encoder(const float* __restrict__ x, const float* __restrict__ w,
                          const float* __restrict__ bias, float* __restrict__ hbuf) {
  __shared__ float wlds[DIN * H_SZ];  // 64 KB
  int tid = threadIdx.x;
  for (int i = tid; i < DIN * H_SZ; i += 256) wlds[i] = w[i];
  int blk = blockIdx.x;            // 512 blocks: b(16) x q(4) x ltile(8)
  int b = blk >> 5;
  int q = (blk >> 3) & 3;
  int l = ((blk & 7) << 8) + tid;
  float xr[DIN];
  const float4* xp = (const float4*)(x + (size_t)(b * L_SZ + l) * DIN);
#pragma unroll
  for (int d4 = 0; d4 < 16; ++d4) {
    float4 v = xp[d4];
    xr[d4 * 4 + 0] = v.x; xr[d4 * 4 + 1] = v.y; xr[d4 * 4 + 2] = v.z; xr[d4 * 4 + 3] = v.w;
  }
  __syncthreads();
  for (int i = 0; i < 64; ++i) {
    int hh = (q << 6) + i;
    float acc = bias[hh];
#pragma unroll
    for (int d = 0; d < DIN; ++d) acc = fmaf(xr[d], wlds[d * H_SZ + hh], acc);
    hbuf[(b * H_SZ + hh) * L_SZ + l] = acc;
  }
}

// ---------------- convert w_out to bf16 ----------------
__global__ void k_cvtw(const float* __restrict__ w, unsigned short* __restrict__ wbf, int n) {
  int i = blockIdx.x * 256 + threadIdx.x;
  if (i < n) wbf[i] = f2b(w[i]);
}

// ---------------- precompute per-state params: lr, li, c2r, c2i, lTr, lTi ----------------
__global__ void k_params(const float* __restrict__ log_dt, const float* __restrict__ log_A_real,
                         const float* __restrict__ A_imag, const float* __restrict__ C_re,
                         const float* __restrict__ C_im, float* __restrict__ par) {
  int id = blockIdx.x * 256 + threadIdx.x;  // i*8192 + h*32 + n
  if (id >= NL * H_SZ * NH) return;
  int i = id >> 13;
  int hn = id & 8191;
  int h = hn >> 5;
  float dt = expf(log_dt[i * H_SZ + h]);
  float Ar = -expf(log_A_real[(size_t)i * H_SZ * NH + hn]);
  float Ai = A_imag[(size_t)i * H_SZ * NH + hn];
  float dr = dt * Ar, di = dt * Ai;
  float e = expf(dr), sn, cs;
  sincosf(di, &sn, &cs);
  float lr = e * cs, li = e * sn;
  float eT = expf((float)TC * dr), snT, csT;
  sincosf((float)TC * di, &snT, &csT);
  float Cr = C_re[(size_t)i * H_SZ * NH + hn], Ci = C_im[(size_t)i * H_SZ * NH + hn];
  float wr = lr - 1.f, wi = li;
  float pr = Cr * wr - Ci * wi;
  float pi = Cr * wi + Ci * wr;
  float inv = 2.f / fmaf(Ar, Ar, Ai * Ai);
  float4* p = (float4*)(par + (size_t)id * 8);
  p[0] = make_float4(lr, li, (pr * Ar + pi * Ai) * inv, (pi * Ar - pr * Ai) * inv);
  p[1] = make_float4(eT * csT, eT * snT, 0.f, 0.f);
}

// ---------------- local chunk scan (state only), layer given by par ----------------
__global__ void k_scan_local(const float* __restrict__ hbuf, float4* __restrict__ sF,
                             const float* __restrict__ par) {
  int gt = blockIdx.x * 256 + threadIdx.x;  // b(4b) c(5b) h(8b) ng(2b)
  int ng = gt & 3;
  int h = (gt >> 2) & 255;
  int c = (gt >> 10) & 31;
  int b = gt >> 15;
  float lr[8], li[8], sre[8], sim[8];
  const float4* pp = (const float4*)(par + (size_t)(h * NH + ng * 8) * 8);
#pragma unroll
  for (int k = 0; k < 8; ++k) {
    float4 p0 = pp[k * 2];
    lr[k] = p0.x; li[k] = p0.y;
    sre[k] = 0.f; sim[k] = 0.f;
  }
  const float* xp = hbuf + (b * H_SZ + h) * L_SZ + c * TC;
  float4 xv = *(const float4*)xp;
  for (int j4 = 0; j4 < TC; j4 += 4) {
    float4 xn = xv;
    if (j4 + 4 < TC) xn = *(const float4*)(xp + j4 + 4);
    float xe[4] = {xv.x, xv.y, xv.z, xv.w};
#pragma unroll
    for (int e = 0; e < 4; ++e) {
      float xj = xe[e];
#pragma unroll
      for (int k = 0; k < 8; ++k) {
        float nr = fmaf(lr[k], sre[k], xj);
        nr = fmaf(-li[k], sim[k], nr);
        float ni = lr[k] * sim[k];
        ni = fmaf(li[k], sre[k], ni);
        sre[k] = nr; sim[k] = ni;
      }
    }
    xv = xn;
  }
  float4* out = sF + (((size_t)((b << 5) + c) * H_SZ + h) * 4 + ng) * 4;
#pragma unroll
  for (int q = 0; q < 4; ++q)
    out[q] = make_float4(sre[2 * q], sim[2 * q], sre[2 * q + 1], sim[2 * q + 1]);
}

// ---------------- fused per-layer kernel (kernel-boundary sync only, no atomics) ----------------
__launch_bounds__(1024, 8)
__global__ void k_layer(float* __restrict__ hbuf, const float4* __restrict__ sFin,
                        float4* __restrict__ sFout,
                        const float* __restrict__ par, const float* __restrict__ parN,
                        const float* __restrict__ D_skip,
                        const unsigned short* __restrict__ wbf,
                        const float* __restrict__ b_out,
                        const float* __restrict__ ln_g, const float* __restrict__ ln_b,
                        float* __restrict__ pooledPart, int last) {
  __shared__ __align__(16) unsigned short yt[TC][H_SZ + 8];  // 33.8 KB
  __shared__ float part[TC][16][2];
  __shared__ float stats[TC][2];
  int tid = threadIdx.x;
  int b = blockIdx.x >> 5;
  int c = blockIdx.x & 31;
  int l0 = c << 6;

  int h = tid >> 2, ng = tid & 3;
  const float4* pp = (const float4*)(par + (size_t)(h * NH + ng * 8) * 8);
  // ---- lookback: combine predecessor chunk-finals (written by PREVIOUS kernel) ----
  float cre[8], cim[8];
#pragma unroll
  for (int k = 0; k < 8; ++k) { cre[k] = 0.f; cim[k] = 0.f; }
  if (c > 0) {
    float lTr[8], lTi[8];
#pragma unroll
    for (int k = 0; k < 8; ++k) {
      float4 p1 = pp[k * 2 + 1];
      lTr[k] = p1.x; lTi[k] = p1.y;
    }
    for (int cc = 0; cc < c; ++cc) {
      const float4* fp = sFin + (((size_t)((b << 5) + cc) * H_SZ + h) * 4 + ng) * 4;
#pragma unroll
      for (int q = 0; q < 4; ++q) {
        float4 f = fp[q];
        const int k0 = 2 * q, k1 = 2 * q + 1;
        float nr0 = fmaf(lTr[k0], cre[k0], f.x); nr0 = fmaf(-lTi[k0], cim[k0], nr0);
        float ni0 = fmaf(lTr[k0], cim[k0], f.y); ni0 = fmaf(lTi[k0], cre[k0], ni0);
        cre[k0] = nr0; cim[k0] = ni0;
        float nr1 = fmaf(lTr[k1], cre[k1], f.z); nr1 = fmaf(-lTi[k1], cim[k1], nr1);
        float ni1 = fmaf(lTr[k1], cim[k1], f.w); ni1 = fmaf(lTi[k1], cre[k1], ni1);
        cre[k1] = nr1; cim[k1] = ni1;
      }
    }
  }
  // ---- pass B: full recurrence from carry; y + D*x -> LDS (bf16) ----
  {
    float lr[8], li[8], c2r[8], c2i[8], sre[8], sim[8];
#pragma unroll
    for (int k = 0; k < 8; ++k) {
      float4 p0 = pp[k * 2];
      lr[k] = p0.x; li[k] = p0.y; c2r[k] = p0.z; c2i[k] = p0.w;
      sre[k] = cre[k]; sim[k] = cim[k];
    }
    float Dh = D_skip[h];
    const float* xp = hbuf + (b * H_SZ + h) * L_SZ + l0;
    float4 xv = *(const float4*)xp;
    for (int j4 = 0; j4 < TC; j4 += 4) {
      float4 xn = xv;
      if (j4 + 4 < TC) xn = *(const float4*)(xp + j4 + 4);
      float xe[4] = {xv.x, xv.y, xv.z, xv.w};
#pragma unroll
      for (int e = 0; e < 4; ++e) {
        float xj = xe[e];
        float yp0 = 0.f, yp1 = 0.f;
#pragma unroll
        for (int k = 0; k < 8; ++k) {
          float nr = fmaf(lr[k], sre[k], xj);
          nr = fmaf(-li[k], sim[k], nr);
          float ni = lr[k] * sim[k];
          ni = fmaf(li[k], sre[k], ni);
          sre[k] = nr; sim[k] = ni;
          if (k & 1) {
            yp1 = fmaf(c2r[k], nr, yp1);
            yp1 = fmaf(-c2i[k], ni, yp1);
          } else {
            yp0 = fmaf(c2r[k], nr, yp0);
            yp0 = fmaf(-c2i[k], ni, yp0);
          }
        }
        float yp = yp0 + yp1;
        yp += __shfl_xor(yp, 1);
        yp += __shfl_xor(yp, 2);
        if (ng == 0) yt[j4 + e][h] = f2b(fmaf(Dh, xj, yp));
      }
      xv = xn;
    }
  }
  __syncthreads();
  // ---- phase 2: exact GELU in place (packed pairs) ----
  for (int it = 0; it < 8; ++it) {
    int id = it * 1024 + tid;
    int jr = id >> 7, hp = id & 127;
    unsigned int u = *(unsigned int*)&yt[jr][hp * 2];
    float v0 = b2f((unsigned short)(u & 0xffff));
    float v1 = b2f((unsigned short)(u >> 16));
    v0 = 0.5f * v0 * (1.f + erff(v0 * 0.70710678118654752f));
    v1 = 0.5f * v1 * (1.f + erff(v1 * 0.70710678118654752f));
    *(unsigned int*)&yt[jr][hp * 2] = (unsigned int)f2b(v0) | ((unsigned int)f2b(v1) << 16);
  }
  __syncthreads();
  // ---- phase 3: 1x1 conv (512x256 @ 256x64) via MFMA + GLU; z -> LDS ----
  {
    int w = tid >> 6, lane = tid & 63;
    int lrow = lane & 15, lk8 = (lane >> 4) << 3;
    f32x4 accA[4], accG[4];
    f32x4 zed = {0.f, 0.f, 0.f, 0.f};
#pragma unroll
    for (int jt = 0; jt < 4; ++jt) { accA[jt] = zed; accG[jt] = zed; }
    const unsigned short* wA = wbf + ((w << 4) + lrow) * H_SZ;
    const unsigned short* wG = wA + 256 * H_SZ;
#pragma unroll
    for (int k0 = 0; k0 < H_SZ; k0 += 32) {
      bf16x8 a0 = *(const bf16x8*)(wA + k0 + lk8);
      bf16x8 a1 = *(const bf16x8*)(wG + k0 + lk8);
#pragma unroll
      for (int jt = 0; jt < 4; ++jt) {
        bf16x8 bb = *(const bf16x8*)(&yt[(jt << 4) + lrow][k0 + lk8]);
        accA[jt] = __builtin_amdgcn_mfma_f32_16x16x32_bf16(a0, bb, accA[jt], 0, 0, 0);
        accG[jt] = __builtin_amdgcn_mfma_f32_16x16x32_bf16(a1, bb, accG[jt], 0, 0, 0);
      }
    }
    __syncthreads();  // all y reads done before overwrite with z
    int rbase = (lane >> 4) << 2;
    float bA[4], bG[4];
#pragma unroll
    for (int r = 0; r < 4; ++r) {
      bA[r] = b_out[(w << 4) + rbase + r];
      bG[r] = b_out[256 + (w << 4) + rbase + r];
    }
#pragma unroll
    for (int jt = 0; jt < 4; ++jt) {
#pragma unroll
      for (int r = 0; r < 4; ++r) {
        float a = accA[jt][r] + bA[r];
        float g = accG[jt][r] + bG[r];
        float z = a / (1.f + expf(-g));
        yt[(jt << 4) + lrow][(w << 4) + rbase + r] = f2b(z);
      }
    }
  }
  __syncthreads();
  // ---- phase 4: LN stats over H; v = z + residual (L2-hot load) ----
  int j = tid & 63, hg = tid >> 6;  // 16 groups of 16 h
  float vreg[16];
  {
    const float* xc = hbuf + (b * H_SZ + (hg << 4)) * L_SZ + l0 + j;
    float s = 0.f, sq = 0.f;
#pragma unroll
    for (int k = 0; k < 16; ++k) {
      float v = b2f(yt[j][(hg << 4) + k]) + xc[(size_t)k * L_SZ];
      vreg[k] = v;
      s += v; sq = fmaf(v, v, sq);
    }
    part[j][hg][0] = s; part[j][hg][1] = sq;
  }
  __syncthreads();
  if (tid < TC) {
    float s = 0.f, sq = 0.f;
#pragma unroll
    for (int g = 0; g < 16; ++g) { s += part[tid][g][0]; sq += part[tid][g][1]; }
    float mu = s * (1.f / 256.f);
    float var = sq * (1.f / 256.f) - mu * mu;
    stats[tid][0] = mu;
    stats[tid][1] = rsqrtf(var + 1e-5f);
  }
  __syncthreads();
  // ---- phase 5: normalized residual; write hbuf OR pool partials (last) ----
  {
    float mu = stats[j][0], rs = stats[j][1];
    if (!last) {
      float* xo = hbuf + (b * H_SZ + (hg << 4)) * L_SZ + l0 + j;
#pragma unroll
      for (int k = 0; k < 16; ++k) {
        int hh = (hg << 4) + k;
        xo[(size_t)k * L_SZ] = (vreg[k] - mu) * rs * ln_g[hh] + ln_b[hh];
      }
    } else {
#pragma unroll
      for (int k = 0; k < 16; ++k) {
        int hh = (hg << 4) + k;
        yt[j][hh] = f2b((vreg[k] - mu) * rs * ln_g[hh] + ln_b[hh]);
      }
      __syncthreads();
      if (tid < H_SZ) {
        float s = 0.f;
        for (int jj = 0; jj < TC; ++jj) s += b2f(yt[jj][tid]);
        pooledPart[(((b << 5) + c) << 8) + tid] = s;
      }
    }
  }
  // ---- epilogue: next layer's local chunk scan from just-written tile (L1/L2-hot) ----
  if (sFout) {
    __syncthreads();  // phase-5 global writes visible within block
    const float4* pp2 = (const float4*)(parN + (size_t)(h * NH + ng * 8) * 8);
    float lr[8], li[8], sre[8], sim[8];
#pragma unroll
    for (int k = 0; k < 8; ++k) {
      float4 p0 = pp2[k * 2];
      lr[k] = p0.x; li[k] = p0.y;
      sre[k] = 0.f; sim[k] = 0.f;
    }
    const float* xp = hbuf + (b * H_SZ + h) * L_SZ + l0;
    float4 xv = *(const float4*)xp;
    for (int j4 = 0; j4 < TC; j4 += 4) {
      float4 xn = xv;
      if (j4 + 4 < TC) xn = *(const float4*)(xp + j4 + 4);
      float xe[4] = {xv.x, xv.y, xv.z, xv.w};
#pragma unroll
      for (int e = 0; e < 4; ++e) {
        float xj = xe[e];
#pragma unroll
        for (int k = 0; k < 8; ++k) {
          float nr = fmaf(lr[k], sre[k], xj);
          nr = fmaf(-li[k], sim[k], nr);
          float ni = lr[k] * sim[k];
          ni = fmaf(li[k], sre[k], ni);
          sre[k] = nr; sim[k] = ni;
        }
      }
      xv = xn;
    }
    float4* out = sFout + (((size_t)((b << 5) + c) * H_SZ + h) * 4 + ng) * 4;
#pragma unroll
    for (int q = 0; q < 4; ++q)
      out[q] = make_float4(sre[2 * q], sim[2 * q], sre[2 * q + 1], sim[2 * q + 1]);
  }
}

// ---------------- decoder MLP (single block) with pooling preamble ----------------
__global__ void k_decoder(const float* __restrict__ pooledPart,
                          const float* __restrict__ w1, const float* __restrict__ b1,
                          const float* __restrict__ w2, const float* __restrict__ b2,
                          const float* __restrict__ w3, const float* __restrict__ b3,
                          float* __restrict__ out) {
  __shared__ float P[16 * 256];
  __shared__ float O1[16 * 128];
  __shared__ float O2[16 * 64];
  int tid = threadIdx.x;
  for (int id = tid; id < 16 * 256; id += 256) {
    int b = id >> 8, hh = id & 255;
    float s = 0.f;
#pragma unroll
    for (int cpart = 0; cpart < 32; ++cpart)
      s += pooledPart[(((b << 5) + cpart) << 8) + hh];
    P[id] = s * (1.f / 2048.f);
  }
  __syncthreads();
  for (int id = tid; id < 16 * 128; id += 256) {
    int r = id >> 7, cc = id & 127;
    float acc = b1[cc];
    for (int d = 0; d < 256; ++d) acc = fmaf(P[(r << 8) + d], w1[(d << 7) + cc], acc);
    O1[id] = fmaxf(acc, 0.f);
  }
  __syncthreads();
  for (int id = tid; id < 16 * 64; id += 256) {
    int r = id >> 6, cc = id & 63;
    float acc = b2[cc];
    for (int d = 0; d < 128; ++d) acc = fmaf(O1[(r << 7) + d], w2[(d << 6) + cc], acc);
    O2[id] = fmaxf(acc, 0.f);
  }
  __syncthreads();
  for (int id = tid; id < 16 * 32; id += 256) {
    int r = id >> 5, cc = id & 31;
    float acc = b3[cc];
    for (int d = 0; d < 64; ++d) acc = fmaf(O2[(r << 6) + d], w3[(d << 5) + cc], acc);
    out[id] = acc;
  }
}

extern "C" void kernel_launch(void* const* d_in, const int* in_sizes, int n_in,
                              void* d_out, int out_size, void* d_ws, size_t ws_size,
                              hipStream_t stream) {
  const float* x          = (const float*)d_in[0];
  const float* enc_w      = (const float*)d_in[1];
  const float* enc_b      = (const float*)d_in[2];
  const float* log_dt     = (const float*)d_in[3];
  const float* C_re       = (const float*)d_in[4];
  const float* C_im       = (const float*)d_in[5];
  const float* log_A_real = (const float*)d_in[6];
  const float* A_imag     = (const float*)d_in[7];
  const float* D_skip     = (const float*)d_in[8];
  const float* w_out      = (const float*)d_in[9];
  const float* b_out      = (const float*)d_in[10];
  const float* ln_g       = (const float*)d_in[11];
  const float* ln_b       = (const float*)d_in[12];
  const float* dw1        = (const float*)d_in[13];
  const float* db1        = (const float*)d_in[14];
  const float* dw2        = (const float*)d_in[15];
  const float* db2        = (const float*)d_in[16];
  const float* dw3        = (const float*)d_in[17];
  const float* db3        = (const float*)d_in[18];

  const size_t SF_BYTES = (size_t)B_SZ * NTC * H_SZ * NH * 8;  // 33,554,432
  char* ws = (char*)d_ws;
  float* hbuf = (float*)ws;
  float4* sFA = (float4*)(ws + 33554432);
  // scheme B (ping-pong sF, fused epilogue scans) needs ~103.3 MB
  bool big = ws_size >= (size_t)(33554432 + 2 * SF_BYTES + 1048576 + 1048576 + 524288);
  float4* sFB;
  unsigned short* wbf;
  float* par;
  float* pooledPart;
  if (big) {
    sFB = (float4*)(ws + 33554432 + SF_BYTES);
    wbf = (unsigned short*)(ws + 33554432 + 2 * SF_BYTES);
    par = (float*)(ws + 33554432 + 2 * SF_BYTES + 1048576);
    pooledPart = (float*)(ws + 33554432 + 2 * SF_BYTES + 2 * 1048576);
  } else {
    sFB = sFA;
    wbf = (unsigned short*)(ws + 33554432 + SF_BYTES);
    par = (float*)(ws + 33554432 + SF_BYTES + 1048576);
    pooledPart = (float*)(ws + 33554432 + SF_BYTES + 2 * 1048576);
  }

  k_encoder<<<512, 256, 0, stream>>>(x, enc_w, enc_b, hbuf);
  k_cvtw<<<2048, 256, 0, stream>>>(w_out, wbf, NL * 512 * H_SZ);
  k_params<<<128, 256, 0, stream>>>(log_dt, log_A_real, A_imag, C_re, C_im, par);

  const size_t PAR_STRIDE = (size_t)H_SZ * NH * 8;
  if (big) {
    k_scan_local<<<2048, 256, 0, stream>>>(hbuf, sFA, par);
    for (int i = 0; i < NL; ++i) {
      const float* pari = par + i * PAR_STRIDE;
      const float* parn = par + (i < NL - 1 ? (i + 1) : i) * PAR_STRIDE;
      float4* sin_ = (i & 1) ? sFB : sFA;
      float4* sout = (i < NL - 1) ? ((i & 1) ? sFA : sFB) : (float4*)nullptr;
      k_layer<<<512, 1024, 0, stream>>>(hbuf, sin_, sout, pari, parn,
                                        D_skip + i * H_SZ, wbf + i * 512 * H_SZ,
                                        b_out + i * 512, ln_g + i * H_SZ, ln_b + i * H_SZ,
                                        pooledPart, (i == NL - 1) ? 1 : 0);
    }
  } else {
    for (int i = 0; i < NL; ++i) {
      const float* pari = par + i * PAR_STRIDE;
      k_scan_local<<<2048, 256, 0, stream>>>(hbuf, sFA, pari);
      k_layer<<<512, 1024, 0, stream>>>(hbuf, sFA, (float4*)nullptr, pari, pari,
                                        D_skip + i * H_SZ, wbf + i * 512 * H_SZ,
                                        b_out + i * 512, ln_g + i * H_SZ, ln_b + i * H_SZ,
                                        pooledPart, (i == NL - 1) ? 1 : 0);
    }
  }
  k_decoder<<<1, 256, 0, stream>>>(pooledPart, dw1, db1, dw2, db2, dw3, db3, (float*)d_out);
}

// Round 6
// 796.494 us; speedup vs baseline: 1.3143x; 1.3143x over previous
//
#include <hip/hip_runtime.h>

#define B_SZ 16
#define L_SZ 2048
#define DIN 64
#define H_SZ 256
#define NH 32
#define NL 4
#define TC 64
#define NTC 32

typedef __attribute__((ext_vector_type(8))) __bf16 bf16x8;
typedef __attribute__((ext_vector_type(4))) float f32x4;

__device__ __forceinline__ unsigned short f2b(float f) {
  unsigned int u = __builtin_bit_cast(unsigned int, f);
  unsigned int r = u + 0x7fffu + ((u >> 16) & 1u);  // RNE (no NaN inputs here)
  return (unsigned short)(r >> 16);
}
__device__ __forceinline__ float b2f(unsigned short u) {
  unsigned int v = ((unsigned int)u) << 16;
  return __builtin_bit_cast(float, v);
}
__device__ __forceinline__ float gelu_exact(float v) {
  return 0.5f * v * (1.f + erff(v * 0.70710678118654752f));
}

// ---------------- encoder: h[b][hh][l] = x[b][l][:] @ enc_w[:,hh] + enc_b ----------------
__global__ void k_encoder(const float* __restrict__ x, const float* __restrict__ w,
                          const float* __restrict__ bias, float* __restrict__ hbuf) {
  __shared__ float wlds[DIN * H_SZ];  // 64 KB
  int tid = threadIdx.x;
  for (int i = tid; i < DIN * H_SZ; i += 256) wlds[i] = w[i];
  int blk = blockIdx.x;            // 512 blocks: b(16) x q(4) x ltile(8)
  int b = blk >> 5;
  int q = (blk >> 3) & 3;
  int l = ((blk & 7) << 8) + tid;
  float xr[DIN];
  const float4* xp = (const float4*)(x + (size_t)(b * L_SZ + l) * DIN);
#pragma unroll
  for (int d4 = 0; d4 < 16; ++d4) {
    float4 v = xp[d4];
    xr[d4 * 4 + 0] = v.x; xr[d4 * 4 + 1] = v.y; xr[d4 * 4 + 2] = v.z; xr[d4 * 4 + 3] = v.w;
  }
  __syncthreads();
  for (int i = 0; i < 64; ++i) {
    int hh = (q << 6) + i;
    float acc = bias[hh];
#pragma unroll
    for (int d = 0; d < DIN; ++d) acc = fmaf(xr[d], wlds[d * H_SZ + hh], acc);
    hbuf[(b * H_SZ + hh) * L_SZ + l] = acc;
  }
}

// ---------------- convert w_out to bf16 ----------------
__global__ void k_cvtw(const float* __restrict__ w, unsigned short* __restrict__ wbf, int n) {
  int i = blockIdx.x * 256 + threadIdx.x;
  if (i < n) wbf[i] = f2b(w[i]);
}

// ---------------- precompute per-state params: lr, li, c2r, c2i, lTr, lTi ----------------
__global__ void k_params(const float* __restrict__ log_dt, const float* __restrict__ log_A_real,
                         const float* __restrict__ A_imag, const float* __restrict__ C_re,
                         const float* __restrict__ C_im, float* __restrict__ par) {
  int id = blockIdx.x * 256 + threadIdx.x;  // i*8192 + h*32 + n
  if (id >= NL * H_SZ * NH) return;
  int i = id >> 13;
  int hn = id & 8191;
  int h = hn >> 5;
  float dt = expf(log_dt[i * H_SZ + h]);
  float Ar = -expf(log_A_real[(size_t)i * H_SZ * NH + hn]);
  float Ai = A_imag[(size_t)i * H_SZ * NH + hn];
  float dr = dt * Ar, di = dt * Ai;
  float e = expf(dr), sn, cs;
  sincosf(di, &sn, &cs);
  float lr = e * cs, li = e * sn;
  float eT = expf((float)TC * dr), snT, csT;
  sincosf((float)TC * di, &snT, &csT);
  float Cr = C_re[(size_t)i * H_SZ * NH + hn], Ci = C_im[(size_t)i * H_SZ * NH + hn];
  float wr = lr - 1.f, wi = li;
  float pr = Cr * wr - Ci * wi;
  float pi = Cr * wi + Ci * wr;
  float inv = 2.f / fmaf(Ar, Ar, Ai * Ai);
  float4* p = (float4*)(par + (size_t)id * 8);
  p[0] = make_float4(lr, li, (pr * Ar + pi * Ai) * inv, (pi * Ar - pr * Ai) * inv);
  p[1] = make_float4(eT * csT, eT * snT, 0.f, 0.f);
}

// ---------------- local chunk scan (state only) ----------------
__global__ void k_scan_local(const float* __restrict__ hbuf, float4* __restrict__ sF,
                             const float* __restrict__ par) {
  int gt = blockIdx.x * 256 + threadIdx.x;  // b(4b) c(5b) h(8b) ng(2b)
  int ng = gt & 3;
  int h = (gt >> 2) & 255;
  int c = (gt >> 10) & 31;
  int b = gt >> 15;
  float lr[8], li[8], sre[8], sim[8];
  const float4* pp = (const float4*)(par + (size_t)(h * NH + ng * 8) * 8);
#pragma unroll
  for (int k = 0; k < 8; ++k) {
    float4 p0 = pp[k * 2];
    lr[k] = p0.x; li[k] = p0.y;
    sre[k] = 0.f; sim[k] = 0.f;
  }
  const float* xp = hbuf + (b * H_SZ + h) * L_SZ + c * TC;
  float4 xv = *(const float4*)xp;
  for (int j4 = 0; j4 < TC; j4 += 4) {
    float4 xn = xv;
    if (j4 + 4 < TC) xn = *(const float4*)(xp + j4 + 4);
    float xe[4] = {xv.x, xv.y, xv.z, xv.w};
#pragma unroll
    for (int e = 0; e < 4; ++e) {
      float xj = xe[e];
#pragma unroll
      for (int k = 0; k < 8; ++k) {
        float nr = fmaf(lr[k], sre[k], xj);
        nr = fmaf(-li[k], sim[k], nr);
        float ni = lr[k] * sim[k];
        ni = fmaf(li[k], sre[k], ni);
        sre[k] = nr; sim[k] = ni;
      }
    }
    xv = xn;
  }
  float4* out = sF + (((size_t)((b << 5) + c) * H_SZ + h) * 4 + ng) * 4;
#pragma unroll
  for (int q = 0; q < 4; ++q)
    out[q] = make_float4(sre[2 * q], sim[2 * q], sre[2 * q + 1], sim[2 * q + 1]);
}

// ---------------- fused per-layer kernel: 512 threads, 2 blocks/CU ----------------
__launch_bounds__(512, 4)
__global__ void k_layer(float* __restrict__ hbuf, const float4* __restrict__ sFin,
                        const float* __restrict__ par,
                        const float* __restrict__ D_skip,
                        const unsigned short* __restrict__ wbf,
                        const float* __restrict__ b_out,
                        const float* __restrict__ ln_g, const float* __restrict__ ln_b,
                        float* __restrict__ pooledPart, int last) {
  __shared__ __align__(16) unsigned short yt[TC][H_SZ + 8];  // 33792 B
  __shared__ float part[TC][8][2];                           // 4096 B
  __shared__ float stats[TC][2];                             // 512 B
  int tid = threadIdx.x;
  int b = blockIdx.x >> 5;
  int c = blockIdx.x & 31;
  int l0 = c << 6;

  // ---- phase 1: recurrence (two h-subpasses of 128 h each) ----
  for (int p01 = 0; p01 < 2; ++p01) {
    int h = (tid >> 2) + (p01 << 7);
    int ng = tid & 3;
    const float4* pp = (const float4*)(par + (size_t)(h * NH + ng * 8) * 8);
    float lr[8], li[8], c2r[8], c2i[8], sre[8], sim[8];
#pragma unroll
    for (int k = 0; k < 8; ++k) {
      float4 p0 = pp[k * 2];
      lr[k] = p0.x; li[k] = p0.y; c2r[k] = p0.z; c2i[k] = p0.w;
      sre[k] = 0.f; sim[k] = 0.f;
    }
    // lookback over predecessor chunk-finals (written by PREVIOUS kernel)
    if (c > 0) {
      float lTr[8], lTi[8];
#pragma unroll
      for (int k = 0; k < 8; ++k) {
        float4 p1 = pp[k * 2 + 1];
        lTr[k] = p1.x; lTi[k] = p1.y;
      }
      for (int cc = 0; cc < c; ++cc) {
        const float4* fp = sFin + (((size_t)((b << 5) + cc) * H_SZ + h) * 4 + ng) * 4;
#pragma unroll
        for (int q = 0; q < 4; ++q) {
          float4 f = fp[q];
          const int k0 = 2 * q, k1 = 2 * q + 1;
          float nr0 = fmaf(lTr[k0], sre[k0], f.x); nr0 = fmaf(-lTi[k0], sim[k0], nr0);
          float ni0 = fmaf(lTr[k0], sim[k0], f.y); ni0 = fmaf(lTi[k0], sre[k0], ni0);
          sre[k0] = nr0; sim[k0] = ni0;
          float nr1 = fmaf(lTr[k1], sre[k1], f.z); nr1 = fmaf(-lTi[k1], sim[k1], nr1);
          float ni1 = fmaf(lTr[k1], sim[k1], f.w); ni1 = fmaf(lTi[k1], sre[k1], ni1);
          sre[k1] = nr1; sim[k1] = ni1;
        }
      }
    }
    // main scan over this tile; y + D*x -> LDS (bf16)
    float Dh = D_skip[h];
    const float* xp = hbuf + (b * H_SZ + h) * L_SZ + l0;
    float4 xv = *(const float4*)xp;
    for (int j4 = 0; j4 < TC; j4 += 4) {
      float4 xn = xv;
      if (j4 + 4 < TC) xn = *(const float4*)(xp + j4 + 4);
      float xe[4] = {xv.x, xv.y, xv.z, xv.w};
#pragma unroll
      for (int e = 0; e < 4; ++e) {
        float xj = xe[e];
        float yp0 = 0.f, yp1 = 0.f;
#pragma unroll
        for (int k = 0; k < 8; ++k) {
          float nr = fmaf(lr[k], sre[k], xj);
          nr = fmaf(-li[k], sim[k], nr);
          float ni = lr[k] * sim[k];
          ni = fmaf(li[k], sre[k], ni);
          sre[k] = nr; sim[k] = ni;
          if (k & 1) {
            yp1 = fmaf(c2r[k], nr, yp1);
            yp1 = fmaf(-c2i[k], ni, yp1);
          } else {
            yp0 = fmaf(c2r[k], nr, yp0);
            yp0 = fmaf(-c2i[k], ni, yp0);
          }
        }
        float yp = yp0 + yp1;
        yp += __shfl_xor(yp, 1);
        yp += __shfl_xor(yp, 2);
        if (ng == 0) yt[j4 + e][h] = f2b(fmaf(Dh, xj, yp));
      }
      xv = xn;
    }
  }
  __syncthreads();
  // ---- phase 2: exact GELU in place (packed pairs) ----
  for (int it = 0; it < 16; ++it) {
    int id = it * 512 + tid;
    int jr = id >> 7, hp = id & 127;
    unsigned int u = *(unsigned int*)&yt[jr][hp * 2];
    float v0 = b2f((unsigned short)(u & 0xffff));
    float v1 = b2f((unsigned short)(u >> 16));
    v0 = gelu_exact(v0);
    v1 = gelu_exact(v1);
    *(unsigned int*)&yt[jr][hp * 2] = (unsigned int)f2b(v0) | ((unsigned int)f2b(v1) << 16);
  }
  __syncthreads();
  // ---- phase 3: 1x1 conv (512x256 @ 256x64) via MFMA + GLU; z -> LDS ----
  {
    int wv = tid >> 6, lane = tid & 63;
    int lrow = lane & 15, lk8 = (lane >> 4) << 3;
    // wave wv covers A rows {wv*16, wv*16+128} and G rows {+256, +384}
    f32x4 accA[8], accG[8];
    f32x4 zed = {0.f, 0.f, 0.f, 0.f};
#pragma unroll
    for (int t = 0; t < 8; ++t) { accA[t] = zed; accG[t] = zed; }
    const unsigned short* wA0 = wbf + ((wv << 4) + lrow) * H_SZ;
    const unsigned short* wA1 = wA0 + 128 * H_SZ;
    const unsigned short* wG0 = wA0 + 256 * H_SZ;
    const unsigned short* wG1 = wA0 + 384 * H_SZ;
#pragma unroll
    for (int k0 = 0; k0 < H_SZ; k0 += 32) {
      bf16x8 a0 = *(const bf16x8*)(wA0 + k0 + lk8);
      bf16x8 a1 = *(const bf16x8*)(wA1 + k0 + lk8);
      bf16x8 g0 = *(const bf16x8*)(wG0 + k0 + lk8);
      bf16x8 g1 = *(const bf16x8*)(wG1 + k0 + lk8);
#pragma unroll
      for (int jt = 0; jt < 4; ++jt) {
        bf16x8 bb = *(const bf16x8*)(&yt[(jt << 4) + lrow][k0 + lk8]);
        accA[jt]     = __builtin_amdgcn_mfma_f32_16x16x32_bf16(a0, bb, accA[jt], 0, 0, 0);
        accA[4 + jt] = __builtin_amdgcn_mfma_f32_16x16x32_bf16(a1, bb, accA[4 + jt], 0, 0, 0);
        accG[jt]     = __builtin_amdgcn_mfma_f32_16x16x32_bf16(g0, bb, accG[jt], 0, 0, 0);
        accG[4 + jt] = __builtin_amdgcn_mfma_f32_16x16x32_bf16(g1, bb, accG[4 + jt], 0, 0, 0);
      }
    }
    __syncthreads();  // all y reads done before overwrite with z
    int rsub = (lane >> 4) << 2;
    float bA[8], bG[8];
#pragma unroll
    for (int t = 0; t < 2; ++t) {
#pragma unroll
      for (int r = 0; r < 4; ++r) {
        bA[t * 4 + r] = b_out[(wv << 4) + t * 128 + rsub + r];
        bG[t * 4 + r] = b_out[256 + (wv << 4) + t * 128 + rsub + r];
      }
    }
#pragma unroll
    for (int t = 0; t < 2; ++t) {
#pragma unroll
      for (int jt = 0; jt < 4; ++jt) {
#pragma unroll
        for (int r = 0; r < 4; ++r) {
          float a = accA[t * 4 + jt][r] + bA[t * 4 + r];
          float g = accG[t * 4 + jt][r] + bG[t * 4 + r];
          float z = a / (1.f + expf(-g));
          yt[(jt << 4) + lrow][(wv << 4) + t * 128 + rsub + r] = f2b(z);
        }
      }
    }
  }
  __syncthreads();
  // ---- phase 4: LN stats over H; v = z + residual ----
  int j = tid & 63, hg = tid >> 6;  // 8 groups of 32 h
  float vreg[32];
  {
    const float* xc = hbuf + (b * H_SZ + (hg << 5)) * L_SZ + l0 + j;
    float s = 0.f, sq = 0.f;
#pragma unroll
    for (int k = 0; k < 32; ++k) {
      float v = b2f(yt[j][(hg << 5) + k]) + xc[(size_t)k * L_SZ];
      vreg[k] = v;
      s += v; sq = fmaf(v, v, sq);
    }
    part[j][hg][0] = s; part[j][hg][1] = sq;
  }
  __syncthreads();
  if (tid < TC) {
    float s = 0.f, sq = 0.f;
#pragma unroll
    for (int g = 0; g < 8; ++g) { s += part[tid][g][0]; sq += part[tid][g][1]; }
    float mu = s * (1.f / 256.f);
    float var = sq * (1.f / 256.f) - mu * mu;
    stats[tid][0] = mu;
    stats[tid][1] = rsqrtf(var + 1e-5f);
  }
  __syncthreads();
  // ---- phase 5: normalized residual; write hbuf OR pool partials (last) ----
  {
    float mu = stats[j][0], rs = stats[j][1];
    if (!last) {
      float* xo = hbuf + (b * H_SZ + (hg << 5)) * L_SZ + l0 + j;
#pragma unroll
      for (int k = 0; k < 32; ++k) {
        int hh = (hg << 5) + k;
        xo[(size_t)k * L_SZ] = (vreg[k] - mu) * rs * ln_g[hh] + ln_b[hh];
      }
    } else {
#pragma unroll
      for (int k = 0; k < 32; ++k) {
        int hh = (hg << 5) + k;
        yt[j][hh] = f2b((vreg[k] - mu) * rs * ln_g[hh] + ln_b[hh]);
      }
      __syncthreads();
      if (tid < H_SZ) {
        float s = 0.f;
        for (int jj = 0; jj < TC; ++jj) s += b2f(yt[jj][tid]);
        pooledPart[(((b << 5) + c) << 8) + tid] = s;
      }
    }
  }
}

// ---------------- decoder MLP (single block) with pooling preamble ----------------
__global__ void k_decoder(const float* __restrict__ pooledPart,
                          const float* __restrict__ w1, const float* __restrict__ b1,
                          const float* __restrict__ w2, const float* __restrict__ b2,
                          const float* __restrict__ w3, const float* __restrict__ b3,
                          float* __restrict__ out) {
  __shared__ float P[16 * 256];
  __shared__ float O1[16 * 128];
  __shared__ float O2[16 * 64];
  int tid = threadIdx.x;
  for (int id = tid; id < 16 * 256; id += 256) {
    int b = id >> 8, hh = id & 255;
    float s = 0.f;
#pragma unroll
    for (int cpart = 0; cpart < 32; ++cpart)
      s += pooledPart[(((b << 5) + cpart) << 8) + hh];
    P[id] = s * (1.f / 2048.f);
  }
  __syncthreads();
  for (int id = tid; id < 16 * 128; id += 256) {
    int r = id >> 7, cc = id & 127;
    float acc = b1[cc];
    for (int d = 0; d < 256; ++d) acc = fmaf(P[(r << 8) + d], w1[(d << 7) + cc], acc);
    O1[id] = fmaxf(acc, 0.f);
  }
  __syncthreads();
  for (int id = tid; id < 16 * 64; id += 256) {
    int r = id >> 6, cc = id & 63;
    float acc = b2[cc];
    for (int d = 0; d < 128; ++d) acc = fmaf(O1[(r << 7) + d], w2[(d << 6) + cc], acc);
    O2[id] = fmaxf(acc, 0.f);
  }
  __syncthreads();
  for (int id = tid; id < 16 * 32; id += 256) {
    int r = id >> 5, cc = id & 31;
    float acc = b3[cc];
    for (int d = 0; d < 64; ++d) acc = fmaf(O2[(r << 6) + d], w3[(d << 5) + cc], acc);
    out[id] = acc;
  }
}

extern "C" void kernel_launch(void* const* d_in, const int* in_sizes, int n_in,
                              void* d_out, int out_size, void* d_ws, size_t ws_size,
                              hipStream_t stream) {
  const float* x          = (const float*)d_in[0];
  const float* enc_w      = (const float*)d_in[1];
  const float* enc_b      = (const float*)d_in[2];
  const float* log_dt     = (const float*)d_in[3];
  const float* C_re       = (const float*)d_in[4];
  const float* C_im       = (const float*)d_in[5];
  const float* log_A_real = (const float*)d_in[6];
  const float* A_imag     = (const float*)d_in[7];
  const float* D_skip     = (const float*)d_in[8];
  const float* w_out      = (const float*)d_in[9];
  const float* b_out      = (const float*)d_in[10];
  const float* ln_g       = (const float*)d_in[11];
  const float* ln_b       = (const float*)d_in[12];
  const float* dw1        = (const float*)d_in[13];
  const float* db1        = (const float*)d_in[14];
  const float* dw2        = (const float*)d_in[15];
  const float* db2        = (const float*)d_in[16];
  const float* dw3        = (const float*)d_in[17];
  const float* db3        = (const float*)d_in[18];

  char* ws = (char*)d_ws;
  float* hbuf = (float*)ws;                                  // 33,554,432 B
  float4* sF = (float4*)(ws + 33554432);                     // 33,554,432 B
  unsigned short* wbf = (unsigned short*)(ws + 67108864);    //  1,048,576 B
  float* par = (float*)(ws + 68157440);                      //  1,048,576 B
  float* pooledPart = (float*)(ws + 69206016);               //    524,288 B

  k_encoder<<<512, 256, 0, stream>>>(x, enc_w, enc_b, hbuf);
  k_cvtw<<<2048, 256, 0, stream>>>(w_out, wbf, NL * 512 * H_SZ);
  k_params<<<128, 256, 0, stream>>>(log_dt, log_A_real, A_imag, C_re, C_im, par);
  const size_t PAR_STRIDE = (size_t)H_SZ * NH * 8;
  for (int i = 0; i < NL; ++i) {
    const float* pari = par + i * PAR_STRIDE;
    k_scan_local<<<2048, 256, 0, stream>>>(hbuf, sF, pari);
    k_layer<<<512, 512, 0, stream>>>(hbuf, sF, pari,
                                     D_skip + i * H_SZ, wbf + i * 512 * H_SZ,
                                     b_out + i * 512, ln_g + i * H_SZ, ln_b + i * H_SZ,
                                     pooledPart, (i == NL - 1) ? 1 : 0);
  }
  k_decoder<<<1, 256, 0, stream>>>(pooledPart, dw1, db1, dw2, db2, dw3, db3, (float*)d_out);
}

// Round 7
// 749.041 us; speedup vs baseline: 1.3975x; 1.0634x over previous
//
#include <hip/hip_runtime.h>

#define B_SZ 16
#define L_SZ 2048
#define DIN 64
#define H_SZ 256
#define NH 32
#define NL 4
#define TC 64
#define NTC 32

typedef __attribute__((ext_vector_type(8))) __bf16 bf16x8;
typedef __attribute__((ext_vector_type(4))) float f32x4;

__device__ __forceinline__ unsigned short f2b(float f) {
  unsigned int u = __builtin_bit_cast(unsigned int, f);
  unsigned int r = u + 0x7fffu + ((u >> 16) & 1u);  // RNE (no NaN inputs here)
  return (unsigned short)(r >> 16);
}
__device__ __forceinline__ float b2f(unsigned short u) {
  unsigned int v = ((unsigned int)u) << 16;
  return __builtin_bit_cast(float, v);
}
__device__ __forceinline__ float gelu_exact(float v) {
  return 0.5f * v * (1.f + erff(v * 0.70710678118654752f));
}

// ---------------- encoder: h[b][hh][l] = x[b][l][:] @ enc_w[:,hh] + enc_b ----------------
__global__ void k_encoder(const float* __restrict__ x, const float* __restrict__ w,
                          const float* __restrict__ bias, float* __restrict__ hbuf) {
  __shared__ float wlds[DIN * H_SZ];  // 64 KB
  int tid = threadIdx.x;
  for (int i = tid; i < DIN * H_SZ; i += 256) wlds[i] = w[i];
  int blk = blockIdx.x;            // 512 blocks: b(16) x q(4) x ltile(8)
  int b = blk >> 5;
  int q = (blk >> 3) & 3;
  int l = ((blk & 7) << 8) + tid;
  float xr[DIN];
  const float4* xp = (const float4*)(x + (size_t)(b * L_SZ + l) * DIN);
#pragma unroll
  for (int d4 = 0; d4 < 16; ++d4) {
    float4 v = xp[d4];
    xr[d4 * 4 + 0] = v.x; xr[d4 * 4 + 1] = v.y; xr[d4 * 4 + 2] = v.z; xr[d4 * 4 + 3] = v.w;
  }
  __syncthreads();
  for (int i = 0; i < 64; ++i) {
    int hh = (q << 6) + i;
    float acc = bias[hh];
#pragma unroll
    for (int d = 0; d < DIN; ++d) acc = fmaf(xr[d], wlds[d * H_SZ + hh], acc);
    hbuf[(b * H_SZ + hh) * L_SZ + l] = acc;
  }
}

// ---------------- convert w_out to bf16 ----------------
__global__ void k_cvtw(const float* __restrict__ w, unsigned short* __restrict__ wbf, int n) {
  int i = blockIdx.x * 256 + threadIdx.x;
  if (i < n) wbf[i] = f2b(w[i]);
}

// ---------------- precompute per-state params: lr, li, c2r, c2i, lTr, lTi ----------------
__global__ void k_params(const float* __restrict__ log_dt, const float* __restrict__ log_A_real,
                         const float* __restrict__ A_imag, const float* __restrict__ C_re,
                         const float* __restrict__ C_im, float* __restrict__ par) {
  int id = blockIdx.x * 256 + threadIdx.x;  // i*8192 + h*32 + n
  if (id >= NL * H_SZ * NH) return;
  int i = id >> 13;
  int hn = id & 8191;
  int h = hn >> 5;
  float dt = expf(log_dt[i * H_SZ + h]);
  float Ar = -expf(log_A_real[(size_t)i * H_SZ * NH + hn]);
  float Ai = A_imag[(size_t)i * H_SZ * NH + hn];
  float dr = dt * Ar, di = dt * Ai;
  float e = expf(dr), sn, cs;
  sincosf(di, &sn, &cs);
  float lr = e * cs, li = e * sn;
  float eT = expf((float)TC * dr), snT, csT;
  sincosf((float)TC * di, &snT, &csT);
  float Cr = C_re[(size_t)i * H_SZ * NH + hn], Ci = C_im[(size_t)i * H_SZ * NH + hn];
  float wr = lr - 1.f, wi = li;
  float pr = Cr * wr - Ci * wi;
  float pi = Cr * wi + Ci * wr;
  float inv = 2.f / fmaf(Ar, Ar, Ai * Ai);
  float4* p = (float4*)(par + (size_t)id * 8);
  p[0] = make_float4(lr, li, (pr * Ar + pi * Ai) * inv, (pi * Ar - pr * Ai) * inv);
  p[1] = make_float4(eT * csT, eT * snT, 0.f, 0.f);
}

// ---------------- local chunk scan (state only) ----------------
__global__ void k_scan_local(const float* __restrict__ hbuf, float4* __restrict__ sF,
                             const float* __restrict__ par) {
  int gt = blockIdx.x * 256 + threadIdx.x;  // b(4b) c(5b) h(8b) ng(2b)
  int ng = gt & 3;
  int h = (gt >> 2) & 255;
  int c = (gt >> 10) & 31;
  int b = gt >> 15;
  float lr[8], li[8], sre[8], sim[8];
  const float4* pp = (const float4*)(par + (size_t)(h * NH + ng * 8) * 8);
#pragma unroll
  for (int k = 0; k < 8; ++k) {
    float4 p0 = pp[k * 2];
    lr[k] = p0.x; li[k] = p0.y;
    sre[k] = 0.f; sim[k] = 0.f;
  }
  const float* xp = hbuf + (b * H_SZ + h) * L_SZ + c * TC;
  float4 xv = *(const float4*)xp;
  for (int j4 = 0; j4 < TC; j4 += 4) {
    float4 xn = xv;
    if (j4 + 4 < TC) xn = *(const float4*)(xp + j4 + 4);
    float xe[4] = {xv.x, xv.y, xv.z, xv.w};
#pragma unroll
    for (int e = 0; e < 4; ++e) {
      float xj = xe[e];
#pragma unroll
      for (int k = 0; k < 8; ++k) {
        float nr = fmaf(lr[k], sre[k], xj);
        nr = fmaf(-li[k], sim[k], nr);
        float ni = lr[k] * sim[k];
        ni = fmaf(li[k], sre[k], ni);
        sre[k] = nr; sim[k] = ni;
      }
    }
    xv = xn;
  }
  float4* out = sF + (((size_t)((b << 5) + c) * H_SZ + h) * 4 + ng) * 4;
#pragma unroll
  for (int q = 0; q < 4; ++q)
    out[q] = make_float4(sre[2 * q], sim[2 * q], sre[2 * q + 1], sim[2 * q + 1]);
}

// ---------------- exclusive prefix over chunk finals (in place) ----------------
// thread = (b, h, ng); serial over the 32 chunks: sF[c] <- carry_before_c
__global__ void k_prefix(float4* __restrict__ sF, const float* __restrict__ par) {
  int id = blockIdx.x * 256 + threadIdx.x;  // 16384 = b(4) h(8) ng(2)
  int ng = id & 3;
  int h = (id >> 2) & 255;
  int b = id >> 10;
  const float4* pp = (const float4*)(par + (size_t)(h * NH + ng * 8) * 8);
  float lTr[8], lTi[8], cr[8], ci[8];
#pragma unroll
  for (int k = 0; k < 8; ++k) {
    float4 p1 = pp[k * 2 + 1];
    lTr[k] = p1.x; lTi[k] = p1.y;
    cr[k] = 0.f; ci[k] = 0.f;
  }
  for (int c = 0; c < NTC; ++c) {
    float4* fp = sF + (((size_t)((b << 5) + c) * H_SZ + h) * 4 + ng) * 4;
    float4 f[4];
#pragma unroll
    for (int q = 0; q < 4; ++q) f[q] = fp[q];
#pragma unroll
    for (int q = 0; q < 4; ++q)
      fp[q] = make_float4(cr[2 * q], ci[2 * q], cr[2 * q + 1], ci[2 * q + 1]);
#pragma unroll
    for (int q = 0; q < 4; ++q) {
      const int k0 = 2 * q, k1 = 2 * q + 1;
      float nr0 = fmaf(lTr[k0], cr[k0], f[q].x); nr0 = fmaf(-lTi[k0], ci[k0], nr0);
      float ni0 = fmaf(lTr[k0], ci[k0], f[q].y); ni0 = fmaf(lTi[k0], cr[k0], ni0);
      cr[k0] = nr0; ci[k0] = ni0;
      float nr1 = fmaf(lTr[k1], cr[k1], f[q].z); nr1 = fmaf(-lTi[k1], ci[k1], nr1);
      float ni1 = fmaf(lTr[k1], ci[k1], f[q].w); ni1 = fmaf(lTi[k1], cr[k1], ni1);
      cr[k1] = nr1; ci[k1] = ni1;
    }
  }
}

// ---------------- fused per-layer kernel: carry load + recurrence + gelu + GLU + LN ----------------
__launch_bounds__(1024, 4)
__global__ void k_layer(float* __restrict__ hbuf, const float4* __restrict__ sFin,
                        const float* __restrict__ par,
                        const float* __restrict__ D_skip,
                        const unsigned short* __restrict__ wbf,
                        const float* __restrict__ b_out,
                        const float* __restrict__ ln_g, const float* __restrict__ ln_b,
                        float* __restrict__ pooledPart, int last) {
  __shared__ __align__(16) unsigned short yt[TC][H_SZ + 8];  // 33792 B
  __shared__ float part[TC][16][2];                          // 8192 B
  __shared__ float stats[TC][2];                             // 512 B
  int tid = threadIdx.x;
  int b = blockIdx.x >> 5;
  int c = blockIdx.x & 31;
  int l0 = c << 6;

  // ---- phase 1: recurrence from precomputed carry; y + D*x -> LDS (bf16) ----
  {
    int h = tid >> 2, ng = tid & 3;
    const float4* pp = (const float4*)(par + (size_t)(h * NH + ng * 8) * 8);
    float lr[8], li[8], c2r[8], c2i[8], sre[8], sim[8];
    const float4* fp = sFin + (((size_t)((b << 5) + c) * H_SZ + h) * 4 + ng) * 4;
#pragma unroll
    for (int q = 0; q < 4; ++q) {
      float4 f = fp[q];
      sre[2 * q] = f.x; sim[2 * q] = f.y;
      sre[2 * q + 1] = f.z; sim[2 * q + 1] = f.w;
    }
#pragma unroll
    for (int k = 0; k < 8; ++k) {
      float4 p0 = pp[k * 2];
      lr[k] = p0.x; li[k] = p0.y; c2r[k] = p0.z; c2i[k] = p0.w;
    }
    float Dh = D_skip[h];
    const float* xp = hbuf + (b * H_SZ + h) * L_SZ + l0;
    float4 xv = *(const float4*)xp;
    for (int j4 = 0; j4 < TC; j4 += 4) {
      float4 xn = xv;
      if (j4 + 4 < TC) xn = *(const float4*)(xp + j4 + 4);
      float xe[4] = {xv.x, xv.y, xv.z, xv.w};
#pragma unroll
      for (int e = 0; e < 4; ++e) {
        float xj = xe[e];
        float yp0 = 0.f, yp1 = 0.f;
#pragma unroll
        for (int k = 0; k < 8; ++k) {
          float nr = fmaf(lr[k], sre[k], xj);
          nr = fmaf(-li[k], sim[k], nr);
          float ni = lr[k] * sim[k];
          ni = fmaf(li[k], sre[k], ni);
          sre[k] = nr; sim[k] = ni;
          if (k & 1) {
            yp1 = fmaf(c2r[k], nr, yp1);
            yp1 = fmaf(-c2i[k], ni, yp1);
          } else {
            yp0 = fmaf(c2r[k], nr, yp0);
            yp0 = fmaf(-c2i[k], ni, yp0);
          }
        }
        float yp = yp0 + yp1;
        yp += __shfl_xor(yp, 1);
        yp += __shfl_xor(yp, 2);
        if (ng == 0) yt[j4 + e][h] = f2b(fmaf(Dh, xj, yp));
      }
      xv = xn;
    }
  }
  __syncthreads();
  // ---- phase 2: exact GELU in place (packed pairs) ----
  for (int it = 0; it < 8; ++it) {
    int id = it * 1024 + tid;
    int jr = id >> 7, hp = id & 127;
    unsigned int u = *(unsigned int*)&yt[jr][hp * 2];
    float v0 = b2f((unsigned short)(u & 0xffff));
    float v1 = b2f((unsigned short)(u >> 16));
    v0 = gelu_exact(v0);
    v1 = gelu_exact(v1);
    *(unsigned int*)&yt[jr][hp * 2] = (unsigned int)f2b(v0) | ((unsigned int)f2b(v1) << 16);
  }
  __syncthreads();
  // ---- phase 3: 1x1 conv (512x256 @ 256x64) via MFMA + GLU; z -> LDS ----
  {
    int w = tid >> 6, lane = tid & 63;
    int lrow = lane & 15, lk8 = (lane >> 4) << 3;
    f32x4 accA[4], accG[4];
    f32x4 zed = {0.f, 0.f, 0.f, 0.f};
#pragma unroll
    for (int jt = 0; jt < 4; ++jt) { accA[jt] = zed; accG[jt] = zed; }
    const unsigned short* wA = wbf + ((w << 4) + lrow) * H_SZ;
    const unsigned short* wG = wA + 256 * H_SZ;
#pragma unroll
    for (int k0 = 0; k0 < H_SZ; k0 += 32) {
      bf16x8 a0 = *(const bf16x8*)(wA + k0 + lk8);
      bf16x8 a1 = *(const bf16x8*)(wG + k0 + lk8);
#pragma unroll
      for (int jt = 0; jt < 4; ++jt) {
        bf16x8 bb = *(const bf16x8*)(&yt[(jt << 4) + lrow][k0 + lk8]);
        accA[jt] = __builtin_amdgcn_mfma_f32_16x16x32_bf16(a0, bb, accA[jt], 0, 0, 0);
        accG[jt] = __builtin_amdgcn_mfma_f32_16x16x32_bf16(a1, bb, accG[jt], 0, 0, 0);
      }
    }
    __syncthreads();  // all y reads done before overwrite with z
    int rbase = (lane >> 4) << 2;
    float bA[4], bG[4];
#pragma unroll
    for (int r = 0; r < 4; ++r) {
      bA[r] = b_out[(w << 4) + rbase + r];
      bG[r] = b_out[256 + (w << 4) + rbase + r];
    }
#pragma unroll
    for (int jt = 0; jt < 4; ++jt) {
#pragma unroll
      for (int r = 0; r < 4; ++r) {
        float a = accA[jt][r] + bA[r];
        float g = accG[jt][r] + bG[r];
        float z = a / (1.f + expf(-g));
        yt[(jt << 4) + lrow][(w << 4) + rbase + r] = f2b(z);
      }
    }
  }
  __syncthreads();
  // ---- phase 4: LN stats over H; v = z + residual ----
  int j = tid & 63, hg = tid >> 6;  // 16 groups of 16 h
  float vreg[16];
  {
    const float* xc = hbuf + (b * H_SZ + (hg << 4)) * L_SZ + l0 + j;
    float s = 0.f, sq = 0.f;
#pragma unroll
    for (int k = 0; k < 16; ++k) {
      float v = b2f(yt[j][(hg << 4) + k]) + xc[(size_t)k * L_SZ];
      vreg[k] = v;
      s += v; sq = fmaf(v, v, sq);
    }
    part[j][hg][0] = s; part[j][hg][1] = sq;
  }
  __syncthreads();
  if (tid < TC) {
    float s = 0.f, sq = 0.f;
#pragma unroll
    for (int g = 0; g < 16; ++g) { s += part[tid][g][0]; sq += part[tid][g][1]; }
    float mu = s * (1.f / 256.f);
    float var = sq * (1.f / 256.f) - mu * mu;
    stats[tid][0] = mu;
    stats[tid][1] = rsqrtf(var + 1e-5f);
  }
  __syncthreads();
  // ---- phase 5: normalized residual; write hbuf OR pool partials (last) ----
  {
    float mu = stats[j][0], rs = stats[j][1];
    if (!last) {
      float* xo = hbuf + (b * H_SZ + (hg << 4)) * L_SZ + l0 + j;
#pragma unroll
      for (int k = 0; k < 16; ++k) {
        int hh = (hg << 4) + k;
        xo[(size_t)k * L_SZ] = (vreg[k] - mu) * rs * ln_g[hh] + ln_b[hh];
      }
    } else {
#pragma unroll
      for (int k = 0; k < 16; ++k) {
        int hh = (hg << 4) + k;
        yt[j][hh] = f2b((vreg[k] - mu) * rs * ln_g[hh] + ln_b[hh]);
      }
      __syncthreads();
      if (tid < H_SZ) {
        float s = 0.f;
        for (int jj = 0; jj < TC; ++jj) s += b2f(yt[jj][tid]);
        pooledPart[(((b << 5) + c) << 8) + tid] = s;
      }
    }
  }
}

// ---------------- decoder MLP (single block) with pooling preamble ----------------
__global__ void k_decoder(const float* __restrict__ pooledPart,
                          const float* __restrict__ w1, const float* __restrict__ b1,
                          const float* __restrict__ w2, const float* __restrict__ b2,
                          const float* __restrict__ w3, const float* __restrict__ b3,
                          float* __restrict__ out) {
  __shared__ float P[16 * 256];
  __shared__ float O1[16 * 128];
  __shared__ float O2[16 * 64];
  int tid = threadIdx.x;
  for (int id = tid; id < 16 * 256; id += 256) {
    int b = id >> 8, hh = id & 255;
    float s = 0.f;
#pragma unroll
    for (int cpart = 0; cpart < 32; ++cpart)
      s += pooledPart[(((b << 5) + cpart) << 8) + hh];
    P[id] = s * (1.f / 2048.f);
  }
  __syncthreads();
  for (int id = tid; id < 16 * 128; id += 256) {
    int r = id >> 7, cc = id & 127;
    float acc = b1[cc];
    for (int d = 0; d < 256; ++d) acc = fmaf(P[(r << 8) + d], w1[(d << 7) + cc], acc);
    O1[id] = fmaxf(acc, 0.f);
  }
  __syncthreads();
  for (int id = tid; id < 16 * 64; id += 256) {
    int r = id >> 6, cc = id & 63;
    float acc = b2[cc];
    for (int d = 0; d < 128; ++d) acc = fmaf(O1[(r << 7) + d], w2[(d << 6) + cc], acc);
    O2[id] = fmaxf(acc, 0.f);
  }
  __syncthreads();
  for (int id = tid; id < 16 * 32; id += 256) {
    int r = id >> 5, cc = id & 31;
    float acc = b3[cc];
    for (int d = 0; d < 64; ++d) acc = fmaf(O2[(r << 6) + d], w3[(d << 5) + cc], acc);
    out[id] = acc;
  }
}

extern "C" void kernel_launch(void* const* d_in, const int* in_sizes, int n_in,
                              void* d_out, int out_size, void* d_ws, size_t ws_size,
                              hipStream_t stream) {
  const float* x          = (const float*)d_in[0];
  const float* enc_w      = (const float*)d_in[1];
  const float* enc_b      = (const float*)d_in[2];
  const float* log_dt     = (const float*)d_in[3];
  const float* C_re       = (const float*)d_in[4];
  const float* C_im       = (const float*)d_in[5];
  const float* log_A_real = (const float*)d_in[6];
  const float* A_imag     = (const float*)d_in[7];
  const float* D_skip     = (const float*)d_in[8];
  const float* w_out      = (const float*)d_in[9];
  const float* b_out      = (const float*)d_in[10];
  const float* ln_g       = (const float*)d_in[11];
  const float* ln_b       = (const float*)d_in[12];
  const float* dw1        = (const float*)d_in[13];
  const float* db1        = (const float*)d_in[14];
  const float* dw2        = (const float*)d_in[15];
  const float* db2        = (const float*)d_in[16];
  const float* dw3        = (const float*)d_in[17];
  const float* db3        = (const float*)d_in[18];

  char* ws = (char*)d_ws;
  float* hbuf = (float*)ws;                                  // 33,554,432 B
  float4* sF = (float4*)(ws + 33554432);                     // 33,554,432 B
  unsigned short* wbf = (unsigned short*)(ws + 67108864);    //  1,048,576 B
  float* par = (float*)(ws + 68157440);                      //  1,048,576 B
  float* pooledPart = (float*)(ws + 69206016);               //    524,288 B

  k_encoder<<<512, 256, 0, stream>>>(x, enc_w, enc_b, hbuf);
  k_cvtw<<<2048, 256, 0, stream>>>(w_out, wbf, NL * 512 * H_SZ);
  k_params<<<128, 256, 0, stream>>>(log_dt, log_A_real, A_imag, C_re, C_im, par);
  const size_t PAR_STRIDE = (size_t)H_SZ * NH * 8;
  for (int i = 0; i < NL; ++i) {
    const float* pari = par + i * PAR_STRIDE;
    k_scan_local<<<2048, 256, 0, stream>>>(hbuf, sF, pari);
    k_prefix<<<64, 256, 0, stream>>>(sF, pari);
    k_layer<<<512, 1024, 0, stream>>>(hbuf, sF, pari,
                                      D_skip + i * H_SZ, wbf + i * 512 * H_SZ,
                                      b_out + i * 512, ln_g + i * H_SZ, ln_b + i * H_SZ,
                                      pooledPart, (i == NL - 1) ? 1 : 0);
  }
  k_decoder<<<1, 256, 0, stream>>>(pooledPart, dw1, db1, dw2, db2, dw3, db3, (float*)d_out);
}

// Round 8
// 603.257 us; speedup vs baseline: 1.7353x; 1.2417x over previous
//
#include <hip/hip_runtime.h>

#define B_SZ 16
#define L_SZ 2048
#define DIN 64
#define H_SZ 256
#define NH 32
#define NL 4
#define TC 64
#define NTC 32

typedef __attribute__((ext_vector_type(8))) __bf16 bf16x8;
typedef __attribute__((ext_vector_type(4))) float f32x4;

__device__ __forceinline__ unsigned short f2b(float f) {
  unsigned int u = __builtin_bit_cast(unsigned int, f);
  unsigned int r = u + 0x7fffu + ((u >> 16) & 1u);  // RNE (no NaN inputs here)
  return (unsigned short)(r >> 16);
}
__device__ __forceinline__ float b2f(unsigned short u) {
  unsigned int v = ((unsigned int)u) << 16;
  return __builtin_bit_cast(float, v);
}
__device__ __forceinline__ float gelu_exact(float v) {
  return 0.5f * v * (1.f + erff(v * 0.70710678118654752f));
}

// ---------------- encoder: h[b][hh][l] = x[b][l][:] @ enc_w[:,hh] + enc_b ----------------
__global__ void k_encoder(const float* __restrict__ x, const float* __restrict__ w,
                          const float* __restrict__ bias, float* __restrict__ hbuf) {
  __shared__ float wlds[DIN * H_SZ];  // 64 KB
  int tid = threadIdx.x;
  for (int i = tid; i < DIN * H_SZ; i += 256) wlds[i] = w[i];
  int blk = blockIdx.x;            // 512 blocks: b(16) x q(4) x ltile(8)
  int b = blk >> 5;
  int q = (blk >> 3) & 3;
  int l = ((blk & 7) << 8) + tid;
  float xr[DIN];
  const float4* xp = (const float4*)(x + (size_t)(b * L_SZ + l) * DIN);
#pragma unroll
  for (int d4 = 0; d4 < 16; ++d4) {
    float4 v = xp[d4];
    xr[d4 * 4 + 0] = v.x; xr[d4 * 4 + 1] = v.y; xr[d4 * 4 + 2] = v.z; xr[d4 * 4 + 3] = v.w;
  }
  __syncthreads();
  for (int i = 0; i < 64; ++i) {
    int hh = (q << 6) + i;
    float acc = bias[hh];
#pragma unroll
    for (int d = 0; d < DIN; ++d) acc = fmaf(xr[d], wlds[d * H_SZ + hh], acc);
    hbuf[(b * H_SZ + hh) * L_SZ + l] = acc;
  }
}

// ---------------- convert w_out to bf16 ----------------
__global__ void k_cvtw(const float* __restrict__ w, unsigned short* __restrict__ wbf, int n) {
  int i = blockIdx.x * 256 + threadIdx.x;
  if (i < n) wbf[i] = f2b(w[i]);
}

// ---------------- precompute per-state params: lr, li, c2r, c2i, lTr, lTi ----------------
__global__ void k_params(const float* __restrict__ log_dt, const float* __restrict__ log_A_real,
                         const float* __restrict__ A_imag, const float* __restrict__ C_re,
                         const float* __restrict__ C_im, float* __restrict__ par) {
  int id = blockIdx.x * 256 + threadIdx.x;  // i*8192 + h*32 + n
  if (id >= NL * H_SZ * NH) return;
  int i = id >> 13;
  int hn = id & 8191;
  int h = hn >> 5;
  float dt = expf(log_dt[i * H_SZ + h]);
  float Ar = -expf(log_A_real[(size_t)i * H_SZ * NH + hn]);
  float Ai = A_imag[(size_t)i * H_SZ * NH + hn];
  float dr = dt * Ar, di = dt * Ai;
  float e = expf(dr), sn, cs;
  sincosf(di, &sn, &cs);
  float lr = e * cs, li = e * sn;
  float eT = expf((float)TC * dr), snT, csT;
  sincosf((float)TC * di, &snT, &csT);
  float Cr = C_re[(size_t)i * H_SZ * NH + hn], Ci = C_im[(size_t)i * H_SZ * NH + hn];
  float wr = lr - 1.f, wi = li;
  float pr = Cr * wr - Ci * wi;
  float pi = Cr * wi + Ci * wr;
  float inv = 2.f / fmaf(Ar, Ar, Ai * Ai);
  float4* p = (float4*)(par + (size_t)id * 8);
  p[0] = make_float4(lr, li, (pr * Ar + pi * Ai) * inv, (pi * Ar - pr * Ai) * inv);
  p[1] = make_float4(eT * csT, eT * snT, 0.f, 0.f);
}

// ---------------- local chunk scan + in-LDS exclusive prefix -> carries to sF ----------------
// block = (b, group of 8 h); threads = (c:32, hsub:8, ng:4); sF gets EXCLUSIVE carries.
__launch_bounds__(1024, 4)
__global__ void k_scan(const float* __restrict__ hbuf, float2* __restrict__ sF2,
                       const float* __restrict__ par) {
  __shared__ float fre[NTC][8][NH];  // 32 KB
  __shared__ float fim[NTC][8][NH];  // 32 KB
  int tid = threadIdx.x;
  int b = blockIdx.x >> 5;
  int hg = blockIdx.x & 31;
  int c = tid >> 5;
  int hsub = (tid >> 2) & 7;
  int ng = tid & 3;
  int h = (hg << 3) + hsub;
  // ---- local chunk scan (proven loop) ----
  {
    float lr[8], li[8], sre[8], sim[8];
    const float4* pp = (const float4*)(par + (size_t)(h * NH + ng * 8) * 8);
#pragma unroll
    for (int k = 0; k < 8; ++k) {
      float4 p0 = pp[k * 2];
      lr[k] = p0.x; li[k] = p0.y;
      sre[k] = 0.f; sim[k] = 0.f;
    }
    const float* xp = hbuf + (b * H_SZ + h) * L_SZ + c * TC;
    float4 xv = *(const float4*)xp;
    for (int j4 = 0; j4 < TC; j4 += 4) {
      float4 xn = xv;
      if (j4 + 4 < TC) xn = *(const float4*)(xp + j4 + 4);
      float xe[4] = {xv.x, xv.y, xv.z, xv.w};
#pragma unroll
      for (int e = 0; e < 4; ++e) {
        float xj = xe[e];
#pragma unroll
        for (int k = 0; k < 8; ++k) {
          float nr = fmaf(lr[k], sre[k], xj);
          nr = fmaf(-li[k], sim[k], nr);
          float ni = lr[k] * sim[k];
          ni = fmaf(li[k], sre[k], ni);
          sre[k] = nr; sim[k] = ni;
        }
      }
      xv = xn;
    }
#pragma unroll
    for (int k = 0; k < 8; ++k) {
      fre[c][hsub][ng * 8 + k] = sre[k];
      fim[c][hsub][ng * 8 + k] = sim[k];
    }
  }
  __syncthreads();
  // ---- exclusive prefix in LDS (256 threads: one (h, state) each) ----
  if (tid < 256) {
    int hs2 = tid >> 5, n = tid & 31;
    int h2 = (hg << 3) + hs2;
    const float* pb = par + (size_t)(h2 * NH + n) * 8;
    float lTr = pb[4], lTi = pb[5];
    float cr = 0.f, ci = 0.f;
    float2* out = sF2 + ((size_t)(b << 5) * H_SZ + h2) * NH + n;
    for (int cc = 0; cc < NTC; ++cc) {
      float fr = fre[cc][hs2][n], fi = fim[cc][hs2][n];
      out[(size_t)cc * H_SZ * NH] = make_float2(cr, ci);
      float nr = fmaf(lTr, cr, fr); nr = fmaf(-lTi, ci, nr);
      float ni = fmaf(lTr, ci, fi); ni = fmaf(lTi, cr, ni);
      cr = nr; ci = ni;
    }
  }
}

// ---------------- fused per-layer kernel: carry load + recurrence + gelu + GLU + LN ----------------
__launch_bounds__(1024, 4)
__global__ void k_layer(float* __restrict__ hbuf, const float4* __restrict__ sFin,
                        const float* __restrict__ par,
                        const float* __restrict__ D_skip,
                        const unsigned short* __restrict__ wbf,
                        const float* __restrict__ b_out,
                        const float* __restrict__ ln_g, const float* __restrict__ ln_b,
                        float* __restrict__ pooledPart, int last) {
  __shared__ __align__(16) unsigned short yt[TC][H_SZ + 8];  // 33792 B
  __shared__ float part[TC][16][2];                          // 8192 B
  __shared__ float stats[TC][2];                             // 512 B
  int tid = threadIdx.x;
  int b = blockIdx.x >> 5;
  int c = blockIdx.x & 31;
  int l0 = c << 6;

  // ---- phase 1: recurrence from precomputed carry; y + D*x -> LDS (bf16) ----
  {
    int h = tid >> 2, ng = tid & 3;
    const float4* pp = (const float4*)(par + (size_t)(h * NH + ng * 8) * 8);
    float lr[8], li[8], c2r[8], c2i[8], sre[8], sim[8];
    const float4* fp = sFin + (((size_t)((b << 5) + c) * H_SZ + h) * 4 + ng) * 4;
#pragma unroll
    for (int q = 0; q < 4; ++q) {
      float4 f = fp[q];
      sre[2 * q] = f.x; sim[2 * q] = f.y;
      sre[2 * q + 1] = f.z; sim[2 * q + 1] = f.w;
    }
#pragma unroll
    for (int k = 0; k < 8; ++k) {
      float4 p0 = pp[k * 2];
      lr[k] = p0.x; li[k] = p0.y; c2r[k] = p0.z; c2i[k] = p0.w;
    }
    float Dh = D_skip[h];
    const float* xp = hbuf + (b * H_SZ + h) * L_SZ + l0;
    float4 xv = *(const float4*)xp;
    for (int j4 = 0; j4 < TC; j4 += 4) {
      float4 xn = xv;
      if (j4 + 4 < TC) xn = *(const float4*)(xp + j4 + 4);
      float xe[4] = {xv.x, xv.y, xv.z, xv.w};
#pragma unroll
      for (int e = 0; e < 4; ++e) {
        float xj = xe[e];
        float yp0 = 0.f, yp1 = 0.f;
#pragma unroll
        for (int k = 0; k < 8; ++k) {
          float nr = fmaf(lr[k], sre[k], xj);
          nr = fmaf(-li[k], sim[k], nr);
          float ni = lr[k] * sim[k];
          ni = fmaf(li[k], sre[k], ni);
          sre[k] = nr; sim[k] = ni;
          if (k & 1) {
            yp1 = fmaf(c2r[k], nr, yp1);
            yp1 = fmaf(-c2i[k], ni, yp1);
          } else {
            yp0 = fmaf(c2r[k], nr, yp0);
            yp0 = fmaf(-c2i[k], ni, yp0);
          }
        }
        float yp = yp0 + yp1;
        yp += __shfl_xor(yp, 1);
        yp += __shfl_xor(yp, 2);
        if (ng == 0) yt[j4 + e][h] = f2b(fmaf(Dh, xj, yp));
      }
      xv = xn;
    }
  }
  __syncthreads();
  // ---- phase 2: exact GELU in place (packed pairs) ----
  for (int it = 0; it < 8; ++it) {
    int id = it * 1024 + tid;
    int jr = id >> 7, hp = id & 127;
    unsigned int u = *(unsigned int*)&yt[jr][hp * 2];
    float v0 = b2f((unsigned short)(u & 0xffff));
    float v1 = b2f((unsigned short)(u >> 16));
    v0 = gelu_exact(v0);
    v1 = gelu_exact(v1);
    *(unsigned int*)&yt[jr][hp * 2] = (unsigned int)f2b(v0) | ((unsigned int)f2b(v1) << 16);
  }
  __syncthreads();
  // ---- phase 3: 1x1 conv (512x256 @ 256x64) via MFMA + GLU; z -> LDS ----
  {
    int w = tid >> 6, lane = tid & 63;
    int lrow = lane & 15, lk8 = (lane >> 4) << 3;
    f32x4 accA[4], accG[4];
    f32x4 zed = {0.f, 0.f, 0.f, 0.f};
#pragma unroll
    for (int jt = 0; jt < 4; ++jt) { accA[jt] = zed; accG[jt] = zed; }
    const unsigned short* wA = wbf + ((w << 4) + lrow) * H_SZ;
    const unsigned short* wG = wA + 256 * H_SZ;
#pragma unroll
    for (int k0 = 0; k0 < H_SZ; k0 += 32) {
      bf16x8 a0 = *(const bf16x8*)(wA + k0 + lk8);
      bf16x8 a1 = *(const bf16x8*)(wG + k0 + lk8);
#pragma unroll
      for (int jt = 0; jt < 4; ++jt) {
        bf16x8 bb = *(const bf16x8*)(&yt[(jt << 4) + lrow][k0 + lk8]);
        accA[jt] = __builtin_amdgcn_mfma_f32_16x16x32_bf16(a0, bb, accA[jt], 0, 0, 0);
        accG[jt] = __builtin_amdgcn_mfma_f32_16x16x32_bf16(a1, bb, accG[jt], 0, 0, 0);
      }
    }
    __syncthreads();  // all y reads done before overwrite with z
    int rbase = (lane >> 4) << 2;
    float bA[4], bG[4];
#pragma unroll
    for (int r = 0; r < 4; ++r) {
      bA[r] = b_out[(w << 4) + rbase + r];
      bG[r] = b_out[256 + (w << 4) + rbase + r];
    }
#pragma unroll
    for (int jt = 0; jt < 4; ++jt) {
#pragma unroll
      for (int r = 0; r < 4; ++r) {
        float a = accA[jt][r] + bA[r];
        float g = accG[jt][r] + bG[r];
        float z = a / (1.f + expf(-g));
        yt[(jt << 4) + lrow][(w << 4) + rbase + r] = f2b(z);
      }
    }
  }
  __syncthreads();
  // ---- phase 4: LN stats over H; v = z + residual ----
  int j = tid & 63, hg = tid >> 6;  // 16 groups of 16 h
  float vreg[16];
  {
    const float* xc = hbuf + (b * H_SZ + (hg << 4)) * L_SZ + l0 + j;
    float s = 0.f, sq = 0.f;
#pragma unroll
    for (int k = 0; k < 16; ++k) {
      float v = b2f(yt[j][(hg << 4) + k]) + xc[(size_t)k * L_SZ];
      vreg[k] = v;
      s += v; sq = fmaf(v, v, sq);
    }
    part[j][hg][0] = s; part[j][hg][1] = sq;
  }
  __syncthreads();
  if (tid < TC) {
    float s = 0.f, sq = 0.f;
#pragma unroll
    for (int g = 0; g < 16; ++g) { s += part[tid][g][0]; sq += part[tid][g][1]; }
    float mu = s * (1.f / 256.f);
    float var = sq * (1.f / 256.f) - mu * mu;
    stats[tid][0] = mu;
    stats[tid][1] = rsqrtf(var + 1e-5f);
  }
  __syncthreads();
  // ---- phase 5: normalized residual; write hbuf OR pool partials (last) ----
  {
    float mu = stats[j][0], rs = stats[j][1];
    if (!last) {
      float* xo = hbuf + (b * H_SZ + (hg << 4)) * L_SZ + l0 + j;
#pragma unroll
      for (int k = 0; k < 16; ++k) {
        int hh = (hg << 4) + k;
        xo[(size_t)k * L_SZ] = (vreg[k] - mu) * rs * ln_g[hh] + ln_b[hh];
      }
    } else {
#pragma unroll
      for (int k = 0; k < 16; ++k) {
        int hh = (hg << 4) + k;
        yt[j][hh] = f2b((vreg[k] - mu) * rs * ln_g[hh] + ln_b[hh]);
      }
      __syncthreads();
      if (tid < H_SZ) {
        float s = 0.f;
        for (int jj = 0; jj < TC; ++jj) s += b2f(yt[jj][tid]);
        pooledPart[(((b << 5) + c) << 8) + tid] = s;
      }
    }
  }
}

// ---------------- decoder MLP (single block) with pooling preamble ----------------
__global__ void k_decoder(const float* __restrict__ pooledPart,
                          const float* __restrict__ w1, const float* __restrict__ b1,
                          const float* __restrict__ w2, const float* __restrict__ b2,
                          const float* __restrict__ w3, const float* __restrict__ b3,
                          float* __restrict__ out) {
  __shared__ float P[16 * 256];
  __shared__ float O1[16 * 128];
  __shared__ float O2[16 * 64];
  int tid = threadIdx.x;
  for (int id = tid; id < 16 * 256; id += 256) {
    int b = id >> 8, hh = id & 255;
    float s = 0.f;
#pragma unroll
    for (int cpart = 0; cpart < 32; ++cpart)
      s += pooledPart[(((b << 5) + cpart) << 8) + hh];
    P[id] = s * (1.f / 2048.f);
  }
  __syncthreads();
  for (int id = tid; id < 16 * 128; id += 256) {
    int r = id >> 7, cc = id & 127;
    float acc = b1[cc];
    for (int d = 0; d < 256; ++d) acc = fmaf(P[(r << 8) + d], w1[(d << 7) + cc], acc);
    O1[id] = fmaxf(acc, 0.f);
  }
  __syncthreads();
  for (int id = tid; id < 16 * 64; id += 256) {
    int r = id >> 6, cc = id & 63;
    float acc = b2[cc];
    for (int d = 0; d < 128; ++d) acc = fmaf(O1[(r << 7) + d], w2[(d << 6) + cc], acc);
    O2[id] = fmaxf(acc, 0.f);
  }
  __syncthreads();
  for (int id = tid; id < 16 * 32; id += 256) {
    int r = id >> 5, cc = id & 31;
    float acc = b3[cc];
    for (int d = 0; d < 64; ++d) acc = fmaf(O2[(r << 6) + d], w3[(d << 5) + cc], acc);
    out[id] = acc;
  }
}

extern "C" void kernel_launch(void* const* d_in, const int* in_sizes, int n_in,
                              void* d_out, int out_size, void* d_ws, size_t ws_size,
                              hipStream_t stream) {
  const float* x          = (const float*)d_in[0];
  const float* enc_w      = (const float*)d_in[1];
  const float* enc_b      = (const float*)d_in[2];
  const float* log_dt     = (const float*)d_in[3];
  const float* C_re       = (const float*)d_in[4];
  const float* C_im       = (const float*)d_in[5];
  const float* log_A_real = (const float*)d_in[6];
  const float* A_imag     = (const float*)d_in[7];
  const float* D_skip     = (const float*)d_in[8];
  const float* w_out      = (const float*)d_in[9];
  const float* b_out      = (const float*)d_in[10];
  const float* ln_g       = (const float*)d_in[11];
  const float* ln_b       = (const float*)d_in[12];
  const float* dw1        = (const float*)d_in[13];
  const float* db1        = (const float*)d_in[14];
  const float* dw2        = (const float*)d_in[15];
  const float* db2        = (const float*)d_in[16];
  const float* dw3        = (const float*)d_in[17];
  const float* db3        = (const float*)d_in[18];

  char* ws = (char*)d_ws;
  float* hbuf = (float*)ws;                                  // 33,554,432 B
  float2* sF2 = (float2*)(ws + 33554432);                    // 33,554,432 B (carries)
  unsigned short* wbf = (unsigned short*)(ws + 67108864);    //  1,048,576 B
  float* par = (float*)(ws + 68157440);                      //  1,048,576 B
  float* pooledPart = (float*)(ws + 69206016);               //    524,288 B

  k_encoder<<<512, 256, 0, stream>>>(x, enc_w, enc_b, hbuf);
  k_cvtw<<<2048, 256, 0, stream>>>(w_out, wbf, NL * 512 * H_SZ);
  k_params<<<128, 256, 0, stream>>>(log_dt, log_A_real, A_imag, C_re, C_im, par);
  const size_t PAR_STRIDE = (size_t)H_SZ * NH * 8;
  for (int i = 0; i < NL; ++i) {
    const float* pari = par + i * PAR_STRIDE;
    k_scan<<<512, 1024, 0, stream>>>(hbuf, sF2, pari);
    k_layer<<<512, 1024, 0, stream>>>(hbuf, (const float4*)sF2, pari,
                                      D_skip + i * H_SZ, wbf + i * 512 * H_SZ,
                                      b_out + i * 512, ln_g + i * H_SZ, ln_b + i * H_SZ,
                                      pooledPart, (i == NL - 1) ? 1 : 0);
  }
  k_decoder<<<1, 256, 0, stream>>>(pooledPart, dw1, db1, dw2, db2, dw3, db3, (float*)d_out);
}

// Round 9
// 592.395 us; speedup vs baseline: 1.7671x; 1.0183x over previous
//
#include <hip/hip_runtime.h>

#define B_SZ 16
#define L_SZ 2048
#define DIN 64
#define H_SZ 256
#define NH 32
#define NL 4
#define TC 64
#define NTC 32

typedef __attribute__((ext_vector_type(8))) __bf16 bf16x8;
typedef __attribute__((ext_vector_type(4))) float f32x4;

__device__ __forceinline__ unsigned short f2b(float f) {
  unsigned int u = __builtin_bit_cast(unsigned int, f);
  unsigned int r = u + 0x7fffu + ((u >> 16) & 1u);  // RNE (no NaN inputs here)
  return (unsigned short)(r >> 16);
}
__device__ __forceinline__ float b2f(unsigned short u) {
  unsigned int v = ((unsigned int)u) << 16;
  return __builtin_bit_cast(float, v);
}
__device__ __forceinline__ float gelu_exact(float v) {
  return 0.5f * v * (1.f + erff(v * 0.70710678118654752f));
}

// ---------------- encoder: h[b][hh][l] = x[b][l][:] @ enc_w[:,hh] + enc_b ----------------
__global__ void k_encoder(const float* __restrict__ x, const float* __restrict__ w,
                          const float* __restrict__ bias, float* __restrict__ hbuf) {
  __shared__ float wlds[DIN * H_SZ];  // 64 KB
  int tid = threadIdx.x;
  for (int i = tid; i < DIN * H_SZ; i += 256) wlds[i] = w[i];
  int blk = blockIdx.x;            // 512 blocks: b(16) x q(4) x ltile(8)
  int b = blk >> 5;
  int q = (blk >> 3) & 3;
  int l = ((blk & 7) << 8) + tid;
  float xr[DIN];
  const float4* xp = (const float4*)(x + (size_t)(b * L_SZ + l) * DIN);
#pragma unroll
  for (int d4 = 0; d4 < 16; ++d4) {
    float4 v = xp[d4];
    xr[d4 * 4 + 0] = v.x; xr[d4 * 4 + 1] = v.y; xr[d4 * 4 + 2] = v.z; xr[d4 * 4 + 3] = v.w;
  }
  __syncthreads();
  for (int i = 0; i < 64; ++i) {
    int hh = (q << 6) + i;
    float acc = bias[hh];
#pragma unroll
    for (int d = 0; d < DIN; ++d) acc = fmaf(xr[d], wlds[d * H_SZ + hh], acc);
    hbuf[(b * H_SZ + hh) * L_SZ + l] = acc;
  }
}

// ---------------- convert w_out to bf16 ----------------
__global__ void k_cvtw(const float* __restrict__ w, unsigned short* __restrict__ wbf, int n) {
  int i = blockIdx.x * 256 + threadIdx.x;
  if (i < n) wbf[i] = f2b(w[i]);
}

// ---------------- precompute per-state params: lr, li, c2r, c2i, lTr, lTi ----------------
__global__ void k_params(const float* __restrict__ log_dt, const float* __restrict__ log_A_real,
                         const float* __restrict__ A_imag, const float* __restrict__ C_re,
                         const float* __restrict__ C_im, float* __restrict__ par) {
  int id = blockIdx.x * 256 + threadIdx.x;  // i*8192 + h*32 + n
  if (id >= NL * H_SZ * NH) return;
  int i = id >> 13;
  int hn = id & 8191;
  int h = hn >> 5;
  float dt = expf(log_dt[i * H_SZ + h]);
  float Ar = -expf(log_A_real[(size_t)i * H_SZ * NH + hn]);
  float Ai = A_imag[(size_t)i * H_SZ * NH + hn];
  float dr = dt * Ar, di = dt * Ai;
  float e = expf(dr), sn, cs;
  sincosf(di, &sn, &cs);
  float lr = e * cs, li = e * sn;
  float eT = expf((float)TC * dr), snT, csT;
  sincosf((float)TC * di, &snT, &csT);
  float Cr = C_re[(size_t)i * H_SZ * NH + hn], Ci = C_im[(size_t)i * H_SZ * NH + hn];
  float wr = lr - 1.f, wi = li;
  float pr = Cr * wr - Ci * wi;
  float pi = Cr * wi + Ci * wr;
  float inv = 2.f / fmaf(Ar, Ar, Ai * Ai);
  float4* p = (float4*)(par + (size_t)id * 8);
  p[0] = make_float4(lr, li, (pr * Ar + pi * Ai) * inv, (pi * Ar - pr * Ai) * inv);
  p[1] = make_float4(eT * csT, eT * snT, 0.f, 0.f);
}

// ---------------- chunk finals via compensated MFMA Vandermonde GEMM + in-kernel prefix ----
// block = one h (256 blocks, 512 threads). finals = U_h @ x_h; then exclusive prefix -> sF2.
__launch_bounds__(512, 1)
__global__ void k_scanM(const float* __restrict__ hbuf, float2* __restrict__ sF2,
                        const float* __restrict__ par) {
  __shared__ __align__(16) unsigned short xbh[256][72];  // 36864 B (x hi, [col][j])
  __shared__ __align__(16) unsigned short xbl[256][72];  // 36864 B (x lo)
  __shared__ __align__(16) unsigned short Uh[64][72];    //  9216 B (U hi, [row][j])
  __shared__ __align__(16) unsigned short Ul[64][72];    //  9216 B (U lo)
  int tid = threadIdx.x;
  int h = blockIdx.x;

  // ---- build U: row 2n = Re(lam_n^{63-j}), row 2n+1 = Im; hi/lo split ----
  if (tid < 64) {
    int n = tid >> 1, q = tid & 1;
    const float* pb = par + (size_t)(h * NH + n) * 8;
    float lr = pb[0], li = pb[1];
    float pr = 1.f, pi = 0.f;
    if (q) {  // lam^32 via 5 squarings
      float sr = lr, si = li;
#pragma unroll
      for (int t = 0; t < 5; ++t) { float nr2 = sr * sr - si * si; si = 2.f * sr * si; sr = nr2; }
      pr = sr; pi = si;
    }
    int p = q << 5;
    for (int s = 0; s < 32; ++s, ++p) {
      int col = 63 - p;
      unsigned short hr = f2b(pr);
      Uh[2 * n][col] = hr; Ul[2 * n][col] = f2b(pr - b2f(hr));
      unsigned short hm = f2b(pi);
      Uh[2 * n + 1][col] = hm; Ul[2 * n + 1][col] = f2b(pi - b2f(hm));
      float nr2 = pr * lr - pi * li;
      pi = pr * li + pi * lr;
      pr = nr2;
    }
  }

  int wv = tid >> 6, lane = tid & 63;
  int lrow = lane & 15, lk8 = (lane >> 4) << 3;
  int rt = wv >> 1;          // row-tile 0..3 (rows rt*16..+15)
  int ct0 = (wv & 1) << 3;   // col-tile base (8 tiles per wave)

  for (int half = 0; half < 2; ++half) {
    __syncthreads();  // U ready / previous half's GEMM reads done
    // ---- stage x hi/lo: cols = (b-b0)*32 + c, 256 cols of 64 j ----
    {
      int colh = tid >> 1, j0 = (tid & 1) << 5;
      int b = (half << 3) + (colh >> 5), c = colh & 31;
      const float* src = hbuf + ((size_t)(b * H_SZ + h) << 11) + (c << 6) + j0;
      unsigned short* dh = &xbh[colh][j0];
      unsigned short* dl = &xbl[colh][j0];
#pragma unroll
      for (int jj = 0; jj < 8; ++jj) {
        float4 v = *(const float4*)(src + jj * 4);
        unsigned short h0 = f2b(v.x); dh[jj * 4 + 0] = h0; dl[jj * 4 + 0] = f2b(v.x - b2f(h0));
        unsigned short h1 = f2b(v.y); dh[jj * 4 + 1] = h1; dl[jj * 4 + 1] = f2b(v.y - b2f(h1));
        unsigned short h2 = f2b(v.z); dh[jj * 4 + 2] = h2; dl[jj * 4 + 2] = f2b(v.z - b2f(h2));
        unsigned short h3 = f2b(v.w); dh[jj * 4 + 3] = h3; dl[jj * 4 + 3] = f2b(v.w - b2f(h3));
      }
    }
    __syncthreads();
    // ---- compensated GEMM: acc += Uhi@xhi + Uhi@xlo + Ulo@xhi ----
    f32x4 acc[8];
#pragma unroll
    for (int ct = 0; ct < 8; ++ct) acc[ct] = (f32x4){0.f, 0.f, 0.f, 0.f};
#pragma unroll
    for (int kk = 0; kk < 2; ++kk) {
      bf16x8 ah = *(const bf16x8*)&Uh[(rt << 4) + lrow][(kk << 5) + lk8];
      bf16x8 al = *(const bf16x8*)&Ul[(rt << 4) + lrow][(kk << 5) + lk8];
#pragma unroll
      for (int ct = 0; ct < 8; ++ct) {
        int colh = ((ct0 + ct) << 4) + lrow;
        bf16x8 bh = *(const bf16x8*)&xbh[colh][(kk << 5) + lk8];
        bf16x8 bl = *(const bf16x8*)&xbl[colh][(kk << 5) + lk8];
        acc[ct] = __builtin_amdgcn_mfma_f32_16x16x32_bf16(ah, bh, acc[ct], 0, 0, 0);
        acc[ct] = __builtin_amdgcn_mfma_f32_16x16x32_bf16(ah, bl, acc[ct], 0, 0, 0);
        acc[ct] = __builtin_amdgcn_mfma_f32_16x16x32_bf16(al, bh, acc[ct], 0, 0, 0);
      }
    }
    // ---- write finals (f32) to sF2: rows (re,im) pairs -> states ----
    {
      int n0 = (rt << 3) + ((lane >> 4) << 1);  // (rt*16 + rsub)/2
#pragma unroll
      for (int ct = 0; ct < 8; ++ct) {
        int colg = (half << 8) + ((ct0 + ct) << 4) + lrow;  // = b*32 + c
        float2* o = sF2 + (size_t)colg * (H_SZ * NH) + h * NH + n0;
        o[0] = make_float2(acc[ct][0], acc[ct][1]);
        o[1] = make_float2(acc[ct][2], acc[ct][3]);
      }
    }
  }
  __syncthreads();  // finals visible block-wide (global RAW within block)
  // ---- exclusive prefix over c (in place, f32 exact), thread = (b, n) ----
  {
    int b = tid >> 5, n = tid & 31;
    const float* pb = par + (size_t)(h * NH + n) * 8;
    float lTr = pb[4], lTi = pb[5];
    float cr = 0.f, ci = 0.f;
    float2* p0 = sF2 + (size_t)(b << 5) * (H_SZ * NH) + h * NH + n;
    const size_t cstride = H_SZ * NH;
    float2 f = p0[0];
    for (int c = 0; c < NTC; ++c) {
      float2 fn = f;
      if (c + 1 < NTC) fn = p0[(size_t)(c + 1) * cstride];
      p0[(size_t)c * cstride] = make_float2(cr, ci);
      float nr = fmaf(lTr, cr, f.x); nr = fmaf(-lTi, ci, nr);
      float ni = fmaf(lTr, ci, f.y); ni = fmaf(lTi, cr, ni);
      cr = nr; ci = ni;
      f = fn;
    }
  }
}

// ---------------- fused per-layer kernel: carry load + recurrence + gelu + GLU + LN ----------------
__launch_bounds__(1024, 4)
__global__ void k_layer(float* __restrict__ hbuf, const float4* __restrict__ sFin,
                        const float* __restrict__ par,
                        const float* __restrict__ D_skip,
                        const unsigned short* __restrict__ wbf,
                        const float* __restrict__ b_out,
                        const float* __restrict__ ln_g, const float* __restrict__ ln_b,
                        float* __restrict__ pooledPart, int last) {
  __shared__ __align__(16) unsigned short yt[TC][H_SZ + 8];  // 33792 B
  __shared__ float part[TC][16][2];                          // 8192 B
  __shared__ float stats[TC][2];                             // 512 B
  int tid = threadIdx.x;
  int b = blockIdx.x >> 5;
  int c = blockIdx.x & 31;
  int l0 = c << 6;

  // ---- phase 1: recurrence from precomputed carry; y + D*x -> LDS (bf16) ----
  {
    int h = tid >> 2, ng = tid & 3;
    const float4* pp = (const float4*)(par + (size_t)(h * NH + ng * 8) * 8);
    float lr[8], li[8], c2r[8], c2i[8], sre[8], sim[8];
    const float4* fp = sFin + (((size_t)((b << 5) + c) * H_SZ + h) * 4 + ng) * 4;
#pragma unroll
    for (int q = 0; q < 4; ++q) {
      float4 f = fp[q];
      sre[2 * q] = f.x; sim[2 * q] = f.y;
      sre[2 * q + 1] = f.z; sim[2 * q + 1] = f.w;
    }
#pragma unroll
    for (int k = 0; k < 8; ++k) {
      float4 p0 = pp[k * 2];
      lr[k] = p0.x; li[k] = p0.y; c2r[k] = p0.z; c2i[k] = p0.w;
    }
    float Dh = D_skip[h];
    const float* xp = hbuf + (b * H_SZ + h) * L_SZ + l0;
    float4 xv = *(const float4*)xp;
    for (int j4 = 0; j4 < TC; j4 += 4) {
      float4 xn = xv;
      if (j4 + 4 < TC) xn = *(const float4*)(xp + j4 + 4);
      float xe[4] = {xv.x, xv.y, xv.z, xv.w};
#pragma unroll
      for (int e = 0; e < 4; ++e) {
        float xj = xe[e];
        float yp0 = 0.f, yp1 = 0.f;
#pragma unroll
        for (int k = 0; k < 8; ++k) {
          float nr = fmaf(lr[k], sre[k], xj);
          nr = fmaf(-li[k], sim[k], nr);
          float ni = lr[k] * sim[k];
          ni = fmaf(li[k], sre[k], ni);
          sre[k] = nr; sim[k] = ni;
          if (k & 1) {
            yp1 = fmaf(c2r[k], nr, yp1);
            yp1 = fmaf(-c2i[k], ni, yp1);
          } else {
            yp0 = fmaf(c2r[k], nr, yp0);
            yp0 = fmaf(-c2i[k], ni, yp0);
          }
        }
        float yp = yp0 + yp1;
        yp += __shfl_xor(yp, 1);
        yp += __shfl_xor(yp, 2);
        if (ng == 0) yt[j4 + e][h] = f2b(fmaf(Dh, xj, yp));
      }
      xv = xn;
    }
  }
  __syncthreads();
  // ---- phase 2: exact GELU in place (packed pairs) ----
  for (int it = 0; it < 8; ++it) {
    int id = it * 1024 + tid;
    int jr = id >> 7, hp = id & 127;
    unsigned int u = *(unsigned int*)&yt[jr][hp * 2];
    float v0 = b2f((unsigned short)(u & 0xffff));
    float v1 = b2f((unsigned short)(u >> 16));
    v0 = gelu_exact(v0);
    v1 = gelu_exact(v1);
    *(unsigned int*)&yt[jr][hp * 2] = (unsigned int)f2b(v0) | ((unsigned int)f2b(v1) << 16);
  }
  __syncthreads();
  // ---- phase 3: 1x1 conv (512x256 @ 256x64) via MFMA + GLU; z -> LDS ----
  {
    int w = tid >> 6, lane = tid & 63;
    int lrow = lane & 15, lk8 = (lane >> 4) << 3;
    f32x4 accA[4], accG[4];
    f32x4 zed = {0.f, 0.f, 0.f, 0.f};
#pragma unroll
    for (int jt = 0; jt < 4; ++jt) { accA[jt] = zed; accG[jt] = zed; }
    const unsigned short* wA = wbf + ((w << 4) + lrow) * H_SZ;
    const unsigned short* wG = wA + 256 * H_SZ;
#pragma unroll
    for (int k0 = 0; k0 < H_SZ; k0 += 32) {
      bf16x8 a0 = *(const bf16x8*)(wA + k0 + lk8);
      bf16x8 a1 = *(const bf16x8*)(wG + k0 + lk8);
#pragma unroll
      for (int jt = 0; jt < 4; ++jt) {
        bf16x8 bb = *(const bf16x8*)(&yt[(jt << 4) + lrow][k0 + lk8]);
        accA[jt] = __builtin_amdgcn_mfma_f32_16x16x32_bf16(a0, bb, accA[jt], 0, 0, 0);
        accG[jt] = __builtin_amdgcn_mfma_f32_16x16x32_bf16(a1, bb, accG[jt], 0, 0, 0);
      }
    }
    __syncthreads();  // all y reads done before overwrite with z
    int rbase = (lane >> 4) << 2;
    float bA[4], bG[4];
#pragma unroll
    for (int r = 0; r < 4; ++r) {
      bA[r] = b_out[(w << 4) + rbase + r];
      bG[r] = b_out[256 + (w << 4) + rbase + r];
    }
#pragma unroll
    for (int jt = 0; jt < 4; ++jt) {
#pragma unroll
      for (int r = 0; r < 4; ++r) {
        float a = accA[jt][r] + bA[r];
        float g = accG[jt][r] + bG[r];
        float z = a / (1.f + expf(-g));
        yt[(jt << 4) + lrow][(w << 4) + rbase + r] = f2b(z);
      }
    }
  }
  __syncthreads();
  // ---- phase 4: LN stats over H; v = z + residual ----
  int j = tid & 63, hg = tid >> 6;  // 16 groups of 16 h
  float vreg[16];
  {
    const float* xc = hbuf + (b * H_SZ + (hg << 4)) * L_SZ + l0 + j;
    float s = 0.f, sq = 0.f;
#pragma unroll
    for (int k = 0; k < 16; ++k) {
      float v = b2f(yt[j][(hg << 4) + k]) + xc[(size_t)k * L_SZ];
      vreg[k] = v;
      s += v; sq = fmaf(v, v, sq);
    }
    part[j][hg][0] = s; part[j][hg][1] = sq;
  }
  __syncthreads();
  if (tid < TC) {
    float s = 0.f, sq = 0.f;
#pragma unroll
    for (int g = 0; g < 16; ++g) { s += part[tid][g][0]; sq += part[tid][g][1]; }
    float mu = s * (1.f / 256.f);
    float var = sq * (1.f / 256.f) - mu * mu;
    stats[tid][0] = mu;
    stats[tid][1] = rsqrtf(var + 1e-5f);
  }
  __syncthreads();
  // ---- phase 5: normalized residual; write hbuf OR pool partials (last) ----
  {
    float mu = stats[j][0], rs = stats[j][1];
    if (!last) {
      float* xo = hbuf + (b * H_SZ + (hg << 4)) * L_SZ + l0 + j;
#pragma unroll
      for (int k = 0; k < 16; ++k) {
        int hh = (hg << 4) + k;
        xo[(size_t)k * L_SZ] = (vreg[k] - mu) * rs * ln_g[hh] + ln_b[hh];
      }
    } else {
#pragma unroll
      for (int k = 0; k < 16; ++k) {
        int hh = (hg << 4) + k;
        yt[j][hh] = f2b((vreg[k] - mu) * rs * ln_g[hh] + ln_b[hh]);
      }
      __syncthreads();
      if (tid < H_SZ) {
        float s = 0.f;
        for (int jj = 0; jj < TC; ++jj) s += b2f(yt[jj][tid]);
        pooledPart[(((b << 5) + c) << 8) + tid] = s;
      }
    }
  }
}

// ---------------- decoder MLP (single block) with pooling preamble ----------------
__global__ void k_decoder(const float* __restrict__ pooledPart,
                          const float* __restrict__ w1, const float* __restrict__ b1,
                          const float* __restrict__ w2, const float* __restrict__ b2,
                          const float* __restrict__ w3, const float* __restrict__ b3,
                          float* __restrict__ out) {
  __shared__ float P[16 * 256];
  __shared__ float O1[16 * 128];
  __shared__ float O2[16 * 64];
  int tid = threadIdx.x;
  for (int id = tid; id < 16 * 256; id += 256) {
    int b = id >> 8, hh = id & 255;
    float s = 0.f;
#pragma unroll
    for (int cpart = 0; cpart < 32; ++cpart)
      s += pooledPart[(((b << 5) + cpart) << 8) + hh];
    P[id] = s * (1.f / 2048.f);
  }
  __syncthreads();
  for (int id = tid; id < 16 * 128; id += 256) {
    int r = id >> 7, cc = id & 127;
    float acc = b1[cc];
    for (int d = 0; d < 256; ++d) acc = fmaf(P[(r << 8) + d], w1[(d << 7) + cc], acc);
    O1[id] = fmaxf(acc, 0.f);
  }
  __syncthreads();
  for (int id = tid; id < 16 * 64; id += 256) {
    int r = id >> 6, cc = id & 63;
    float acc = b2[cc];
    for (int d = 0; d < 128; ++d) acc = fmaf(O1[(r << 7) + d], w2[(d << 6) + cc], acc);
    O2[id] = fmaxf(acc, 0.f);
  }
  __syncthreads();
  for (int id = tid; id < 16 * 32; id += 256) {
    int r = id >> 5, cc = id & 31;
    float acc = b3[cc];
    for (int d = 0; d < 64; ++d) acc = fmaf(O2[(r << 6) + d], w3[(d << 5) + cc], acc);
    out[id] = acc;
  }
}

extern "C" void kernel_launch(void* const* d_in, const int* in_sizes, int n_in,
                              void* d_out, int out_size, void* d_ws, size_t ws_size,
                              hipStream_t stream) {
  const float* x          = (const float*)d_in[0];
  const float* enc_w      = (const float*)d_in[1];
  const float* enc_b      = (const float*)d_in[2];
  const float* log_dt     = (const float*)d_in[3];
  const float* C_re       = (const float*)d_in[4];
  const float* C_im       = (const float*)d_in[5];
  const float* log_A_real = (const float*)d_in[6];
  const float* A_imag     = (const float*)d_in[7];
  const float* D_skip     = (const float*)d_in[8];
  const float* w_out      = (const float*)d_in[9];
  const float* b_out      = (const float*)d_in[10];
  const float* ln_g       = (const float*)d_in[11];
  const float* ln_b       = (const float*)d_in[12];
  const float* dw1        = (const float*)d_in[13];
  const float* db1        = (const float*)d_in[14];
  const float* dw2        = (const float*)d_in[15];
  const float* db2        = (const float*)d_in[16];
  const float* dw3        = (const float*)d_in[17];
  const float* db3        = (const float*)d_in[18];

  char* ws = (char*)d_ws;
  float* hbuf = (float*)ws;                                  // 33,554,432 B
  float2* sF2 = (float2*)(ws + 33554432);                    // 33,554,432 B (finals -> carries)
  unsigned short* wbf = (unsigned short*)(ws + 67108864);    //  1,048,576 B
  float* par = (float*)(ws + 68157440);                      //  1,048,576 B
  float* pooledPart = (float*)(ws + 69206016);               //    524,288 B

  k_encoder<<<512, 256, 0, stream>>>(x, enc_w, enc_b, hbuf);
  k_cvtw<<<2048, 256, 0, stream>>>(w_out, wbf, NL * 512 * H_SZ);
  k_params<<<128, 256, 0, stream>>>(log_dt, log_A_real, A_imag, C_re, C_im, par);
  const size_t PAR_STRIDE = (size_t)H_SZ * NH * 8;
  for (int i = 0; i < NL; ++i) {
    const float* pari = par + i * PAR_STRIDE;
    k_scanM<<<256, 512, 0, stream>>>(hbuf, sF2, pari);
    k_layer<<<512, 1024, 0, stream>>>(hbuf, (const float4*)sF2, pari,
                                      D_skip + i * H_SZ, wbf + i * 512 * H_SZ,
                                      b_out + i * 512, ln_g + i * H_SZ, ln_b + i * H_SZ,
                                      pooledPart, (i == NL - 1) ? 1 : 0);
  }
  k_decoder<<<1, 256, 0, stream>>>(pooledPart, dw1, db1, dw2, db2, dw3, db3, (float*)d_out);
}

// Round 10
// 549.498 us; speedup vs baseline: 1.9050x; 1.0781x over previous
//
#include <hip/hip_runtime.h>

#define B_SZ 16
#define L_SZ 2048
#define DIN 64
#define H_SZ 256
#define NH 32
#define NL 4
#define TC 64
#define NTC 32

typedef __attribute__((ext_vector_type(8))) __bf16 bf16x8;
typedef __attribute__((ext_vector_type(4))) float f32x4;

__device__ __forceinline__ unsigned short f2b(float f) {
  unsigned int u = __builtin_bit_cast(unsigned int, f);
  unsigned int r = u + 0x7fffu + ((u >> 16) & 1u);  // RNE (no NaN inputs here)
  return (unsigned short)(r >> 16);
}
__device__ __forceinline__ float b2f(unsigned short u) {
  unsigned int v = ((unsigned int)u) << 16;
  return __builtin_bit_cast(float, v);
}
__device__ __forceinline__ float gelu_exact(float v) {
  return 0.5f * v * (1.f + erff(v * 0.70710678118654752f));
}

// ---------------- encoder: h[b][hh][l] = x[b][l][:] @ enc_w[:,hh] + enc_b ----------------
__global__ void k_encoder(const float* __restrict__ x, const float* __restrict__ w,
                          const float* __restrict__ bias, float* __restrict__ hbuf) {
  __shared__ float wlds[DIN * H_SZ];  // 64 KB
  int tid = threadIdx.x;
  for (int i = tid; i < DIN * H_SZ; i += 256) wlds[i] = w[i];
  int blk = blockIdx.x;            // 512 blocks: b(16) x q(4) x ltile(8)
  int b = blk >> 5;
  int q = (blk >> 3) & 3;
  int l = ((blk & 7) << 8) + tid;
  float xr[DIN];
  const float4* xp = (const float4*)(x + (size_t)(b * L_SZ + l) * DIN);
#pragma unroll
  for (int d4 = 0; d4 < 16; ++d4) {
    float4 v = xp[d4];
    xr[d4 * 4 + 0] = v.x; xr[d4 * 4 + 1] = v.y; xr[d4 * 4 + 2] = v.z; xr[d4 * 4 + 3] = v.w;
  }
  __syncthreads();
  for (int i = 0; i < 64; ++i) {
    int hh = (q << 6) + i;
    float acc = bias[hh];
#pragma unroll
    for (int d = 0; d < DIN; ++d) acc = fmaf(xr[d], wlds[d * H_SZ + hh], acc);
    hbuf[(b * H_SZ + hh) * L_SZ + l] = acc;
  }
}

// ---------------- convert w_out to bf16 ----------------
__global__ void k_cvtw(const float* __restrict__ w, unsigned short* __restrict__ wbf, int n) {
  int i = blockIdx.x * 256 + threadIdx.x;
  if (i < n) wbf[i] = f2b(w[i]);
}

// ---------------- precompute per-state params: lr, li, c2r, c2i, lTr, lTi ----------------
__global__ void k_params(const float* __restrict__ log_dt, const float* __restrict__ log_A_real,
                         const float* __restrict__ A_imag, const float* __restrict__ C_re,
                         const float* __restrict__ C_im, float* __restrict__ par) {
  int id = blockIdx.x * 256 + threadIdx.x;  // i*8192 + h*32 + n
  if (id >= NL * H_SZ * NH) return;
  int i = id >> 13;
  int hn = id & 8191;
  int h = hn >> 5;
  float dt = expf(log_dt[i * H_SZ + h]);
  float Ar = -expf(log_A_real[(size_t)i * H_SZ * NH + hn]);
  float Ai = A_imag[(size_t)i * H_SZ * NH + hn];
  float dr = dt * Ar, di = dt * Ai;
  float e = expf(dr), sn, cs;
  sincosf(di, &sn, &cs);
  float lr = e * cs, li = e * sn;
  float eT = expf((float)TC * dr), snT, csT;
  sincosf((float)TC * di, &snT, &csT);
  float Cr = C_re[(size_t)i * H_SZ * NH + hn], Ci = C_im[(size_t)i * H_SZ * NH + hn];
  float wr = lr - 1.f, wi = li;
  float pr = Cr * wr - Ci * wi;
  float pi = Cr * wi + Ci * wr;
  float inv = 2.f / fmaf(Ar, Ar, Ai * Ai);
  float4* p = (float4*)(par + (size_t)id * 8);
  p[0] = make_float4(lr, li, (pr * Ar + pi * Ai) * inv, (pi * Ar - pr * Ai) * inv);
  p[1] = make_float4(eT * csT, eT * snT, 0.f, 0.f);
}

// ---------------- chunk finals via compensated MFMA Vandermonde GEMM + in-kernel prefix ----
__launch_bounds__(512, 1)
__global__ void k_scanM(const float* __restrict__ hbuf, float2* __restrict__ sF2,
                        const float* __restrict__ par) {
  __shared__ __align__(16) unsigned short xbh[256][72];  // 36864 B
  __shared__ __align__(16) unsigned short xbl[256][72];  // 36864 B
  __shared__ __align__(16) unsigned short Uh[64][72];    //  9216 B
  __shared__ __align__(16) unsigned short Ul[64][72];    //  9216 B
  int tid = threadIdx.x;
  int h = blockIdx.x;

  if (tid < 64) {
    int n = tid >> 1, q = tid & 1;
    const float* pb = par + (size_t)(h * NH + n) * 8;
    float lr = pb[0], li = pb[1];
    float pr = 1.f, pi = 0.f;
    if (q) {
      float sr = lr, si = li;
#pragma unroll
      for (int t = 0; t < 5; ++t) { float nr2 = sr * sr - si * si; si = 2.f * sr * si; sr = nr2; }
      pr = sr; pi = si;
    }
    int p = q << 5;
    for (int s = 0; s < 32; ++s, ++p) {
      int col = 63 - p;
      unsigned short hr = f2b(pr);
      Uh[2 * n][col] = hr; Ul[2 * n][col] = f2b(pr - b2f(hr));
      unsigned short hm = f2b(pi);
      Uh[2 * n + 1][col] = hm; Ul[2 * n + 1][col] = f2b(pi - b2f(hm));
      float nr2 = pr * lr - pi * li;
      pi = pr * li + pi * lr;
      pr = nr2;
    }
  }

  int wv = tid >> 6, lane = tid & 63;
  int lrow = lane & 15, lk8 = (lane >> 4) << 3;
  int rt = wv >> 1;
  int ct0 = (wv & 1) << 3;

  for (int half = 0; half < 2; ++half) {
    __syncthreads();
    {
      int colh = tid >> 1, j0 = (tid & 1) << 5;
      int b = (half << 3) + (colh >> 5), c = colh & 31;
      const float* src = hbuf + ((size_t)(b * H_SZ + h) << 11) + (c << 6) + j0;
      unsigned short* dh = &xbh[colh][j0];
      unsigned short* dl = &xbl[colh][j0];
#pragma unroll
      for (int jj = 0; jj < 8; ++jj) {
        float4 v = *(const float4*)(src + jj * 4);
        unsigned short h0 = f2b(v.x); dh[jj * 4 + 0] = h0; dl[jj * 4 + 0] = f2b(v.x - b2f(h0));
        unsigned short h1 = f2b(v.y); dh[jj * 4 + 1] = h1; dl[jj * 4 + 1] = f2b(v.y - b2f(h1));
        unsigned short h2 = f2b(v.z); dh[jj * 4 + 2] = h2; dl[jj * 4 + 2] = f2b(v.z - b2f(h2));
        unsigned short h3 = f2b(v.w); dh[jj * 4 + 3] = h3; dl[jj * 4 + 3] = f2b(v.w - b2f(h3));
      }
    }
    __syncthreads();
    f32x4 acc[8];
#pragma unroll
    for (int ct = 0; ct < 8; ++ct) acc[ct] = (f32x4){0.f, 0.f, 0.f, 0.f};
#pragma unroll
    for (int kk = 0; kk < 2; ++kk) {
      bf16x8 ah = *(const bf16x8*)&Uh[(rt << 4) + lrow][(kk << 5) + lk8];
      bf16x8 al = *(const bf16x8*)&Ul[(rt << 4) + lrow][(kk << 5) + lk8];
#pragma unroll
      for (int ct = 0; ct < 8; ++ct) {
        int colh = ((ct0 + ct) << 4) + lrow;
        bf16x8 bh = *(const bf16x8*)&xbh[colh][(kk << 5) + lk8];
        bf16x8 bl = *(const bf16x8*)&xbl[colh][(kk << 5) + lk8];
        acc[ct] = __builtin_amdgcn_mfma_f32_16x16x32_bf16(ah, bh, acc[ct], 0, 0, 0);
        acc[ct] = __builtin_amdgcn_mfma_f32_16x16x32_bf16(ah, bl, acc[ct], 0, 0, 0);
        acc[ct] = __builtin_amdgcn_mfma_f32_16x16x32_bf16(al, bh, acc[ct], 0, 0, 0);
      }
    }
    {
      int n0 = (rt << 3) + ((lane >> 4) << 1);
#pragma unroll
      for (int ct = 0; ct < 8; ++ct) {
        int colg = (half << 8) + ((ct0 + ct) << 4) + lrow;
        float2* o = sF2 + (size_t)colg * (H_SZ * NH) + h * NH + n0;
        o[0] = make_float2(acc[ct][0], acc[ct][1]);
        o[1] = make_float2(acc[ct][2], acc[ct][3]);
      }
    }
  }
  __syncthreads();
  {
    int b = tid >> 5, n = tid & 31;
    const float* pb = par + (size_t)(h * NH + n) * 8;
    float lTr = pb[4], lTi = pb[5];
    float cr = 0.f, ci = 0.f;
    float2* p0 = sF2 + (size_t)(b << 5) * (H_SZ * NH) + h * NH + n;
    const size_t cstride = H_SZ * NH;
    float2 f = p0[0];
    for (int c = 0; c < NTC; ++c) {
      float2 fn = f;
      if (c + 1 < NTC) fn = p0[(size_t)(c + 1) * cstride];
      p0[(size_t)c * cstride] = make_float2(cr, ci);
      float nr = fmaf(lTr, cr, f.x); nr = fmaf(-lTi, ci, nr);
      float ni = fmaf(lTr, ci, f.y); ni = fmaf(lTi, cr, ni);
      cr = nr; ci = ni;
      f = fn;
    }
  }
}

// ---------------- S4D conv via per-h MFMA: y = T@x + W@s_in  (f32 out) ----------------
// block = one h, 512 threads. T[j][j'] = K[j-j'] (j'<=j); W[j][2n]=Re(c2 l^{j+1}), [2n+1]=-Im.
__launch_bounds__(512, 1)
__global__ void k_conv(const float* __restrict__ hbuf, const float2* __restrict__ sF2,
                       const float* __restrict__ par, float* __restrict__ yloc) {
  __shared__ __align__(16) unsigned short xbh[256][72];  // 36864 B (x / svec, hi)
  __shared__ __align__(16) unsigned short xbl[256][72];  // 36864 B (lo)
  __shared__ __align__(16) unsigned short Th[64][72];    //  9216 B
  __shared__ __align__(16) unsigned short Tl[64][72];
  __shared__ __align__(16) unsigned short Wh[64][72];
  __shared__ __align__(16) unsigned short Wl[64][72];
  __shared__ float Kc[64];
  int tid = threadIdx.x;
  int h = blockIdx.x;
  float* Wm = (float*)&xbh[0][0];  // [64][66] f32 scratch, consumed before x staging

  // ---- build Wm[j][2n]=c2*lam^{j+1} (Re), [2n+1]=-(Im) ----
  if (tid < 64) {
    int n = tid >> 1, q = tid & 1;
    const float* pb = par + (size_t)(h * NH + n) * 8;
    float lr = pb[0], li = pb[1], c2r = pb[2], c2i = pb[3];
    float pr = lr, pi = li;  // lam^1
    if (q) {                 // lam^33
      float sr = lr, si = li;
#pragma unroll
      for (int t = 0; t < 5; ++t) { float nr2 = sr * sr - si * si; si = 2.f * sr * si; sr = nr2; }
      pr = sr * lr - si * li; pi = sr * li + si * lr;
    }
    int p = q << 5;
    for (int s = 0; s < 32; ++s, ++p) {
      Wm[p * 66 + 2 * n] = c2r * pr - c2i * pi;
      Wm[p * 66 + 2 * n + 1] = -(c2r * pi + c2i * pr);
      float nr2 = pr * lr - pi * li;
      pi = pr * li + pi * lr;
      pr = nr2;
    }
  }
  __syncthreads();
  // ---- K[d] = sum_n Re-coef: K[0]=sum c2r; K[d>=1]=sum_n Wm[d-1][2n]  +  Wh/Wl from Wm ----
  if (tid < 64) {
    float kv = 0.f;
    if (tid == 0) {
      for (int n = 0; n < 32; ++n) kv += par[(size_t)(h * NH + n) * 8 + 2];
    } else {
      for (int n = 0; n < 32; ++n) kv += Wm[(tid - 1) * 66 + 2 * n];
    }
    Kc[tid] = kv;
  }
  {
    int base = tid * 8;
    int row = base >> 6, col0 = base & 63;
#pragma unroll
    for (int e = 0; e < 8; ++e) {
      float v = Wm[row * 66 + col0 + e];
      unsigned short hv = f2b(v);
      Wh[row][col0 + e] = hv; Wl[row][col0 + e] = f2b(v - b2f(hv));
    }
  }
  __syncthreads();
  // ---- T from Kc (Wm dead; xbh free after this barrier wave completes staging below) ----
  {
    int base = tid * 8;
    int row = base >> 6, col0 = base & 63;
#pragma unroll
    for (int e = 0; e < 8; ++e) {
      int col = col0 + e;
      float v = (col <= row) ? Kc[row - col] : 0.f;
      unsigned short hv = f2b(v);
      Th[row][col] = hv; Tl[row][col] = f2b(v - b2f(hv));
    }
  }

  int wv = tid >> 6, lane = tid & 63;
  int lrow = lane & 15, lk8 = (lane >> 4) << 3;
  int rt = wv >> 1;
  int ct0 = (wv & 1) << 3;
  int rsub = (lane >> 4) << 2;

  for (int half = 0; half < 2; ++half) {
    __syncthreads();  // T/W ready (half 0) / svec reads done (half 1)
    // ---- stage x hi/lo ----
    {
      int colh = tid >> 1, j0 = (tid & 1) << 5;
      int b = (half << 3) + (colh >> 5), c = colh & 31;
      const float* src = hbuf + ((size_t)(b * H_SZ + h) << 11) + (c << 6) + j0;
      unsigned short* dh = &xbh[colh][j0];
      unsigned short* dl = &xbl[colh][j0];
#pragma unroll
      for (int jj = 0; jj < 8; ++jj) {
        float4 v = *(const float4*)(src + jj * 4);
        unsigned short h0 = f2b(v.x); dh[jj * 4 + 0] = h0; dl[jj * 4 + 0] = f2b(v.x - b2f(h0));
        unsigned short h1 = f2b(v.y); dh[jj * 4 + 1] = h1; dl[jj * 4 + 1] = f2b(v.y - b2f(h1));
        unsigned short h2 = f2b(v.z); dh[jj * 4 + 2] = h2; dl[jj * 4 + 2] = f2b(v.z - b2f(h2));
        unsigned short h3 = f2b(v.w); dh[jj * 4 + 3] = h3; dl[jj * 4 + 3] = f2b(v.w - b2f(h3));
      }
    }
    __syncthreads();
    f32x4 acc[8];
#pragma unroll
    for (int ct = 0; ct < 8; ++ct) acc[ct] = (f32x4){0.f, 0.f, 0.f, 0.f};
    // ---- T-GEMM (compensated) ----
#pragma unroll
    for (int kk = 0; kk < 2; ++kk) {
      bf16x8 ah = *(const bf16x8*)&Th[(rt << 4) + lrow][(kk << 5) + lk8];
      bf16x8 al = *(const bf16x8*)&Tl[(rt << 4) + lrow][(kk << 5) + lk8];
#pragma unroll
      for (int ct = 0; ct < 8; ++ct) {
        int col = ((ct0 + ct) << 4) + lrow;
        bf16x8 bh = *(const bf16x8*)&xbh[col][(kk << 5) + lk8];
        bf16x8 bl = *(const bf16x8*)&xbl[col][(kk << 5) + lk8];
        acc[ct] = __builtin_amdgcn_mfma_f32_16x16x32_bf16(ah, bh, acc[ct], 0, 0, 0);
        acc[ct] = __builtin_amdgcn_mfma_f32_16x16x32_bf16(ah, bl, acc[ct], 0, 0, 0);
        acc[ct] = __builtin_amdgcn_mfma_f32_16x16x32_bf16(al, bh, acc[ct], 0, 0, 0);
      }
    }
    __syncthreads();  // x reads done; reuse xbh/xbl for svec
    // ---- stage svec (carries) hi/lo: rows 2n=Re, 2n+1=Im ----
    {
      int colh = tid >> 1, n0 = (tid & 1) << 4;
      int colg = (half << 8) + colh;
      const float2* cp = sF2 + (size_t)colg * (H_SZ * NH) + h * NH;
#pragma unroll
      for (int n = 0; n < 16; ++n) {
        float2 s = cp[n0 + n];
        int k2 = 2 * (n0 + n);
        unsigned short hr = f2b(s.x);
        xbh[colh][k2] = hr; xbl[colh][k2] = f2b(s.x - b2f(hr));
        unsigned short hm = f2b(s.y);
        xbh[colh][k2 + 1] = hm; xbl[colh][k2 + 1] = f2b(s.y - b2f(hm));
      }
    }
    __syncthreads();
    // ---- W-GEMM (compensated), accumulate ----
#pragma unroll
    for (int kk = 0; kk < 2; ++kk) {
      bf16x8 ah = *(const bf16x8*)&Wh[(rt << 4) + lrow][(kk << 5) + lk8];
      bf16x8 al = *(const bf16x8*)&Wl[(rt << 4) + lrow][(kk << 5) + lk8];
#pragma unroll
      for (int ct = 0; ct < 8; ++ct) {
        int col = ((ct0 + ct) << 4) + lrow;
        bf16x8 bh = *(const bf16x8*)&xbh[col][(kk << 5) + lk8];
        bf16x8 bl = *(const bf16x8*)&xbl[col][(kk << 5) + lk8];
        acc[ct] = __builtin_amdgcn_mfma_f32_16x16x32_bf16(ah, bh, acc[ct], 0, 0, 0);
        acc[ct] = __builtin_amdgcn_mfma_f32_16x16x32_bf16(ah, bl, acc[ct], 0, 0, 0);
        acc[ct] = __builtin_amdgcn_mfma_f32_16x16x32_bf16(al, bh, acc[ct], 0, 0, 0);
      }
    }
    // ---- write y f32: yloc[h][colg*64 + j] ----
#pragma unroll
    for (int ct = 0; ct < 8; ++ct) {
      int colg = (half << 8) + ((ct0 + ct) << 4) + lrow;
      float4 o = make_float4(acc[ct][0], acc[ct][1], acc[ct][2], acc[ct][3]);
      *(float4*)(yloc + (size_t)h * (B_SZ * L_SZ) + (size_t)colg * 64 + (rt << 4) + rsub) = o;
    }
  }
}

// ---------------- post: fill(y+Dx)+GELU + GLU + LN  (new fast path) ----------------
__launch_bounds__(1024, 4)
__global__ void k_layer2(float* __restrict__ hbuf, const float* __restrict__ yloc,
                         const float* __restrict__ D_skip,
                         const unsigned short* __restrict__ wbf,
                         const float* __restrict__ b_out,
                         const float* __restrict__ ln_g, const float* __restrict__ ln_b,
                         float* __restrict__ pooledPart, int last) {
  __shared__ __align__(16) unsigned short yt[TC][H_SZ + 8];
  __shared__ float part[TC][16][2];
  __shared__ float stats[TC][2];
  int tid = threadIdx.x;
  int b = blockIdx.x >> 5;
  int c = blockIdx.x & 31;
  int l0 = c << 6;

  // ---- fill + gelu ----
  {
    int h = tid >> 2, q = tid & 3;
    float Dh = D_skip[h];
    const float* xp = hbuf + ((size_t)(b * H_SZ + h) << 11) + l0 + (q << 4);
    const float* yp2 = yloc + (size_t)h * (B_SZ * L_SZ) + b * L_SZ + l0 + (q << 4);
#pragma unroll
    for (int jj = 0; jj < 16; jj += 4) {
      float4 xv = *(const float4*)(xp + jj);
      float4 yv = *(const float4*)(yp2 + jj);
      int jb = (q << 4) + jj;
      yt[jb + 0][h] = f2b(gelu_exact(fmaf(Dh, xv.x, yv.x)));
      yt[jb + 1][h] = f2b(gelu_exact(fmaf(Dh, xv.y, yv.y)));
      yt[jb + 2][h] = f2b(gelu_exact(fmaf(Dh, xv.z, yv.z)));
      yt[jb + 3][h] = f2b(gelu_exact(fmaf(Dh, xv.w, yv.w)));
    }
  }
  __syncthreads();
  // ---- GLU: 1x1 conv via MFMA; z -> yt ----
  {
    int w = tid >> 6, lane = tid & 63;
    int lrow = lane & 15, lk8 = (lane >> 4) << 3;
    f32x4 accA[4], accG[4];
    f32x4 zed = {0.f, 0.f, 0.f, 0.f};
#pragma unroll
    for (int jt = 0; jt < 4; ++jt) { accA[jt] = zed; accG[jt] = zed; }
    const unsigned short* wA = wbf + ((w << 4) + lrow) * H_SZ;
    const unsigned short* wG = wA + 256 * H_SZ;
#pragma unroll
    for (int k0 = 0; k0 < H_SZ; k0 += 32) {
      bf16x8 a0 = *(const bf16x8*)(wA + k0 + lk8);
      bf16x8 a1 = *(const bf16x8*)(wG + k0 + lk8);
#pragma unroll
      for (int jt = 0; jt < 4; ++jt) {
        bf16x8 bb = *(const bf16x8*)(&yt[(jt << 4) + lrow][k0 + lk8]);
        accA[jt] = __builtin_amdgcn_mfma_f32_16x16x32_bf16(a0, bb, accA[jt], 0, 0, 0);
        accG[jt] = __builtin_amdgcn_mfma_f32_16x16x32_bf16(a1, bb, accG[jt], 0, 0, 0);
      }
    }
    __syncthreads();
    int rbase = (lane >> 4) << 2;
    float bA[4], bG[4];
#pragma unroll
    for (int r = 0; r < 4; ++r) {
      bA[r] = b_out[(w << 4) + rbase + r];
      bG[r] = b_out[256 + (w << 4) + rbase + r];
    }
#pragma unroll
    for (int jt = 0; jt < 4; ++jt) {
#pragma unroll
      for (int r = 0; r < 4; ++r) {
        float a = accA[jt][r] + bA[r];
        float g = accG[jt][r] + bG[r];
        float z = a / (1.f + expf(-g));
        yt[(jt << 4) + lrow][(w << 4) + rbase + r] = f2b(z);
      }
    }
  }
  __syncthreads();
  // ---- LN stats; v = z + residual ----
  int j = tid & 63, hg = tid >> 6;
  float vreg[16];
  {
    const float* xc = hbuf + (b * H_SZ + (hg << 4)) * L_SZ + l0 + j;
    float s = 0.f, sq = 0.f;
#pragma unroll
    for (int k = 0; k < 16; ++k) {
      float v = b2f(yt[j][(hg << 4) + k]) + xc[(size_t)k * L_SZ];
      vreg[k] = v;
      s += v; sq = fmaf(v, v, sq);
    }
    part[j][hg][0] = s; part[j][hg][1] = sq;
  }
  __syncthreads();
  if (tid < TC) {
    float s = 0.f, sq = 0.f;
#pragma unroll
    for (int g = 0; g < 16; ++g) { s += part[tid][g][0]; sq += part[tid][g][1]; }
    float mu = s * (1.f / 256.f);
    float var = sq * (1.f / 256.f) - mu * mu;
    stats[tid][0] = mu;
    stats[tid][1] = rsqrtf(var + 1e-5f);
  }
  __syncthreads();
  {
    float mu = stats[j][0], rs = stats[j][1];
    if (!last) {
      float* xo = hbuf + (b * H_SZ + (hg << 4)) * L_SZ + l0 + j;
#pragma unroll
      for (int k = 0; k < 16; ++k) {
        int hh = (hg << 4) + k;
        xo[(size_t)k * L_SZ] = (vreg[k] - mu) * rs * ln_g[hh] + ln_b[hh];
      }
    } else {
#pragma unroll
      for (int k = 0; k < 16; ++k) {
        int hh = (hg << 4) + k;
        yt[j][hh] = f2b((vreg[k] - mu) * rs * ln_g[hh] + ln_b[hh]);
      }
      __syncthreads();
      if (tid < H_SZ) {
        float s = 0.f;
        for (int jj = 0; jj < TC; ++jj) s += b2f(yt[jj][tid]);
        pooledPart[(((b << 5) + c) << 8) + tid] = s;
      }
    }
  }
}

// ---------------- legacy fused per-layer kernel (fallback if ws too small) ----------------
__launch_bounds__(1024, 4)
__global__ void k_layer(float* __restrict__ hbuf, const float4* __restrict__ sFin,
                        const float* __restrict__ par,
                        const float* __restrict__ D_skip,
                        const unsigned short* __restrict__ wbf,
                        const float* __restrict__ b_out,
                        const float* __restrict__ ln_g, const float* __restrict__ ln_b,
                        float* __restrict__ pooledPart, int last) {
  __shared__ __align__(16) unsigned short yt[TC][H_SZ + 8];
  __shared__ float part[TC][16][2];
  __shared__ float stats[TC][2];
  int tid = threadIdx.x;
  int b = blockIdx.x >> 5;
  int c = blockIdx.x & 31;
  int l0 = c << 6;
  {
    int h = tid >> 2, ng = tid & 3;
    const float4* pp = (const float4*)(par + (size_t)(h * NH + ng * 8) * 8);
    float lr[8], li[8], c2r[8], c2i[8], sre[8], sim[8];
    const float4* fp = sFin + (((size_t)((b << 5) + c) * H_SZ + h) * 4 + ng) * 4;
#pragma unroll
    for (int q = 0; q < 4; ++q) {
      float4 f = fp[q];
      sre[2 * q] = f.x; sim[2 * q] = f.y;
      sre[2 * q + 1] = f.z; sim[2 * q + 1] = f.w;
    }
#pragma unroll
    for (int k = 0; k < 8; ++k) {
      float4 p0 = pp[k * 2];
      lr[k] = p0.x; li[k] = p0.y; c2r[k] = p0.z; c2i[k] = p0.w;
    }
    float Dh = D_skip[h];
    const float* xp = hbuf + (b * H_SZ + h) * L_SZ + l0;
    float4 xv = *(const float4*)xp;
    for (int j4 = 0; j4 < TC; j4 += 4) {
      float4 xn = xv;
      if (j4 + 4 < TC) xn = *(const float4*)(xp + j4 + 4);
      float xe[4] = {xv.x, xv.y, xv.z, xv.w};
#pragma unroll
      for (int e = 0; e < 4; ++e) {
        float xj = xe[e];
        float yp0 = 0.f, yp1 = 0.f;
#pragma unroll
        for (int k = 0; k < 8; ++k) {
          float nr = fmaf(lr[k], sre[k], xj);
          nr = fmaf(-li[k], sim[k], nr);
          float ni = lr[k] * sim[k];
          ni = fmaf(li[k], sre[k], ni);
          sre[k] = nr; sim[k] = ni;
          if (k & 1) {
            yp1 = fmaf(c2r[k], nr, yp1);
            yp1 = fmaf(-c2i[k], ni, yp1);
          } else {
            yp0 = fmaf(c2r[k], nr, yp0);
            yp0 = fmaf(-c2i[k], ni, yp0);
          }
        }
        float yp = yp0 + yp1;
        yp += __shfl_xor(yp, 1);
        yp += __shfl_xor(yp, 2);
        if (ng == 0) yt[j4 + e][h] = f2b(fmaf(Dh, xj, yp));
      }
      xv = xn;
    }
  }
  __syncthreads();
  for (int it = 0; it < 8; ++it) {
    int id = it * 1024 + tid;
    int jr = id >> 7, hp = id & 127;
    unsigned int u = *(unsigned int*)&yt[jr][hp * 2];
    float v0 = b2f((unsigned short)(u & 0xffff));
    float v1 = b2f((unsigned short)(u >> 16));
    v0 = gelu_exact(v0);
    v1 = gelu_exact(v1);
    *(unsigned int*)&yt[jr][hp * 2] = (unsigned int)f2b(v0) | ((unsigned int)f2b(v1) << 16);
  }
  __syncthreads();
  {
    int w = tid >> 6, lane = tid & 63;
    int lrow = lane & 15, lk8 = (lane >> 4) << 3;
    f32x4 accA[4], accG[4];
    f32x4 zed = {0.f, 0.f, 0.f, 0.f};
#pragma unroll
    for (int jt = 0; jt < 4; ++jt) { accA[jt] = zed; accG[jt] = zed; }
    const unsigned short* wA = wbf + ((w << 4) + lrow) * H_SZ;
    const unsigned short* wG = wA + 256 * H_SZ;
#pragma unroll
    for (int k0 = 0; k0 < H_SZ; k0 += 32) {
      bf16x8 a0 = *(const bf16x8*)(wA + k0 + lk8);
      bf16x8 a1 = *(const bf16x8*)(wG + k0 + lk8);
#pragma unroll
      for (int jt = 0; jt < 4; ++jt) {
        bf16x8 bb = *(const bf16x8*)(&yt[(jt << 4) + lrow][k0 + lk8]);
        accA[jt] = __builtin_amdgcn_mfma_f32_16x16x32_bf16(a0, bb, accA[jt], 0, 0, 0);
        accG[jt] = __builtin_amdgcn_mfma_f32_16x16x32_bf16(a1, bb, accG[jt], 0, 0, 0);
      }
    }
    __syncthreads();
    int rbase = (lane >> 4) << 2;
    float bA[4], bG[4];
#pragma unroll
    for (int r = 0; r < 4; ++r) {
      bA[r] = b_out[(w << 4) + rbase + r];
      bG[r] = b_out[256 + (w << 4) + rbase + r];
    }
#pragma unroll
    for (int jt = 0; jt < 4; ++jt) {
#pragma unroll
      for (int r = 0; r < 4; ++r) {
        float a = accA[jt][r] + bA[r];
        float g = accG[jt][r] + bG[r];
        float z = a / (1.f + expf(-g));
        yt[(jt << 4) + lrow][(w << 4) + rbase + r] = f2b(z);
      }
    }
  }
  __syncthreads();
  int j = tid & 63, hg = tid >> 6;
  float vreg[16];
  {
    const float* xc = hbuf + (b * H_SZ + (hg << 4)) * L_SZ + l0 + j;
    float s = 0.f, sq = 0.f;
#pragma unroll
    for (int k = 0; k < 16; ++k) {
      float v = b2f(yt[j][(hg << 4) + k]) + xc[(size_t)k * L_SZ];
      vreg[k] = v;
      s += v; sq = fmaf(v, v, sq);
    }
    part[j][hg][0] = s; part[j][hg][1] = sq;
  }
  __syncthreads();
  if (tid < TC) {
    float s = 0.f, sq = 0.f;
#pragma unroll
    for (int g = 0; g < 16; ++g) { s += part[tid][g][0]; sq += part[tid][g][1]; }
    float mu = s * (1.f / 256.f);
    float var = sq * (1.f / 256.f) - mu * mu;
    stats[tid][0] = mu;
    stats[tid][1] = rsqrtf(var + 1e-5f);
  }
  __syncthreads();
  {
    float mu = stats[j][0], rs = stats[j][1];
    if (!last) {
      float* xo = hbuf + (b * H_SZ + (hg << 4)) * L_SZ + l0 + j;
#pragma unroll
      for (int k = 0; k < 16; ++k) {
        int hh = (hg << 4) + k;
        xo[(size_t)k * L_SZ] = (vreg[k] - mu) * rs * ln_g[hh] + ln_b[hh];
      }
    } else {
#pragma unroll
      for (int k = 0; k < 16; ++k) {
        int hh = (hg << 4) + k;
        yt[j][hh] = f2b((vreg[k] - mu) * rs * ln_g[hh] + ln_b[hh]);
      }
      __syncthreads();
      if (tid < H_SZ) {
        float s = 0.f;
        for (int jj = 0; jj < TC; ++jj) s += b2f(yt[jj][tid]);
        pooledPart[(((b << 5) + c) << 8) + tid] = s;
      }
    }
  }
}

// ---------------- decoder MLP (single block) with pooling preamble ----------------
__global__ void k_decoder(const float* __restrict__ pooledPart,
                          const float* __restrict__ w1, const float* __restrict__ b1,
                          const float* __restrict__ w2, const float* __restrict__ b2,
                          const float* __restrict__ w3, const float* __restrict__ b3,
                          float* __restrict__ out) {
  __shared__ float P[16 * 256];
  __shared__ float O1[16 * 128];
  __shared__ float O2[16 * 64];
  int tid = threadIdx.x;
  for (int id = tid; id < 16 * 256; id += 256) {
    int b = id >> 8, hh = id & 255;
    float s = 0.f;
#pragma unroll
    for (int cpart = 0; cpart < 32; ++cpart)
      s += pooledPart[(((b << 5) + cpart) << 8) + hh];
    P[id] = s * (1.f / 2048.f);
  }
  __syncthreads();
  for (int id = tid; id < 16 * 128; id += 256) {
    int r = id >> 7, cc = id & 127;
    float acc = b1[cc];
    for (int d = 0; d < 256; ++d) acc = fmaf(P[(r << 8) + d], w1[(d << 7) + cc], acc);
    O1[id] = fmaxf(acc, 0.f);
  }
  __syncthreads();
  for (int id = tid; id < 16 * 64; id += 256) {
    int r = id >> 6, cc = id & 63;
    float acc = b2[cc];
    for (int d = 0; d < 128; ++d) acc = fmaf(O1[(r << 7) + d], w2[(d << 6) + cc], acc);
    O2[id] = fmaxf(acc, 0.f);
  }
  __syncthreads();
  for (int id = tid; id < 16 * 32; id += 256) {
    int r = id >> 5, cc = id & 31;
    float acc = b3[cc];
    for (int d = 0; d < 64; ++d) acc = fmaf(O2[(r << 6) + d], w3[(d << 5) + cc], acc);
    out[id] = acc;
  }
}

extern "C" void kernel_launch(void* const* d_in, const int* in_sizes, int n_in,
                              void* d_out, int out_size, void* d_ws, size_t ws_size,
                              hipStream_t stream) {
  const float* x          = (const float*)d_in[0];
  const float* enc_w      = (const float*)d_in[1];
  const float* enc_b      = (const float*)d_in[2];
  const float* log_dt     = (const float*)d_in[3];
  const float* C_re       = (const float*)d_in[4];
  const float* C_im       = (const float*)d_in[5];
  const float* log_A_real = (const float*)d_in[6];
  const float* A_imag     = (const float*)d_in[7];
  const float* D_skip     = (const float*)d_in[8];
  const float* w_out      = (const float*)d_in[9];
  const float* b_out      = (const float*)d_in[10];
  const float* ln_g       = (const float*)d_in[11];
  const float* ln_b       = (const float*)d_in[12];
  const float* dw1        = (const float*)d_in[13];
  const float* db1        = (const float*)d_in[14];
  const float* dw2        = (const float*)d_in[15];
  const float* db2        = (const float*)d_in[16];
  const float* dw3        = (const float*)d_in[17];
  const float* db3        = (const float*)d_in[18];

  char* ws = (char*)d_ws;
  float* hbuf = (float*)ws;                                  // 33,554,432 B
  float2* sF2 = (float2*)(ws + 33554432);                    // 33,554,432 B
  // fast path layout (needs 103,284,736 B total)
  const size_t NEED_BIG = 33554432ull * 3 + 1048576 * 2 + 524288;
  bool big = ws_size >= NEED_BIG;
  float* yloc;
  unsigned short* wbf;
  float* par;
  float* pooledPart;
  if (big) {
    yloc = (float*)(ws + 67108864);                          // 33,554,432 B
    wbf = (unsigned short*)(ws + 100663296);                 //  1,048,576 B
    par = (float*)(ws + 101711872);                          //  1,048,576 B
    pooledPart = (float*)(ws + 102760448);                   //    524,288 B
  } else {
    yloc = nullptr;
    wbf = (unsigned short*)(ws + 67108864);
    par = (float*)(ws + 68157440);
    pooledPart = (float*)(ws + 69206016);
  }

  k_encoder<<<512, 256, 0, stream>>>(x, enc_w, enc_b, hbuf);
  k_cvtw<<<2048, 256, 0, stream>>>(w_out, wbf, NL * 512 * H_SZ);
  k_params<<<128, 256, 0, stream>>>(log_dt, log_A_real, A_imag, C_re, C_im, par);
  const size_t PAR_STRIDE = (size_t)H_SZ * NH * 8;
  for (int i = 0; i < NL; ++i) {
    const float* pari = par + i * PAR_STRIDE;
    k_scanM<<<256, 512, 0, stream>>>(hbuf, sF2, pari);
    if (big) {
      k_conv<<<256, 512, 0, stream>>>(hbuf, sF2, pari, yloc);
      k_layer2<<<512, 1024, 0, stream>>>(hbuf, yloc,
                                         D_skip + i * H_SZ, wbf + i * 512 * H_SZ,
                                         b_out + i * 512, ln_g + i * H_SZ, ln_b + i * H_SZ,
                                         pooledPart, (i == NL - 1) ? 1 : 0);
    } else {
      k_layer<<<512, 1024, 0, stream>>>(hbuf, (const float4*)sF2, pari,
                                        D_skip + i * H_SZ, wbf + i * 512 * H_SZ,
                                        b_out + i * 512, ln_g + i * H_SZ, ln_b + i * H_SZ,
                                        pooledPart, (i == NL - 1) ? 1 : 0);
    }
  }
  k_decoder<<<1, 256, 0, stream>>>(pooledPart, dw1, db1, dw2, db2, dw3, db3, (float*)d_out);
}

// Round 11
// 494.732 us; speedup vs baseline: 2.1159x; 1.1107x over previous
//
#include <hip/hip_runtime.h>

#define B_SZ 16
#define L_SZ 2048
#define DIN 64
#define H_SZ 256
#define NH 32
#define NL 4
#define TC 64
#define NTC 32

typedef __attribute__((ext_vector_type(8))) __bf16 bf16x8;
typedef __attribute__((ext_vector_type(4))) float f32x4;

__device__ __forceinline__ unsigned short f2b(float f) {
  unsigned int u = __builtin_bit_cast(unsigned int, f);
  unsigned int r = u + 0x7fffu + ((u >> 16) & 1u);  // RNE (no NaN inputs here)
  return (unsigned short)(r >> 16);
}
__device__ __forceinline__ float b2f(unsigned short u) {
  unsigned int v = ((unsigned int)u) << 16;
  return __builtin_bit_cast(float, v);
}
__device__ __forceinline__ float gelu_exact(float v) {
  return 0.5f * v * (1.f + erff(v * 0.70710678118654752f));
}

// ---------------- encoder as compensated MFMA GEMM ----------------
// block = (b, ltile, hhalf): 128 h x 128 l. hbuf[(b*H+h)*L + l] = x[b][l][:] @ w[:,h] + bias
__launch_bounds__(512, 4)
__global__ void k_encoder(const float* __restrict__ x, const float* __restrict__ w,
                          const float* __restrict__ bias, float* __restrict__ hbuf) {
  __shared__ __align__(16) unsigned short Wh[128][72];  // 18432 B
  __shared__ __align__(16) unsigned short Wl[128][72];
  __shared__ __align__(16) unsigned short xh[128][72];
  __shared__ __align__(16) unsigned short xl[128][72];  // total 73728 B
  int tid = threadIdx.x;
  int blk = blockIdx.x;           // b(4b) lt(4b) hh(1b)
  int b = blk >> 5;
  int lt = (blk >> 1) & 15;
  int hh = blk & 1;

  // ---- stage W[hl][d] hi/lo (transposed from w[d][h]); coalesced reads ----
#pragma unroll
  for (int i = 0; i < 16; ++i) {
    int flat = i * 512 + tid;     // 8192 = 64 d x 128 hl
    int d = flat >> 7, hl = flat & 127;
    float v = w[d * H_SZ + (hh << 7) + hl];
    unsigned short hv = f2b(v);
    Wh[hl][d] = hv; Wl[hl][d] = f2b(v - b2f(hv));
  }
  // ---- stage X[l][d] hi/lo; fully coalesced float4 ----
  {
    int l = tid >> 2, d0 = (tid & 3) << 4;
    const float* src = x + ((size_t)(b * L_SZ + (lt << 7) + l) << 6) + d0;
    unsigned short* dh = &xh[l][d0];
    unsigned short* dl = &xl[l][d0];
#pragma unroll
    for (int jj = 0; jj < 4; ++jj) {
      float4 v = *(const float4*)(src + jj * 4);
      unsigned short h0 = f2b(v.x); dh[jj * 4 + 0] = h0; dl[jj * 4 + 0] = f2b(v.x - b2f(h0));
      unsigned short h1 = f2b(v.y); dh[jj * 4 + 1] = h1; dl[jj * 4 + 1] = f2b(v.y - b2f(h1));
      unsigned short h2 = f2b(v.z); dh[jj * 4 + 2] = h2; dl[jj * 4 + 2] = f2b(v.z - b2f(h2));
      unsigned short h3 = f2b(v.w); dh[jj * 4 + 3] = h3; dl[jj * 4 + 3] = f2b(v.w - b2f(h3));
    }
  }
  __syncthreads();

  int wv = tid >> 6, lane = tid & 63;
  int lrow = lane & 15, lk8 = (lane >> 4) << 3;
  int rsub = (lane >> 4) << 2;
  // ---- wave wv owns h-tile wv (rows wv*16..+15), all 8 l-tiles ----
  f32x4 acc[8];
#pragma unroll
  for (int ct = 0; ct < 8; ++ct) acc[ct] = (f32x4){0.f, 0.f, 0.f, 0.f};
#pragma unroll
  for (int kk = 0; kk < 2; ++kk) {
    bf16x8 ah = *(const bf16x8*)&Wh[(wv << 4) + lrow][(kk << 5) + lk8];
    bf16x8 al = *(const bf16x8*)&Wl[(wv << 4) + lrow][(kk << 5) + lk8];
#pragma unroll
    for (int ct = 0; ct < 8; ++ct) {
      bf16x8 bh = *(const bf16x8*)&xh[(ct << 4) + lrow][(kk << 5) + lk8];
      bf16x8 bl = *(const bf16x8*)&xl[(ct << 4) + lrow][(kk << 5) + lk8];
      acc[ct] = __builtin_amdgcn_mfma_f32_16x16x32_bf16(ah, bh, acc[ct], 0, 0, 0);
      acc[ct] = __builtin_amdgcn_mfma_f32_16x16x32_bf16(ah, bl, acc[ct], 0, 0, 0);
      acc[ct] = __builtin_amdgcn_mfma_f32_16x16x32_bf16(al, bh, acc[ct], 0, 0, 0);
    }
  }
  // ---- bias + store (row = h, col = l; C layout: col=lane&15, row=(lane>>4)*4+r) ----
  float bi[4];
#pragma unroll
  for (int r = 0; r < 4; ++r) bi[r] = bias[(hh << 7) + (wv << 4) + rsub + r];
#pragma unroll
  for (int ct = 0; ct < 8; ++ct) {
    int lglob = (lt << 7) + (ct << 4) + lrow;
#pragma unroll
    for (int r = 0; r < 4; ++r) {
      int hglob = (hh << 7) + (wv << 4) + rsub + r;
      hbuf[((size_t)(b * H_SZ + hglob) << 11) + lglob] = acc[ct][r] + bi[r];
    }
  }
}

// ---------------- convert w_out to bf16 ----------------
__global__ void k_cvtw(const float* __restrict__ w, unsigned short* __restrict__ wbf, int n) {
  int i = blockIdx.x * 256 + threadIdx.x;
  if (i < n) wbf[i] = f2b(w[i]);
}

// ---------------- precompute per-state params: lr, li, c2r, c2i, lTr, lTi ----------------
__global__ void k_params(const float* __restrict__ log_dt, const float* __restrict__ log_A_real,
                         const float* __restrict__ A_imag, const float* __restrict__ C_re,
                         const float* __restrict__ C_im, float* __restrict__ par) {
  int id = blockIdx.x * 256 + threadIdx.x;  // i*8192 + h*32 + n
  if (id >= NL * H_SZ * NH) return;
  int i = id >> 13;
  int hn = id & 8191;
  int h = hn >> 5;
  float dt = expf(log_dt[i * H_SZ + h]);
  float Ar = -expf(log_A_real[(size_t)i * H_SZ * NH + hn]);
  float Ai = A_imag[(size_t)i * H_SZ * NH + hn];
  float dr = dt * Ar, di = dt * Ai;
  float e = expf(dr), sn, cs;
  sincosf(di, &sn, &cs);
  float lr = e * cs, li = e * sn;
  float eT = expf((float)TC * dr), snT, csT;
  sincosf((float)TC * di, &snT, &csT);
  float Cr = C_re[(size_t)i * H_SZ * NH + hn], Ci = C_im[(size_t)i * H_SZ * NH + hn];
  float wr = lr - 1.f, wi = li;
  float pr = Cr * wr - Ci * wi;
  float pi = Cr * wi + Ci * wr;
  float inv = 2.f / fmaf(Ar, Ar, Ai * Ai);
  float4* p = (float4*)(par + (size_t)id * 8);
  p[0] = make_float4(lr, li, (pr * Ar + pi * Ai) * inv, (pi * Ar - pr * Ai) * inv);
  p[1] = make_float4(eT * csT, eT * snT, 0.f, 0.f);
}

// ---------------- chunk finals via compensated MFMA Vandermonde GEMM + in-kernel prefix ----
__launch_bounds__(512, 1)
__global__ void k_scanM(const float* __restrict__ hbuf, float2* __restrict__ sF2,
                        const float* __restrict__ par) {
  __shared__ __align__(16) unsigned short xbh[256][72];  // 36864 B
  __shared__ __align__(16) unsigned short xbl[256][72];  // 36864 B
  __shared__ __align__(16) unsigned short Uh[64][72];    //  9216 B
  __shared__ __align__(16) unsigned short Ul[64][72];    //  9216 B
  int tid = threadIdx.x;
  int h = blockIdx.x;

  if (tid < 64) {
    int n = tid >> 1, q = tid & 1;
    const float* pb = par + (size_t)(h * NH + n) * 8;
    float lr = pb[0], li = pb[1];
    float pr = 1.f, pi = 0.f;
    if (q) {
      float sr = lr, si = li;
#pragma unroll
      for (int t = 0; t < 5; ++t) { float nr2 = sr * sr - si * si; si = 2.f * sr * si; sr = nr2; }
      pr = sr; pi = si;
    }
    int p = q << 5;
    for (int s = 0; s < 32; ++s, ++p) {
      int col = 63 - p;
      unsigned short hr = f2b(pr);
      Uh[2 * n][col] = hr; Ul[2 * n][col] = f2b(pr - b2f(hr));
      unsigned short hm = f2b(pi);
      Uh[2 * n + 1][col] = hm; Ul[2 * n + 1][col] = f2b(pi - b2f(hm));
      float nr2 = pr * lr - pi * li;
      pi = pr * li + pi * lr;
      pr = nr2;
    }
  }

  int wv = tid >> 6, lane = tid & 63;
  int lrow = lane & 15, lk8 = (lane >> 4) << 3;
  int rt = wv >> 1;
  int ct0 = (wv & 1) << 3;

  for (int half = 0; half < 2; ++half) {
    __syncthreads();
    {
      int colh = tid >> 1, j0 = (tid & 1) << 5;
      int b = (half << 3) + (colh >> 5), c = colh & 31;
      const float* src = hbuf + ((size_t)(b * H_SZ + h) << 11) + (c << 6) + j0;
      unsigned short* dh = &xbh[colh][j0];
      unsigned short* dl = &xbl[colh][j0];
#pragma unroll
      for (int jj = 0; jj < 8; ++jj) {
        float4 v = *(const float4*)(src + jj * 4);
        unsigned short h0 = f2b(v.x); dh[jj * 4 + 0] = h0; dl[jj * 4 + 0] = f2b(v.x - b2f(h0));
        unsigned short h1 = f2b(v.y); dh[jj * 4 + 1] = h1; dl[jj * 4 + 1] = f2b(v.y - b2f(h1));
        unsigned short h2 = f2b(v.z); dh[jj * 4 + 2] = h2; dl[jj * 4 + 2] = f2b(v.z - b2f(h2));
        unsigned short h3 = f2b(v.w); dh[jj * 4 + 3] = h3; dl[jj * 4 + 3] = f2b(v.w - b2f(h3));
      }
    }
    __syncthreads();
    f32x4 acc[8];
#pragma unroll
    for (int ct = 0; ct < 8; ++ct) acc[ct] = (f32x4){0.f, 0.f, 0.f, 0.f};
#pragma unroll
    for (int kk = 0; kk < 2; ++kk) {
      bf16x8 ah = *(const bf16x8*)&Uh[(rt << 4) + lrow][(kk << 5) + lk8];
      bf16x8 al = *(const bf16x8*)&Ul[(rt << 4) + lrow][(kk << 5) + lk8];
#pragma unroll
      for (int ct = 0; ct < 8; ++ct) {
        int colh = ((ct0 + ct) << 4) + lrow;
        bf16x8 bh = *(const bf16x8*)&xbh[colh][(kk << 5) + lk8];
        bf16x8 bl = *(const bf16x8*)&xbl[colh][(kk << 5) + lk8];
        acc[ct] = __builtin_amdgcn_mfma_f32_16x16x32_bf16(ah, bh, acc[ct], 0, 0, 0);
        acc[ct] = __builtin_amdgcn_mfma_f32_16x16x32_bf16(ah, bl, acc[ct], 0, 0, 0);
        acc[ct] = __builtin_amdgcn_mfma_f32_16x16x32_bf16(al, bh, acc[ct], 0, 0, 0);
      }
    }
    {
      int n0 = (rt << 3) + ((lane >> 4) << 1);
#pragma unroll
      for (int ct = 0; ct < 8; ++ct) {
        int colg = (half << 8) + ((ct0 + ct) << 4) + lrow;
        float2* o = sF2 + (size_t)colg * (H_SZ * NH) + h * NH + n0;
        o[0] = make_float2(acc[ct][0], acc[ct][1]);
        o[1] = make_float2(acc[ct][2], acc[ct][3]);
      }
    }
  }
  __syncthreads();
  {
    int b = tid >> 5, n = tid & 31;
    const float* pb = par + (size_t)(h * NH + n) * 8;
    float lTr = pb[4], lTi = pb[5];
    float cr = 0.f, ci = 0.f;
    float2* p0 = sF2 + (size_t)(b << 5) * (H_SZ * NH) + h * NH + n;
    const size_t cstride = H_SZ * NH;
    float2 f = p0[0];
    for (int c = 0; c < NTC; ++c) {
      float2 fn = f;
      if (c + 1 < NTC) fn = p0[(size_t)(c + 1) * cstride];
      p0[(size_t)c * cstride] = make_float2(cr, ci);
      float nr = fmaf(lTr, cr, f.x); nr = fmaf(-lTi, ci, nr);
      float ni = fmaf(lTr, ci, f.y); ni = fmaf(lTi, cr, ni);
      cr = nr; ci = ni;
      f = fn;
    }
  }
}

// ---------------- S4D conv via per-h MFMA: y = T@x + W@s_in  (f32 out) ----------------
__launch_bounds__(512, 1)
__global__ void k_conv(const float* __restrict__ hbuf, const float2* __restrict__ sF2,
                       const float* __restrict__ par, float* __restrict__ yloc) {
  __shared__ __align__(16) unsigned short xbh[256][72];  // 36864 B (x / svec, hi)
  __shared__ __align__(16) unsigned short xbl[256][72];  // 36864 B (lo)
  __shared__ __align__(16) unsigned short Th[64][72];    //  9216 B
  __shared__ __align__(16) unsigned short Tl[64][72];
  __shared__ __align__(16) unsigned short Wh[64][72];
  __shared__ __align__(16) unsigned short Wl[64][72];
  __shared__ float Kc[64];
  int tid = threadIdx.x;
  int h = blockIdx.x;
  float* Wm = (float*)&xbh[0][0];  // [64][66] f32 scratch, consumed before x staging

  if (tid < 64) {
    int n = tid >> 1, q = tid & 1;
    const float* pb = par + (size_t)(h * NH + n) * 8;
    float lr = pb[0], li = pb[1], c2r = pb[2], c2i = pb[3];
    float pr = lr, pi = li;  // lam^1
    if (q) {                 // lam^33
      float sr = lr, si = li;
#pragma unroll
      for (int t = 0; t < 5; ++t) { float nr2 = sr * sr - si * si; si = 2.f * sr * si; sr = nr2; }
      pr = sr * lr - si * li; pi = sr * li + si * lr;
    }
    int p = q << 5;
    for (int s = 0; s < 32; ++s, ++p) {
      Wm[p * 66 + 2 * n] = c2r * pr - c2i * pi;
      Wm[p * 66 + 2 * n + 1] = -(c2r * pi + c2i * pr);
      float nr2 = pr * lr - pi * li;
      pi = pr * li + pi * lr;
      pr = nr2;
    }
  }
  __syncthreads();
  if (tid < 64) {
    float kv = 0.f;
    if (tid == 0) {
      for (int n = 0; n < 32; ++n) kv += par[(size_t)(h * NH + n) * 8 + 2];
    } else {
      for (int n = 0; n < 32; ++n) kv += Wm[(tid - 1) * 66 + 2 * n];
    }
    Kc[tid] = kv;
  }
  {
    int base = tid * 8;
    int row = base >> 6, col0 = base & 63;
#pragma unroll
    for (int e = 0; e < 8; ++e) {
      float v = Wm[row * 66 + col0 + e];
      unsigned short hv = f2b(v);
      Wh[row][col0 + e] = hv; Wl[row][col0 + e] = f2b(v - b2f(hv));
    }
  }
  __syncthreads();
  {
    int base = tid * 8;
    int row = base >> 6, col0 = base & 63;
#pragma unroll
    for (int e = 0; e < 8; ++e) {
      int col = col0 + e;
      float v = (col <= row) ? Kc[row - col] : 0.f;
      unsigned short hv = f2b(v);
      Th[row][col] = hv; Tl[row][col] = f2b(v - b2f(hv));
    }
  }

  int wv = tid >> 6, lane = tid & 63;
  int lrow = lane & 15, lk8 = (lane >> 4) << 3;
  int rt = wv >> 1;
  int ct0 = (wv & 1) << 3;
  int rsub = (lane >> 4) << 2;

  for (int half = 0; half < 2; ++half) {
    __syncthreads();
    {
      int colh = tid >> 1, j0 = (tid & 1) << 5;
      int b = (half << 3) + (colh >> 5), c = colh & 31;
      const float* src = hbuf + ((size_t)(b * H_SZ + h) << 11) + (c << 6) + j0;
      unsigned short* dh = &xbh[colh][j0];
      unsigned short* dl = &xbl[colh][j0];
#pragma unroll
      for (int jj = 0; jj < 8; ++jj) {
        float4 v = *(const float4*)(src + jj * 4);
        unsigned short h0 = f2b(v.x); dh[jj * 4 + 0] = h0; dl[jj * 4 + 0] = f2b(v.x - b2f(h0));
        unsigned short h1 = f2b(v.y); dh[jj * 4 + 1] = h1; dl[jj * 4 + 1] = f2b(v.y - b2f(h1));
        unsigned short h2 = f2b(v.z); dh[jj * 4 + 2] = h2; dl[jj * 4 + 2] = f2b(v.z - b2f(h2));
        unsigned short h3 = f2b(v.w); dh[jj * 4 + 3] = h3; dl[jj * 4 + 3] = f2b(v.w - b2f(h3));
      }
    }
    __syncthreads();
    f32x4 acc[8];
#pragma unroll
    for (int ct = 0; ct < 8; ++ct) acc[ct] = (f32x4){0.f, 0.f, 0.f, 0.f};
#pragma unroll
    for (int kk = 0; kk < 2; ++kk) {
      bf16x8 ah = *(const bf16x8*)&Th[(rt << 4) + lrow][(kk << 5) + lk8];
      bf16x8 al = *(const bf16x8*)&Tl[(rt << 4) + lrow][(kk << 5) + lk8];
#pragma unroll
      for (int ct = 0; ct < 8; ++ct) {
        int col = ((ct0 + ct) << 4) + lrow;
        bf16x8 bh = *(const bf16x8*)&xbh[col][(kk << 5) + lk8];
        bf16x8 bl = *(const bf16x8*)&xbl[col][(kk << 5) + lk8];
        acc[ct] = __builtin_amdgcn_mfma_f32_16x16x32_bf16(ah, bh, acc[ct], 0, 0, 0);
        acc[ct] = __builtin_amdgcn_mfma_f32_16x16x32_bf16(ah, bl, acc[ct], 0, 0, 0);
        acc[ct] = __builtin_amdgcn_mfma_f32_16x16x32_bf16(al, bh, acc[ct], 0, 0, 0);
      }
    }
    __syncthreads();
    {
      int colh = tid >> 1, n0 = (tid & 1) << 4;
      int colg = (half << 8) + colh;
      const float2* cp = sF2 + (size_t)colg * (H_SZ * NH) + h * NH;
#pragma unroll
      for (int n = 0; n < 16; ++n) {
        float2 s = cp[n0 + n];
        int k2 = 2 * (n0 + n);
        unsigned short hr = f2b(s.x);
        xbh[colh][k2] = hr; xbl[colh][k2] = f2b(s.x - b2f(hr));
        unsigned short hm = f2b(s.y);
        xbh[colh][k2 + 1] = hm; xbl[colh][k2 + 1] = f2b(s.y - b2f(hm));
      }
    }
    __syncthreads();
#pragma unroll
    for (int kk = 0; kk < 2; ++kk) {
      bf16x8 ah = *(const bf16x8*)&Wh[(rt << 4) + lrow][(kk << 5) + lk8];
      bf16x8 al = *(const bf16x8*)&Wl[(rt << 4) + lrow][(kk << 5) + lk8];
#pragma unroll
      for (int ct = 0; ct < 8; ++ct) {
        int col = ((ct0 + ct) << 4) + lrow;
        bf16x8 bh = *(const bf16x8*)&xbh[col][(kk << 5) + lk8];
        bf16x8 bl = *(const bf16x8*)&xbl[col][(kk << 5) + lk8];
        acc[ct] = __builtin_amdgcn_mfma_f32_16x16x32_bf16(ah, bh, acc[ct], 0, 0, 0);
        acc[ct] = __builtin_amdgcn_mfma_f32_16x16x32_bf16(ah, bl, acc[ct], 0, 0, 0);
        acc[ct] = __builtin_amdgcn_mfma_f32_16x16x32_bf16(al, bh, acc[ct], 0, 0, 0);
      }
    }
#pragma unroll
    for (int ct = 0; ct < 8; ++ct) {
      int colg = (half << 8) + ((ct0 + ct) << 4) + lrow;
      float4 o = make_float4(acc[ct][0], acc[ct][1], acc[ct][2], acc[ct][3]);
      *(float4*)(yloc + (size_t)h * (B_SZ * L_SZ) + (size_t)colg * 64 + (rt << 4) + rsub) = o;
    }
  }
}

// ---------------- post: fill(y+Dx)+GELU + GLU + LN ----------------
__launch_bounds__(1024, 4)
__global__ void k_layer2(float* __restrict__ hbuf, const float* __restrict__ yloc,
                         const float* __restrict__ D_skip,
                         const unsigned short* __restrict__ wbf,
                         const float* __restrict__ b_out,
                         const float* __restrict__ ln_g, const float* __restrict__ ln_b,
                         float* __restrict__ pooledPart, int last) {
  __shared__ __align__(16) unsigned short yt[TC][H_SZ + 8];
  __shared__ float part[TC][16][2];
  __shared__ float stats[TC][2];
  int tid = threadIdx.x;
  int b = blockIdx.x >> 5;
  int c = blockIdx.x & 31;
  int l0 = c << 6;

  {
    int h = tid >> 2, q = tid & 3;
    float Dh = D_skip[h];
    const float* xp = hbuf + ((size_t)(b * H_SZ + h) << 11) + l0 + (q << 4);
    const float* yp2 = yloc + (size_t)h * (B_SZ * L_SZ) + b * L_SZ + l0 + (q << 4);
#pragma unroll
    for (int jj = 0; jj < 16; jj += 4) {
      float4 xv = *(const float4*)(xp + jj);
      float4 yv = *(const float4*)(yp2 + jj);
      int jb = (q << 4) + jj;
      yt[jb + 0][h] = f2b(gelu_exact(fmaf(Dh, xv.x, yv.x)));
      yt[jb + 1][h] = f2b(gelu_exact(fmaf(Dh, xv.y, yv.y)));
      yt[jb + 2][h] = f2b(gelu_exact(fmaf(Dh, xv.z, yv.z)));
      yt[jb + 3][h] = f2b(gelu_exact(fmaf(Dh, xv.w, yv.w)));
    }
  }
  __syncthreads();
  {
    int w = tid >> 6, lane = tid & 63;
    int lrow = lane & 15, lk8 = (lane >> 4) << 3;
    f32x4 accA[4], accG[4];
    f32x4 zed = {0.f, 0.f, 0.f, 0.f};
#pragma unroll
    for (int jt = 0; jt < 4; ++jt) { accA[jt] = zed; accG[jt] = zed; }
    const unsigned short* wA = wbf + ((w << 4) + lrow) * H_SZ;
    const unsigned short* wG = wA + 256 * H_SZ;
#pragma unroll
    for (int k0 = 0; k0 < H_SZ; k0 += 32) {
      bf16x8 a0 = *(const bf16x8*)(wA + k0 + lk8);
      bf16x8 a1 = *(const bf16x8*)(wG + k0 + lk8);
#pragma unroll
      for (int jt = 0; jt < 4; ++jt) {
        bf16x8 bb = *(const bf16x8*)(&yt[(jt << 4) + lrow][k0 + lk8]);
        accA[jt] = __builtin_amdgcn_mfma_f32_16x16x32_bf16(a0, bb, accA[jt], 0, 0, 0);
        accG[jt] = __builtin_amdgcn_mfma_f32_16x16x32_bf16(a1, bb, accG[jt], 0, 0, 0);
      }
    }
    __syncthreads();
    int rbase = (lane >> 4) << 2;
    float bA[4], bG[4];
#pragma unroll
    for (int r = 0; r < 4; ++r) {
      bA[r] = b_out[(w << 4) + rbase + r];
      bG[r] = b_out[256 + (w << 4) + rbase + r];
    }
#pragma unroll
    for (int jt = 0; jt < 4; ++jt) {
#pragma unroll
      for (int r = 0; r < 4; ++r) {
        float a = accA[jt][r] + bA[r];
        float g = accG[jt][r] + bG[r];
        float z = a / (1.f + expf(-g));
        yt[(jt << 4) + lrow][(w << 4) + rbase + r] = f2b(z);
      }
    }
  }
  __syncthreads();
  int j = tid & 63, hg = tid >> 6;
  float vreg[16];
  {
    const float* xc = hbuf + (b * H_SZ + (hg << 4)) * L_SZ + l0 + j;
    float s = 0.f, sq = 0.f;
#pragma unroll
    for (int k = 0; k < 16; ++k) {
      float v = b2f(yt[j][(hg << 4) + k]) + xc[(size_t)k * L_SZ];
      vreg[k] = v;
      s += v; sq = fmaf(v, v, sq);
    }
    part[j][hg][0] = s; part[j][hg][1] = sq;
  }
  __syncthreads();
  if (tid < TC) {
    float s = 0.f, sq = 0.f;
#pragma unroll
    for (int g = 0; g < 16; ++g) { s += part[tid][g][0]; sq += part[tid][g][1]; }
    float mu = s * (1.f / 256.f);
    float var = sq * (1.f / 256.f) - mu * mu;
    stats[tid][0] = mu;
    stats[tid][1] = rsqrtf(var + 1e-5f);
  }
  __syncthreads();
  {
    float mu = stats[j][0], rs = stats[j][1];
    if (!last) {
      float* xo = hbuf + (b * H_SZ + (hg << 4)) * L_SZ + l0 + j;
#pragma unroll
      for (int k = 0; k < 16; ++k) {
        int hh = (hg << 4) + k;
        xo[(size_t)k * L_SZ] = (vreg[k] - mu) * rs * ln_g[hh] + ln_b[hh];
      }
    } else {
#pragma unroll
      for (int k = 0; k < 16; ++k) {
        int hh = (hg << 4) + k;
        yt[j][hh] = f2b((vreg[k] - mu) * rs * ln_g[hh] + ln_b[hh]);
      }
      __syncthreads();
      if (tid < H_SZ) {
        float s = 0.f;
        for (int jj = 0; jj < TC; ++jj) s += b2f(yt[jj][tid]);
        pooledPart[(((b << 5) + c) << 8) + tid] = s;
      }
    }
  }
}

// ---------------- legacy fused per-layer kernel (fallback if ws too small) ----------------
__launch_bounds__(1024, 4)
__global__ void k_layer(float* __restrict__ hbuf, const float4* __restrict__ sFin,
                        const float* __restrict__ par,
                        const float* __restrict__ D_skip,
                        const unsigned short* __restrict__ wbf,
                        const float* __restrict__ b_out,
                        const float* __restrict__ ln_g, const float* __restrict__ ln_b,
                        float* __restrict__ pooledPart, int last) {
  __shared__ __align__(16) unsigned short yt[TC][H_SZ + 8];
  __shared__ float part[TC][16][2];
  __shared__ float stats[TC][2];
  int tid = threadIdx.x;
  int b = blockIdx.x >> 5;
  int c = blockIdx.x & 31;
  int l0 = c << 6;
  {
    int h = tid >> 2, ng = tid & 3;
    const float4* pp = (const float4*)(par + (size_t)(h * NH + ng * 8) * 8);
    float lr[8], li[8], c2r[8], c2i[8], sre[8], sim[8];
    const float4* fp = sFin + (((size_t)((b << 5) + c) * H_SZ + h) * 4 + ng) * 4;
#pragma unroll
    for (int q = 0; q < 4; ++q) {
      float4 f = fp[q];
      sre[2 * q] = f.x; sim[2 * q] = f.y;
      sre[2 * q + 1] = f.z; sim[2 * q + 1] = f.w;
    }
#pragma unroll
    for (int k = 0; k < 8; ++k) {
      float4 p0 = pp[k * 2];
      lr[k] = p0.x; li[k] = p0.y; c2r[k] = p0.z; c2i[k] = p0.w;
    }
    float Dh = D_skip[h];
    const float* xp = hbuf + (b * H_SZ + h) * L_SZ + l0;
    float4 xv = *(const float4*)xp;
    for (int j4 = 0; j4 < TC; j4 += 4) {
      float4 xn = xv;
      if (j4 + 4 < TC) xn = *(const float4*)(xp + j4 + 4);
      float xe[4] = {xv.x, xv.y, xv.z, xv.w};
#pragma unroll
      for (int e = 0; e < 4; ++e) {
        float xj = xe[e];
        float yp0 = 0.f, yp1 = 0.f;
#pragma unroll
        for (int k = 0; k < 8; ++k) {
          float nr = fmaf(lr[k], sre[k], xj);
          nr = fmaf(-li[k], sim[k], nr);
          float ni = lr[k] * sim[k];
          ni = fmaf(li[k], sre[k], ni);
          sre[k] = nr; sim[k] = ni;
          if (k & 1) {
            yp1 = fmaf(c2r[k], nr, yp1);
            yp1 = fmaf(-c2i[k], ni, yp1);
          } else {
            yp0 = fmaf(c2r[k], nr, yp0);
            yp0 = fmaf(-c2i[k], ni, yp0);
          }
        }
        float yp = yp0 + yp1;
        yp += __shfl_xor(yp, 1);
        yp += __shfl_xor(yp, 2);
        if (ng == 0) yt[j4 + e][h] = f2b(fmaf(Dh, xj, yp));
      }
      xv = xn;
    }
  }
  __syncthreads();
  for (int it = 0; it < 8; ++it) {
    int id = it * 1024 + tid;
    int jr = id >> 7, hp = id & 127;
    unsigned int u = *(unsigned int*)&yt[jr][hp * 2];
    float v0 = b2f((unsigned short)(u & 0xffff));
    float v1 = b2f((unsigned short)(u >> 16));
    v0 = gelu_exact(v0);
    v1 = gelu_exact(v1);
    *(unsigned int*)&yt[jr][hp * 2] = (unsigned int)f2b(v0) | ((unsigned int)f2b(v1) << 16);
  }
  __syncthreads();
  {
    int w = tid >> 6, lane = tid & 63;
    int lrow = lane & 15, lk8 = (lane >> 4) << 3;
    f32x4 accA[4], accG[4];
    f32x4 zed = {0.f, 0.f, 0.f, 0.f};
#pragma unroll
    for (int jt = 0; jt < 4; ++jt) { accA[jt] = zed; accG[jt] = zed; }
    const unsigned short* wA = wbf + ((w << 4) + lrow) * H_SZ;
    const unsigned short* wG = wA + 256 * H_SZ;
#pragma unroll
    for (int k0 = 0; k0 < H_SZ; k0 += 32) {
      bf16x8 a0 = *(const bf16x8*)(wA + k0 + lk8);
      bf16x8 a1 = *(const bf16x8*)(wG + k0 + lk8);
#pragma unroll
      for (int jt = 0; jt < 4; ++jt) {
        bf16x8 bb = *(const bf16x8*)(&yt[(jt << 4) + lrow][k0 + lk8]);
        accA[jt] = __builtin_amdgcn_mfma_f32_16x16x32_bf16(a0, bb, accA[jt], 0, 0, 0);
        accG[jt] = __builtin_amdgcn_mfma_f32_16x16x32_bf16(a1, bb, accG[jt], 0, 0, 0);
      }
    }
    __syncthreads();
    int rbase = (lane >> 4) << 2;
    float bA[4], bG[4];
#pragma unroll
    for (int r = 0; r < 4; ++r) {
      bA[r] = b_out[(w << 4) + rbase + r];
      bG[r] = b_out[256 + (w << 4) + rbase + r];
    }
#pragma unroll
    for (int jt = 0; jt < 4; ++jt) {
#pragma unroll
      for (int r = 0; r < 4; ++r) {
        float a = accA[jt][r] + bA[r];
        float g = accG[jt][r] + bG[r];
        float z = a / (1.f + expf(-g));
        yt[(jt << 4) + lrow][(w << 4) + rbase + r] = f2b(z);
      }
    }
  }
  __syncthreads();
  int j = tid & 63, hg = tid >> 6;
  float vreg[16];
  {
    const float* xc = hbuf + (b * H_SZ + (hg << 4)) * L_SZ + l0 + j;
    float s = 0.f, sq = 0.f;
#pragma unroll
    for (int k = 0; k < 16; ++k) {
      float v = b2f(yt[j][(hg << 4) + k]) + xc[(size_t)k * L_SZ];
      vreg[k] = v;
      s += v; sq = fmaf(v, v, sq);
    }
    part[j][hg][0] = s; part[j][hg][1] = sq;
  }
  __syncthreads();
  if (tid < TC) {
    float s = 0.f, sq = 0.f;
#pragma unroll
    for (int g = 0; g < 16; ++g) { s += part[tid][g][0]; sq += part[tid][g][1]; }
    float mu = s * (1.f / 256.f);
    float var = sq * (1.f / 256.f) - mu * mu;
    stats[tid][0] = mu;
    stats[tid][1] = rsqrtf(var + 1e-5f);
  }
  __syncthreads();
  {
    float mu = stats[j][0], rs = stats[j][1];
    if (!last) {
      float* xo = hbuf + (b * H_SZ + (hg << 4)) * L_SZ + l0 + j;
#pragma unroll
      for (int k = 0; k < 16; ++k) {
        int hh = (hg << 4) + k;
        xo[(size_t)k * L_SZ] = (vreg[k] - mu) * rs * ln_g[hh] + ln_b[hh];
      }
    } else {
#pragma unroll
      for (int k = 0; k < 16; ++k) {
        int hh = (hg << 4) + k;
        yt[j][hh] = f2b((vreg[k] - mu) * rs * ln_g[hh] + ln_b[hh]);
      }
      __syncthreads();
      if (tid < H_SZ) {
        float s = 0.f;
        for (int jj = 0; jj < TC; ++jj) s += b2f(yt[jj][tid]);
        pooledPart[(((b << 5) + c) << 8) + tid] = s;
      }
    }
  }
}

// ---------------- decoder MLP (single block) with pooling preamble ----------------
__global__ void k_decoder(const float* __restrict__ pooledPart,
                          const float* __restrict__ w1, const float* __restrict__ b1,
                          const float* __restrict__ w2, const float* __restrict__ b2,
                          const float* __restrict__ w3, const float* __restrict__ b3,
                          float* __restrict__ out) {
  __shared__ float P[16 * 256];
  __shared__ float O1[16 * 128];
  __shared__ float O2[16 * 64];
  int tid = threadIdx.x;
  for (int id = tid; id < 16 * 256; id += 256) {
    int b = id >> 8, hh = id & 255;
    float s = 0.f;
#pragma unroll
    for (int cpart = 0; cpart < 32; ++cpart)
      s += pooledPart[(((b << 5) + cpart) << 8) + hh];
    P[id] = s * (1.f / 2048.f);
  }
  __syncthreads();
  for (int id = tid; id < 16 * 128; id += 256) {
    int r = id >> 7, cc = id & 127;
    float acc = b1[cc];
    for (int d = 0; d < 256; ++d) acc = fmaf(P[(r << 8) + d], w1[(d << 7) + cc], acc);
    O1[id] = fmaxf(acc, 0.f);
  }
  __syncthreads();
  for (int id = tid; id < 16 * 64; id += 256) {
    int r = id >> 6, cc = id & 63;
    float acc = b2[cc];
    for (int d = 0; d < 128; ++d) acc = fmaf(O1[(r << 7) + d], w2[(d << 6) + cc], acc);
    O2[id] = fmaxf(acc, 0.f);
  }
  __syncthreads();
  for (int id = tid; id < 16 * 32; id += 256) {
    int r = id >> 5, cc = id & 31;
    float acc = b3[cc];
    for (int d = 0; d < 64; ++d) acc = fmaf(O2[(r << 6) + d], w3[(d << 5) + cc], acc);
    out[id] = acc;
  }
}

extern "C" void kernel_launch(void* const* d_in, const int* in_sizes, int n_in,
                              void* d_out, int out_size, void* d_ws, size_t ws_size,
                              hipStream_t stream) {
  const float* x          = (const float*)d_in[0];
  const float* enc_w      = (const float*)d_in[1];
  const float* enc_b      = (const float*)d_in[2];
  const float* log_dt     = (const float*)d_in[3];
  const float* C_re       = (const float*)d_in[4];
  const float* C_im       = (const float*)d_in[5];
  const float* log_A_real = (const float*)d_in[6];
  const float* A_imag     = (const float*)d_in[7];
  const float* D_skip     = (const float*)d_in[8];
  const float* w_out      = (const float*)d_in[9];
  const float* b_out      = (const float*)d_in[10];
  const float* ln_g       = (const float*)d_in[11];
  const float* ln_b       = (const float*)d_in[12];
  const float* dw1        = (const float*)d_in[13];
  const float* db1        = (const float*)d_in[14];
  const float* dw2        = (const float*)d_in[15];
  const float* db2        = (const float*)d_in[16];
  const float* dw3        = (const float*)d_in[17];
  const float* db3        = (const float*)d_in[18];

  char* ws = (char*)d_ws;
  float* hbuf = (float*)ws;                                  // 33,554,432 B
  float2* sF2 = (float2*)(ws + 33554432);                    // 33,554,432 B
  const size_t NEED_BIG = 33554432ull * 3 + 1048576 * 2 + 524288;
  bool big = ws_size >= NEED_BIG;
  float* yloc;
  unsigned short* wbf;
  float* par;
  float* pooledPart;
  if (big) {
    yloc = (float*)(ws + 67108864);                          // 33,554,432 B
    wbf = (unsigned short*)(ws + 100663296);                 //  1,048,576 B
    par = (float*)(ws + 101711872);                          //  1,048,576 B
    pooledPart = (float*)(ws + 102760448);                   //    524,288 B
  } else {
    yloc = nullptr;
    wbf = (unsigned short*)(ws + 67108864);
    par = (float*)(ws + 68157440);
    pooledPart = (float*)(ws + 69206016);
  }

  k_encoder<<<512, 512, 0, stream>>>(x, enc_w, enc_b, hbuf);
  k_cvtw<<<2048, 256, 0, stream>>>(w_out, wbf, NL * 512 * H_SZ);
  k_params<<<128, 256, 0, stream>>>(log_dt, log_A_real, A_imag, C_re, C_im, par);
  const size_t PAR_STRIDE = (size_t)H_SZ * NH * 8;
  for (int i = 0; i < NL; ++i) {
    const float* pari = par + i * PAR_STRIDE;
    k_scanM<<<256, 512, 0, stream>>>(hbuf, sF2, pari);
    if (big) {
      k_conv<<<256, 512, 0, stream>>>(hbuf, sF2, pari, yloc);
      k_layer2<<<512, 1024, 0, stream>>>(hbuf, yloc,
                                         D_skip + i * H_SZ, wbf + i * 512 * H_SZ,
                                         b_out + i * 512, ln_g + i * H_SZ, ln_b + i * H_SZ,
                                         pooledPart, (i == NL - 1) ? 1 : 0);
    } else {
      k_layer<<<512, 1024, 0, stream>>>(hbuf, (const float4*)sF2, pari,
                                        D_skip + i * H_SZ, wbf + i * 512 * H_SZ,
                                        b_out + i * 512, ln_g + i * H_SZ, ln_b + i * H_SZ,
                                        pooledPart, (i == NL - 1) ? 1 : 0);
    }
  }
  k_decoder<<<1, 256, 0, stream>>>(pooledPart, dw1, db1, dw2, db2, dw3, db3, (float*)d_out);
}

// Round 12
// 406.339 us; speedup vs baseline: 2.5762x; 1.2175x over previous
//
#include <hip/hip_runtime.h>

#define B_SZ 16
#define L_SZ 2048
#define DIN 64
#define H_SZ 256
#define NH 32
#define NL 4
#define TC 64
#define NTC 32

typedef __attribute__((ext_vector_type(8))) __bf16 bf16x8;
typedef __attribute__((ext_vector_type(4))) float f32x4;

__device__ __forceinline__ unsigned short f2b(float f) {
  unsigned int u = __builtin_bit_cast(unsigned int, f);
  unsigned int r = u + 0x7fffu + ((u >> 16) & 1u);  // RNE (no NaN inputs here)
  return (unsigned short)(r >> 16);
}
__device__ __forceinline__ float b2f(unsigned short u) {
  unsigned int v = ((unsigned int)u) << 16;
  return __builtin_bit_cast(float, v);
}
__device__ __forceinline__ float gelu_exact(float v) {
  return 0.5f * v * (1.f + erff(v * 0.70710678118654752f));
}

// ---------------- encoder as compensated MFMA GEMM ----------------
__launch_bounds__(512, 4)
__global__ void k_encoder(const float* __restrict__ x, const float* __restrict__ w,
                          const float* __restrict__ bias, float* __restrict__ hbuf) {
  __shared__ __align__(16) unsigned short Wh[128][72];
  __shared__ __align__(16) unsigned short Wl[128][72];
  __shared__ __align__(16) unsigned short xh[128][72];
  __shared__ __align__(16) unsigned short xl[128][72];
  int tid = threadIdx.x;
  int blk = blockIdx.x;           // b(4b) lt(4b) hh(1b)
  int b = blk >> 5;
  int lt = (blk >> 1) & 15;
  int hh = blk & 1;

#pragma unroll
  for (int i = 0; i < 16; ++i) {
    int flat = i * 512 + tid;
    int d = flat >> 7, hl = flat & 127;
    float v = w[d * H_SZ + (hh << 7) + hl];
    unsigned short hv = f2b(v);
    Wh[hl][d] = hv; Wl[hl][d] = f2b(v - b2f(hv));
  }
  {
    int l = tid >> 2, d0 = (tid & 3) << 4;
    const float* src = x + ((size_t)(b * L_SZ + (lt << 7) + l) << 6) + d0;
    unsigned short* dh = &xh[l][d0];
    unsigned short* dl = &xl[l][d0];
#pragma unroll
    for (int jj = 0; jj < 4; ++jj) {
      float4 v = *(const float4*)(src + jj * 4);
      unsigned short h0 = f2b(v.x); dh[jj * 4 + 0] = h0; dl[jj * 4 + 0] = f2b(v.x - b2f(h0));
      unsigned short h1 = f2b(v.y); dh[jj * 4 + 1] = h1; dl[jj * 4 + 1] = f2b(v.y - b2f(h1));
      unsigned short h2 = f2b(v.z); dh[jj * 4 + 2] = h2; dl[jj * 4 + 2] = f2b(v.z - b2f(h2));
      unsigned short h3 = f2b(v.w); dh[jj * 4 + 3] = h3; dl[jj * 4 + 3] = f2b(v.w - b2f(h3));
    }
  }
  __syncthreads();

  int wv = tid >> 6, lane = tid & 63;
  int lrow = lane & 15, lk8 = (lane >> 4) << 3;
  int rsub = (lane >> 4) << 2;
  f32x4 acc[8];
#pragma unroll
  for (int ct = 0; ct < 8; ++ct) acc[ct] = (f32x4){0.f, 0.f, 0.f, 0.f};
#pragma unroll
  for (int kk = 0; kk < 2; ++kk) {
    bf16x8 ah = *(const bf16x8*)&Wh[(wv << 4) + lrow][(kk << 5) + lk8];
    bf16x8 al = *(const bf16x8*)&Wl[(wv << 4) + lrow][(kk << 5) + lk8];
#pragma unroll
    for (int ct = 0; ct < 8; ++ct) {
      bf16x8 bh = *(const bf16x8*)&xh[(ct << 4) + lrow][(kk << 5) + lk8];
      bf16x8 bl = *(const bf16x8*)&xl[(ct << 4) + lrow][(kk << 5) + lk8];
      acc[ct] = __builtin_amdgcn_mfma_f32_16x16x32_bf16(ah, bh, acc[ct], 0, 0, 0);
      acc[ct] = __builtin_amdgcn_mfma_f32_16x16x32_bf16(ah, bl, acc[ct], 0, 0, 0);
      acc[ct] = __builtin_amdgcn_mfma_f32_16x16x32_bf16(al, bh, acc[ct], 0, 0, 0);
    }
  }
  float bi[4];
#pragma unroll
  for (int r = 0; r < 4; ++r) bi[r] = bias[(hh << 7) + (wv << 4) + rsub + r];
#pragma unroll
  for (int ct = 0; ct < 8; ++ct) {
    int lglob = (lt << 7) + (ct << 4) + lrow;
#pragma unroll
    for (int r = 0; r < 4; ++r) {
      int hglob = (hh << 7) + (wv << 4) + rsub + r;
      hbuf[((size_t)(b * H_SZ + hglob) << 11) + lglob] = acc[ct][r] + bi[r];
    }
  }
}

// ---------------- convert w_out to bf16 ----------------
__global__ void k_cvtw(const float* __restrict__ w, unsigned short* __restrict__ wbf, int n) {
  int i = blockIdx.x * 256 + threadIdx.x;
  if (i < n) wbf[i] = f2b(w[i]);
}

// ---------------- precompute per-state params: lr, li, c2r, c2i, lTr, lTi ----------------
__global__ void k_params(const float* __restrict__ log_dt, const float* __restrict__ log_A_real,
                         const float* __restrict__ A_imag, const float* __restrict__ C_re,
                         const float* __restrict__ C_im, float* __restrict__ par) {
  int id = blockIdx.x * 256 + threadIdx.x;  // i*8192 + h*32 + n
  if (id >= NL * H_SZ * NH) return;
  int i = id >> 13;
  int hn = id & 8191;
  int h = hn >> 5;
  float dt = expf(log_dt[i * H_SZ + h]);
  float Ar = -expf(log_A_real[(size_t)i * H_SZ * NH + hn]);
  float Ai = A_imag[(size_t)i * H_SZ * NH + hn];
  float dr = dt * Ar, di = dt * Ai;
  float e = expf(dr), sn, cs;
  sincosf(di, &sn, &cs);
  float lr = e * cs, li = e * sn;
  float eT = expf((float)TC * dr), snT, csT;
  sincosf((float)TC * di, &snT, &csT);
  float Cr = C_re[(size_t)i * H_SZ * NH + hn], Ci = C_im[(size_t)i * H_SZ * NH + hn];
  float wr = lr - 1.f, wi = li;
  float pr = Cr * wr - Ci * wi;
  float pi = Cr * wi + Ci * wr;
  float inv = 2.f / fmaf(Ar, Ar, Ai * Ai);
  float4* p = (float4*)(par + (size_t)id * 8);
  p[0] = make_float4(lr, li, (pr * Ar + pi * Ai) * inv, (pi * Ar - pr * Ai) * inv);
  p[1] = make_float4(eT * csT, eT * snT, 0.f, 0.f);
}

// ---------------- merged SSM kernel: finals + prefix + conv, one x staging ----------------
// block = one h, 512 threads. sF2 scratch for finals->carries; y out bf16.
__launch_bounds__(512, 1)
__global__ void k_ssm(const float* __restrict__ hbuf, float2* __restrict__ sF2,
                      const float* __restrict__ par, unsigned short* __restrict__ yloc) {
  __shared__ __align__(16) unsigned short xbh[256][72];  // 36864 (x / svec hi; Wm overlay)
  __shared__ __align__(16) unsigned short xbl[256][72];  // 36864 (lo)
  __shared__ __align__(16) unsigned short Uh[64][72];    // 9216
  __shared__ __align__(16) unsigned short Ul[64][72];
  __shared__ __align__(16) unsigned short Th[64][72];
  __shared__ __align__(16) unsigned short Tl[64][72];
  __shared__ __align__(16) unsigned short Wh[64][72];
  __shared__ __align__(16) unsigned short Wl[64][72];    // 6*9216 = 55296
  __shared__ float Kc[64];                               // total 129280 B
  int tid = threadIdx.x;
  int h = blockIdx.x;
  float* Wm = (float*)&xbh[0][0];  // [64][66] f32 scratch (16896 B), dead before x staging

  // ---- build Wm[p][2n] = Re(c2*lam^{p+1}), [2n+1] = -Im ----
  if (tid < 64) {
    int n = tid >> 1, q = tid & 1;
    const float* pb = par + (size_t)(h * NH + n) * 8;
    float lr = pb[0], li = pb[1], c2r = pb[2], c2i = pb[3];
    float pr = lr, pi = li;  // lam^1
    if (q) {                 // lam^33
      float sr = lr, si = li;
#pragma unroll
      for (int t = 0; t < 5; ++t) { float nr2 = sr * sr - si * si; si = 2.f * sr * si; sr = nr2; }
      pr = sr * lr - si * li; pi = sr * li + si * lr;
    }
    int p = q << 5;
    for (int s = 0; s < 32; ++s, ++p) {
      Wm[p * 66 + 2 * n] = c2r * pr - c2i * pi;
      Wm[p * 66 + 2 * n + 1] = -(c2r * pi + c2i * pr);
      float nr2 = pr * lr - pi * li;
      pi = pr * li + pi * lr;
      pr = nr2;
    }
  }
  __syncthreads();
  // ---- Kc from Wm/par; Wh/Wl from Wm ----
  if (tid < 64) {
    float kv = 0.f;
    if (tid == 0) {
      for (int n = 0; n < 32; ++n) kv += par[(size_t)(h * NH + n) * 8 + 2];
    } else {
      for (int n = 0; n < 32; ++n) kv += Wm[(tid - 1) * 66 + 2 * n];
    }
    Kc[tid] = kv;
  }
  {
    int base = tid * 8;
    int row = base >> 6, col0 = base & 63;
#pragma unroll
    for (int e = 0; e < 8; ++e) {
      float v = Wm[row * 66 + col0 + e];
      unsigned short hv = f2b(v);
      Wh[row][col0 + e] = hv; Wl[row][col0 + e] = f2b(v - b2f(hv));
    }
  }
  __syncthreads();
  // ---- Th/Tl from Kc (all threads); Uh/Ul power chain (tid<64) ----
  {
    int base = tid * 8;
    int row = base >> 6, col0 = base & 63;
#pragma unroll
    for (int e = 0; e < 8; ++e) {
      int col = col0 + e;
      float v = (col <= row) ? Kc[row - col] : 0.f;
      unsigned short hv = f2b(v);
      Th[row][col] = hv; Tl[row][col] = f2b(v - b2f(hv));
    }
  }
  if (tid < 64) {
    int n = tid >> 1, q = tid & 1;
    const float* pb = par + (size_t)(h * NH + n) * 8;
    float lr = pb[0], li = pb[1];
    float pr = 1.f, pi = 0.f;
    if (q) {
      float sr = lr, si = li;
#pragma unroll
      for (int t = 0; t < 5; ++t) { float nr2 = sr * sr - si * si; si = 2.f * sr * si; sr = nr2; }
      pr = sr; pi = si;
    }
    int p = q << 5;
    for (int s = 0; s < 32; ++s, ++p) {
      int col = 63 - p;
      unsigned short hr = f2b(pr);
      Uh[2 * n][col] = hr; Ul[2 * n][col] = f2b(pr - b2f(hr));
      unsigned short hm = f2b(pi);
      Uh[2 * n + 1][col] = hm; Ul[2 * n + 1][col] = f2b(pi - b2f(hm));
      float nr2 = pr * lr - pi * li;
      pi = pr * li + pi * lr;
      pr = nr2;
    }
  }

  int wv = tid >> 6, lane = tid & 63;
  int lrow = lane & 15, lk8 = (lane >> 4) << 3;
  int rt = wv >> 1;
  int ct0 = (wv & 1) << 3;
  int rsub = (lane >> 4) << 2;

  for (int half = 0; half < 2; ++half) {
    __syncthreads();  // matrices ready / previous half's svec reads done
    // ---- stage x hi/lo (single staging serves U-GEMM and T-GEMM) ----
    {
      int colh = tid >> 1, j0 = (tid & 1) << 5;
      int b = (half << 3) + (colh >> 5), c = colh & 31;
      const float* src = hbuf + ((size_t)(b * H_SZ + h) << 11) + (c << 6) + j0;
      unsigned short* dh = &xbh[colh][j0];
      unsigned short* dl = &xbl[colh][j0];
#pragma unroll
      for (int jj = 0; jj < 8; ++jj) {
        float4 v = *(const float4*)(src + jj * 4);
        unsigned short h0 = f2b(v.x); dh[jj * 4 + 0] = h0; dl[jj * 4 + 0] = f2b(v.x - b2f(h0));
        unsigned short h1 = f2b(v.y); dh[jj * 4 + 1] = h1; dl[jj * 4 + 1] = f2b(v.y - b2f(h1));
        unsigned short h2 = f2b(v.z); dh[jj * 4 + 2] = h2; dl[jj * 4 + 2] = f2b(v.z - b2f(h2));
        unsigned short h3 = f2b(v.w); dh[jj * 4 + 3] = h3; dl[jj * 4 + 3] = f2b(v.w - b2f(h3));
      }
    }
    __syncthreads();
    // ---- U-GEMM: chunk finals -> sF2 (f32) ----
    {
      f32x4 uacc[8];
#pragma unroll
      for (int ct = 0; ct < 8; ++ct) uacc[ct] = (f32x4){0.f, 0.f, 0.f, 0.f};
#pragma unroll
      for (int kk = 0; kk < 2; ++kk) {
        bf16x8 ah = *(const bf16x8*)&Uh[(rt << 4) + lrow][(kk << 5) + lk8];
        bf16x8 al = *(const bf16x8*)&Ul[(rt << 4) + lrow][(kk << 5) + lk8];
#pragma unroll
        for (int ct = 0; ct < 8; ++ct) {
          int col = ((ct0 + ct) << 4) + lrow;
          bf16x8 bh = *(const bf16x8*)&xbh[col][(kk << 5) + lk8];
          bf16x8 bl = *(const bf16x8*)&xbl[col][(kk << 5) + lk8];
          uacc[ct] = __builtin_amdgcn_mfma_f32_16x16x32_bf16(ah, bh, uacc[ct], 0, 0, 0);
          uacc[ct] = __builtin_amdgcn_mfma_f32_16x16x32_bf16(ah, bl, uacc[ct], 0, 0, 0);
          uacc[ct] = __builtin_amdgcn_mfma_f32_16x16x32_bf16(al, bh, uacc[ct], 0, 0, 0);
        }
      }
      int n0 = (rt << 3) + ((lane >> 4) << 1);
#pragma unroll
      for (int ct = 0; ct < 8; ++ct) {
        int colg = (half << 8) + ((ct0 + ct) << 4) + lrow;
        float2* o = sF2 + (size_t)colg * (H_SZ * NH) + h * NH + n0;
        o[0] = make_float2(uacc[ct][0], uacc[ct][1]);
        o[1] = make_float2(uacc[ct][2], uacc[ct][3]);
      }
    }
    // ---- T-GEMM (x still staged) ----
    f32x4 acc[8];
#pragma unroll
    for (int ct = 0; ct < 8; ++ct) acc[ct] = (f32x4){0.f, 0.f, 0.f, 0.f};
#pragma unroll
    for (int kk = 0; kk < 2; ++kk) {
      bf16x8 ah = *(const bf16x8*)&Th[(rt << 4) + lrow][(kk << 5) + lk8];
      bf16x8 al = *(const bf16x8*)&Tl[(rt << 4) + lrow][(kk << 5) + lk8];
#pragma unroll
      for (int ct = 0; ct < 8; ++ct) {
        int col = ((ct0 + ct) << 4) + lrow;
        bf16x8 bh = *(const bf16x8*)&xbh[col][(kk << 5) + lk8];
        bf16x8 bl = *(const bf16x8*)&xbl[col][(kk << 5) + lk8];
        acc[ct] = __builtin_amdgcn_mfma_f32_16x16x32_bf16(ah, bh, acc[ct], 0, 0, 0);
        acc[ct] = __builtin_amdgcn_mfma_f32_16x16x32_bf16(ah, bl, acc[ct], 0, 0, 0);
        acc[ct] = __builtin_amdgcn_mfma_f32_16x16x32_bf16(al, bh, acc[ct], 0, 0, 0);
      }
    }
    __syncthreads();  // finals stores drained; x reads done
    // ---- exclusive prefix over this half's 8 b (in place, f32 exact) ----
    if (tid < 256) {
      int b = (half << 3) + (tid >> 5), n = tid & 31;
      const float* pb = par + (size_t)(h * NH + n) * 8;
      float lTr = pb[4], lTi = pb[5];
      float cr = 0.f, ci = 0.f;
      float2* p0 = sF2 + (size_t)(b << 5) * (H_SZ * NH) + h * NH + n;
      const size_t cstride = H_SZ * NH;
      float2 f = p0[0];
      for (int c = 0; c < NTC; ++c) {
        float2 fn = f;
        if (c + 1 < NTC) fn = p0[(size_t)(c + 1) * cstride];
        p0[(size_t)c * cstride] = make_float2(cr, ci);
        float nr = fmaf(lTr, cr, f.x); nr = fmaf(-lTi, ci, nr);
        float ni = fmaf(lTr, ci, f.y); ni = fmaf(lTi, cr, ni);
        cr = nr; ci = ni;
        f = fn;
      }
    }
    __syncthreads();  // prefix done
    // ---- stage svec (carries) hi/lo into xbh/xbl ----
    {
      int colh = tid >> 1, n0 = (tid & 1) << 4;
      int colg = (half << 8) + colh;
      const float2* cp = sF2 + (size_t)colg * (H_SZ * NH) + h * NH;
#pragma unroll
      for (int n = 0; n < 16; ++n) {
        float2 s = cp[n0 + n];
        int k2 = 2 * (n0 + n);
        unsigned short hr = f2b(s.x);
        xbh[colh][k2] = hr; xbl[colh][k2] = f2b(s.x - b2f(hr));
        unsigned short hm = f2b(s.y);
        xbh[colh][k2 + 1] = hm; xbl[colh][k2 + 1] = f2b(s.y - b2f(hm));
      }
    }
    __syncthreads();
    // ---- W-GEMM (carry contribution), accumulate; write y bf16 ----
#pragma unroll
    for (int kk = 0; kk < 2; ++kk) {
      bf16x8 ah = *(const bf16x8*)&Wh[(rt << 4) + lrow][(kk << 5) + lk8];
      bf16x8 al = *(const bf16x8*)&Wl[(rt << 4) + lrow][(kk << 5) + lk8];
#pragma unroll
      for (int ct = 0; ct < 8; ++ct) {
        int col = ((ct0 + ct) << 4) + lrow;
        bf16x8 bh = *(const bf16x8*)&xbh[col][(kk << 5) + lk8];
        bf16x8 bl = *(const bf16x8*)&xbl[col][(kk << 5) + lk8];
        acc[ct] = __builtin_amdgcn_mfma_f32_16x16x32_bf16(ah, bh, acc[ct], 0, 0, 0);
        acc[ct] = __builtin_amdgcn_mfma_f32_16x16x32_bf16(ah, bl, acc[ct], 0, 0, 0);
        acc[ct] = __builtin_amdgcn_mfma_f32_16x16x32_bf16(al, bh, acc[ct], 0, 0, 0);
      }
    }
#pragma unroll
    for (int ct = 0; ct < 8; ++ct) {
      int colg = (half << 8) + ((ct0 + ct) << 4) + lrow;
      ushort4 o;
      o.x = f2b(acc[ct][0]); o.y = f2b(acc[ct][1]);
      o.z = f2b(acc[ct][2]); o.w = f2b(acc[ct][3]);
      *(ushort4*)(yloc + (size_t)h * (B_SZ * L_SZ) + (size_t)colg * 64 + (rt << 4) + rsub) = o;
    }
  }
}

// ---------------- post: fill(y+Dx)+GELU + GLU + LN ----------------
__launch_bounds__(1024, 4)
__global__ void k_layer2(float* __restrict__ hbuf, const unsigned short* __restrict__ yloc,
                         const float* __restrict__ D_skip,
                         const unsigned short* __restrict__ wbf,
                         const float* __restrict__ b_out,
                         const float* __restrict__ ln_g, const float* __restrict__ ln_b,
                         float* __restrict__ pooledPart, int last) {
  __shared__ __align__(16) unsigned short yt[TC][H_SZ + 8];
  __shared__ float part[TC][16][2];
  __shared__ float stats[TC][2];
  int tid = threadIdx.x;
  int b = blockIdx.x >> 5;
  int c = blockIdx.x & 31;
  int l0 = c << 6;

  {
    int h = tid >> 2, q = tid & 3;
    float Dh = D_skip[h];
    const float* xp = hbuf + ((size_t)(b * H_SZ + h) << 11) + l0 + (q << 4);
    const unsigned short* yp2 = yloc + (size_t)h * (B_SZ * L_SZ) + b * L_SZ + l0 + (q << 4);
#pragma unroll
    for (int jj = 0; jj < 16; jj += 4) {
      float4 xv = *(const float4*)(xp + jj);
      ushort4 yv = *(const ushort4*)(yp2 + jj);
      int jb = (q << 4) + jj;
      yt[jb + 0][h] = f2b(gelu_exact(fmaf(Dh, xv.x, b2f(yv.x))));
      yt[jb + 1][h] = f2b(gelu_exact(fmaf(Dh, xv.y, b2f(yv.y))));
      yt[jb + 2][h] = f2b(gelu_exact(fmaf(Dh, xv.z, b2f(yv.z))));
      yt[jb + 3][h] = f2b(gelu_exact(fmaf(Dh, xv.w, b2f(yv.w))));
    }
  }
  __syncthreads();
  {
    int w = tid >> 6, lane = tid & 63;
    int lrow = lane & 15, lk8 = (lane >> 4) << 3;
    f32x4 accA[4], accG[4];
    f32x4 zed = {0.f, 0.f, 0.f, 0.f};
#pragma unroll
    for (int jt = 0; jt < 4; ++jt) { accA[jt] = zed; accG[jt] = zed; }
    const unsigned short* wA = wbf + ((w << 4) + lrow) * H_SZ;
    const unsigned short* wG = wA + 256 * H_SZ;
#pragma unroll
    for (int k0 = 0; k0 < H_SZ; k0 += 32) {
      bf16x8 a0 = *(const bf16x8*)(wA + k0 + lk8);
      bf16x8 a1 = *(const bf16x8*)(wG + k0 + lk8);
#pragma unroll
      for (int jt = 0; jt < 4; ++jt) {
        bf16x8 bb = *(const bf16x8*)(&yt[(jt << 4) + lrow][k0 + lk8]);
        accA[jt] = __builtin_amdgcn_mfma_f32_16x16x32_bf16(a0, bb, accA[jt], 0, 0, 0);
        accG[jt] = __builtin_amdgcn_mfma_f32_16x16x32_bf16(a1, bb, accG[jt], 0, 0, 0);
      }
    }
    __syncthreads();
    int rbase = (lane >> 4) << 2;
    float bA[4], bG[4];
#pragma unroll
    for (int r = 0; r < 4; ++r) {
      bA[r] = b_out[(w << 4) + rbase + r];
      bG[r] = b_out[256 + (w << 4) + rbase + r];
    }
#pragma unroll
    for (int jt = 0; jt < 4; ++jt) {
#pragma unroll
      for (int r = 0; r < 4; ++r) {
        float a = accA[jt][r] + bA[r];
        float g = accG[jt][r] + bG[r];
        float z = a / (1.f + expf(-g));
        yt[(jt << 4) + lrow][(w << 4) + rbase + r] = f2b(z);
      }
    }
  }
  __syncthreads();
  int j = tid & 63, hg = tid >> 6;
  float vreg[16];
  {
    const float* xc = hbuf + (b * H_SZ + (hg << 4)) * L_SZ + l0 + j;
    float s = 0.f, sq = 0.f;
#pragma unroll
    for (int k = 0; k < 16; ++k) {
      float v = b2f(yt[j][(hg << 4) + k]) + xc[(size_t)k * L_SZ];
      vreg[k] = v;
      s += v; sq = fmaf(v, v, sq);
    }
    part[j][hg][0] = s; part[j][hg][1] = sq;
  }
  __syncthreads();
  if (tid < TC) {
    float s = 0.f, sq = 0.f;
#pragma unroll
    for (int g = 0; g < 16; ++g) { s += part[tid][g][0]; sq += part[tid][g][1]; }
    float mu = s * (1.f / 256.f);
    float var = sq * (1.f / 256.f) - mu * mu;
    stats[tid][0] = mu;
    stats[tid][1] = rsqrtf(var + 1e-5f);
  }
  __syncthreads();
  {
    float mu = stats[j][0], rs = stats[j][1];
    if (!last) {
      float* xo = hbuf + (b * H_SZ + (hg << 4)) * L_SZ + l0 + j;
#pragma unroll
      for (int k = 0; k < 16; ++k) {
        int hh = (hg << 4) + k;
        xo[(size_t)k * L_SZ] = (vreg[k] - mu) * rs * ln_g[hh] + ln_b[hh];
      }
    } else {
#pragma unroll
      for (int k = 0; k < 16; ++k) {
        int hh = (hg << 4) + k;
        yt[j][hh] = f2b((vreg[k] - mu) * rs * ln_g[hh] + ln_b[hh]);
      }
      __syncthreads();
      if (tid < H_SZ) {
        float s = 0.f;
        for (int jj = 0; jj < TC; ++jj) s += b2f(yt[jj][tid]);
        pooledPart[(((b << 5) + c) << 8) + tid] = s;
      }
    }
  }
}

// ---------------- decoder MLP (single block) with pooling preamble ----------------
__global__ void k_decoder(const float* __restrict__ pooledPart,
                          const float* __restrict__ w1, const float* __restrict__ b1,
                          const float* __restrict__ w2, const float* __restrict__ b2,
                          const float* __restrict__ w3, const float* __restrict__ b3,
                          float* __restrict__ out) {
  __shared__ float P[16 * 256];
  __shared__ float O1[16 * 128];
  __shared__ float O2[16 * 64];
  int tid = threadIdx.x;
  for (int id = tid; id < 16 * 256; id += 256) {
    int b = id >> 8, hh = id & 255;
    float s = 0.f;
#pragma unroll
    for (int cpart = 0; cpart < 32; ++cpart)
      s += pooledPart[(((b << 5) + cpart) << 8) + hh];
    P[id] = s * (1.f / 2048.f);
  }
  __syncthreads();
  for (int id = tid; id < 16 * 128; id += 256) {
    int r = id >> 7, cc = id & 127;
    float acc = b1[cc];
    for (int d = 0; d < 256; ++d) acc = fmaf(P[(r << 8) + d], w1[(d << 7) + cc], acc);
    O1[id] = fmaxf(acc, 0.f);
  }
  __syncthreads();
  for (int id = tid; id < 16 * 64; id += 256) {
    int r = id >> 6, cc = id & 63;
    float acc = b2[cc];
    for (int d = 0; d < 128; ++d) acc = fmaf(O1[(r << 7) + d], w2[(d << 6) + cc], acc);
    O2[id] = fmaxf(acc, 0.f);
  }
  __syncthreads();
  for (int id = tid; id < 16 * 32; id += 256) {
    int r = id >> 5, cc = id & 31;
    float acc = b3[cc];
    for (int d = 0; d < 64; ++d) acc = fmaf(O2[(r << 6) + d], w3[(d << 5) + cc], acc);
    out[id] = acc;
  }
}

extern "C" void kernel_launch(void* const* d_in, const int* in_sizes, int n_in,
                              void* d_out, int out_size, void* d_ws, size_t ws_size,
                              hipStream_t stream) {
  const float* x          = (const float*)d_in[0];
  const float* enc_w      = (const float*)d_in[1];
  const float* enc_b      = (const float*)d_in[2];
  const float* log_dt     = (const float*)d_in[3];
  const float* C_re       = (const float*)d_in[4];
  const float* C_im       = (const float*)d_in[5];
  const float* log_A_real = (const float*)d_in[6];
  const float* A_imag     = (const float*)d_in[7];
  const float* D_skip     = (const float*)d_in[8];
  const float* w_out      = (const float*)d_in[9];
  const float* b_out      = (const float*)d_in[10];
  const float* ln_g       = (const float*)d_in[11];
  const float* ln_b       = (const float*)d_in[12];
  const float* dw1        = (const float*)d_in[13];
  const float* db1        = (const float*)d_in[14];
  const float* dw2        = (const float*)d_in[15];
  const float* db2        = (const float*)d_in[16];
  const float* dw3        = (const float*)d_in[17];
  const float* db3        = (const float*)d_in[18];

  char* ws = (char*)d_ws;
  float* hbuf = (float*)ws;                                  // 33,554,432 B
  float2* sF2 = (float2*)(ws + 33554432);                    // 33,554,432 B
  unsigned short* yloc = (unsigned short*)(ws + 67108864);   // 16,777,216 B (bf16)
  unsigned short* wbf = (unsigned short*)(ws + 83886080);    //  1,048,576 B
  float* par = (float*)(ws + 84934656);                      //  1,048,576 B
  float* pooledPart = (float*)(ws + 85983232);               //    524,288 B

  k_encoder<<<512, 512, 0, stream>>>(x, enc_w, enc_b, hbuf);
  k_cvtw<<<2048, 256, 0, stream>>>(w_out, wbf, NL * 512 * H_SZ);
  k_params<<<128, 256, 0, stream>>>(log_dt, log_A_real, A_imag, C_re, C_im, par);
  const size_t PAR_STRIDE = (size_t)H_SZ * NH * 8;
  for (int i = 0; i < NL; ++i) {
    const float* pari = par + i * PAR_STRIDE;
    k_ssm<<<256, 512, 0, stream>>>(hbuf, sF2, pari, yloc);
    k_layer2<<<512, 1024, 0, stream>>>(hbuf, yloc,
                                       D_skip + i * H_SZ, wbf + i * 512 * H_SZ,
                                       b_out + i * 512, ln_g + i * H_SZ, ln_b + i * H_SZ,
                                       pooledPart, (i == NL - 1) ? 1 : 0);
  }
  k_decoder<<<1, 256, 0, stream>>>(pooledPart, dw1, db1, dw2, db2, dw3, db3, (float*)d_out);
}

// Round 13
// 374.525 us; speedup vs baseline: 2.7950x; 1.0849x over previous
//
#include <hip/hip_runtime.h>

#define B_SZ 16
#define L_SZ 2048
#define DIN 64
#define H_SZ 256
#define NH 32
#define NL 4
#define TC 64
#define NTC 32
#define YROW (H_SZ + 8)

typedef __attribute__((ext_vector_type(8))) __bf16 bf16x8;
typedef __attribute__((ext_vector_type(4))) float f32x4;

__device__ __forceinline__ unsigned short f2b(float f) {
  unsigned int u = __builtin_bit_cast(unsigned int, f);
  unsigned int r = u + 0x7fffu + ((u >> 16) & 1u);  // RNE (no NaN inputs here)
  return (unsigned short)(r >> 16);
}
__device__ __forceinline__ float b2f(unsigned short u) {
  unsigned int v = ((unsigned int)u) << 16;
  return __builtin_bit_cast(float, v);
}
__device__ __forceinline__ float gelu_exact(float v) {
  return 0.5f * v * (1.f + erff(v * 0.70710678118654752f));
}
// 16B-granule XOR swizzle for yt: spreads column-wise (cross-row) access
// across banks while keeping every 16B chunk intact (MFMA b128 reads stay free).
__device__ __forceinline__ int yswz(int row, int col) {
  return (row * YROW + col) ^ (((row >> 3) & 7) << 3);
}

// ---------------- encoder as compensated MFMA GEMM ----------------
__launch_bounds__(512, 4)
__global__ void k_encoder(const float* __restrict__ x, const float* __restrict__ w,
                          const float* __restrict__ bias, float* __restrict__ hbuf) {
  __shared__ __align__(16) unsigned short Wh[128][72];
  __shared__ __align__(16) unsigned short Wl[128][72];
  __shared__ __align__(16) unsigned short xh[128][72];
  __shared__ __align__(16) unsigned short xl[128][72];
  int tid = threadIdx.x;
  int blk = blockIdx.x;           // b(4b) lt(4b) hh(1b)
  int b = blk >> 5;
  int lt = (blk >> 1) & 15;
  int hh = blk & 1;

#pragma unroll
  for (int i = 0; i < 16; ++i) {
    int flat = i * 512 + tid;
    int d = flat >> 7, hl = flat & 127;
    float v = w[d * H_SZ + (hh << 7) + hl];
    unsigned short hv = f2b(v);
    Wh[hl][d] = hv; Wl[hl][d] = f2b(v - b2f(hv));
  }
  {
    int l = tid >> 2, d0 = (tid & 3) << 4;
    const float* src = x + ((size_t)(b * L_SZ + (lt << 7) + l) << 6) + d0;
    unsigned short* dh = &xh[l][d0];
    unsigned short* dl = &xl[l][d0];
#pragma unroll
    for (int jj = 0; jj < 4; ++jj) {
      float4 v = *(const float4*)(src + jj * 4);
      unsigned short h0 = f2b(v.x); dh[jj * 4 + 0] = h0; dl[jj * 4 + 0] = f2b(v.x - b2f(h0));
      unsigned short h1 = f2b(v.y); dh[jj * 4 + 1] = h1; dl[jj * 4 + 1] = f2b(v.y - b2f(h1));
      unsigned short h2 = f2b(v.z); dh[jj * 4 + 2] = h2; dl[jj * 4 + 2] = f2b(v.z - b2f(h2));
      unsigned short h3 = f2b(v.w); dh[jj * 4 + 3] = h3; dl[jj * 4 + 3] = f2b(v.w - b2f(h3));
    }
  }
  __syncthreads();

  int wv = tid >> 6, lane = tid & 63;
  int lrow = lane & 15, lk8 = (lane >> 4) << 3;
  int rsub = (lane >> 4) << 2;
  f32x4 acc[8];
#pragma unroll
  for (int ct = 0; ct < 8; ++ct) acc[ct] = (f32x4){0.f, 0.f, 0.f, 0.f};
#pragma unroll
  for (int kk = 0; kk < 2; ++kk) {
    bf16x8 ah = *(const bf16x8*)&Wh[(wv << 4) + lrow][(kk << 5) + lk8];
    bf16x8 al = *(const bf16x8*)&Wl[(wv << 4) + lrow][(kk << 5) + lk8];
#pragma unroll
    for (int ct = 0; ct < 8; ++ct) {
      bf16x8 bh = *(const bf16x8*)&xh[(ct << 4) + lrow][(kk << 5) + lk8];
      bf16x8 bl = *(const bf16x8*)&xl[(ct << 4) + lrow][(kk << 5) + lk8];
      acc[ct] = __builtin_amdgcn_mfma_f32_16x16x32_bf16(ah, bh, acc[ct], 0, 0, 0);
      acc[ct] = __builtin_amdgcn_mfma_f32_16x16x32_bf16(ah, bl, acc[ct], 0, 0, 0);
      acc[ct] = __builtin_amdgcn_mfma_f32_16x16x32_bf16(al, bh, acc[ct], 0, 0, 0);
    }
  }
  float bi[4];
#pragma unroll
  for (int r = 0; r < 4; ++r) bi[r] = bias[(hh << 7) + (wv << 4) + rsub + r];
#pragma unroll
  for (int ct = 0; ct < 8; ++ct) {
    int lglob = (lt << 7) + (ct << 4) + lrow;
#pragma unroll
    for (int r = 0; r < 4; ++r) {
      int hglob = (hh << 7) + (wv << 4) + rsub + r;
      hbuf[((size_t)(b * H_SZ + hglob) << 11) + lglob] = acc[ct][r] + bi[r];
    }
  }
}

// ---------------- convert w_out to bf16 ----------------
__global__ void k_cvtw(const float* __restrict__ w, unsigned short* __restrict__ wbf, int n) {
  int i = blockIdx.x * 256 + threadIdx.x;
  if (i < n) wbf[i] = f2b(w[i]);
}

// ---------------- precompute per-state params: lr, li, c2r, c2i, lTr, lTi ----------------
__global__ void k_params(const float* __restrict__ log_dt, const float* __restrict__ log_A_real,
                         const float* __restrict__ A_imag, const float* __restrict__ C_re,
                         const float* __restrict__ C_im, float* __restrict__ par) {
  int id = blockIdx.x * 256 + threadIdx.x;  // i*8192 + h*32 + n
  if (id >= NL * H_SZ * NH) return;
  int i = id >> 13;
  int hn = id & 8191;
  int h = hn >> 5;
  float dt = expf(log_dt[i * H_SZ + h]);
  float Ar = -expf(log_A_real[(size_t)i * H_SZ * NH + hn]);
  float Ai = A_imag[(size_t)i * H_SZ * NH + hn];
  float dr = dt * Ar, di = dt * Ai;
  float e = expf(dr), sn, cs;
  sincosf(di, &sn, &cs);
  float lr = e * cs, li = e * sn;
  float eT = expf((float)TC * dr), snT, csT;
  sincosf((float)TC * di, &snT, &csT);
  float Cr = C_re[(size_t)i * H_SZ * NH + hn], Ci = C_im[(size_t)i * H_SZ * NH + hn];
  float wr = lr - 1.f, wi = li;
  float pr = Cr * wr - Ci * wi;
  float pi = Cr * wi + Ci * wr;
  float inv = 2.f / fmaf(Ar, Ar, Ai * Ai);
  float4* p = (float4*)(par + (size_t)id * 8);
  p[0] = make_float4(lr, li, (pr * Ar + pi * Ai) * inv, (pi * Ar - pr * Ai) * inv);
  p[1] = make_float4(eT * csT, eT * snT, 0.f, 0.f);
}

// ---------------- merged SSM kernel: finals + prefix + conv, one x staging ----------------
__launch_bounds__(512, 1)
__global__ void k_ssm(const float* __restrict__ hbuf, float2* __restrict__ sF2,
                      const float* __restrict__ par, unsigned short* __restrict__ yloc) {
  __shared__ __align__(16) unsigned short xbh[256][72];
  __shared__ __align__(16) unsigned short xbl[256][72];
  __shared__ __align__(16) unsigned short Uh[64][72];
  __shared__ __align__(16) unsigned short Ul[64][72];
  __shared__ __align__(16) unsigned short Th[64][72];
  __shared__ __align__(16) unsigned short Tl[64][72];
  __shared__ __align__(16) unsigned short Wh[64][72];
  __shared__ __align__(16) unsigned short Wl[64][72];
  __shared__ float Kc[64];
  int tid = threadIdx.x;
  int h = blockIdx.x;
  float* Wm = (float*)&xbh[0][0];  // [64][66] f32 scratch, dead before x staging

  if (tid < 64) {
    int n = tid >> 1, q = tid & 1;
    const float* pb = par + (size_t)(h * NH + n) * 8;
    float lr = pb[0], li = pb[1], c2r = pb[2], c2i = pb[3];
    float pr = lr, pi = li;  // lam^1
    if (q) {                 // lam^33
      float sr = lr, si = li;
#pragma unroll
      for (int t = 0; t < 5; ++t) { float nr2 = sr * sr - si * si; si = 2.f * sr * si; sr = nr2; }
      pr = sr * lr - si * li; pi = sr * li + si * lr;
    }
    int p = q << 5;
    for (int s = 0; s < 32; ++s, ++p) {
      Wm[p * 66 + 2 * n] = c2r * pr - c2i * pi;
      Wm[p * 66 + 2 * n + 1] = -(c2r * pi + c2i * pr);
      float nr2 = pr * lr - pi * li;
      pi = pr * li + pi * lr;
      pr = nr2;
    }
  }
  __syncthreads();
  if (tid < 64) {
    float kv = 0.f;
    if (tid == 0) {
      for (int n = 0; n < 32; ++n) kv += par[(size_t)(h * NH + n) * 8 + 2];
    } else {
      for (int n = 0; n < 32; ++n) kv += Wm[(tid - 1) * 66 + 2 * n];
    }
    Kc[tid] = kv;
  }
  {
    int base = tid * 8;
    int row = base >> 6, col0 = base & 63;
#pragma unroll
    for (int e = 0; e < 8; ++e) {
      float v = Wm[row * 66 + col0 + e];
      unsigned short hv = f2b(v);
      Wh[row][col0 + e] = hv; Wl[row][col0 + e] = f2b(v - b2f(hv));
    }
  }
  __syncthreads();
  {
    int base = tid * 8;
    int row = base >> 6, col0 = base & 63;
#pragma unroll
    for (int e = 0; e < 8; ++e) {
      int col = col0 + e;
      float v = (col <= row) ? Kc[row - col] : 0.f;
      unsigned short hv = f2b(v);
      Th[row][col] = hv; Tl[row][col] = f2b(v - b2f(hv));
    }
  }
  if (tid < 64) {
    int n = tid >> 1, q = tid & 1;
    const float* pb = par + (size_t)(h * NH + n) * 8;
    float lr = pb[0], li = pb[1];
    float pr = 1.f, pi = 0.f;
    if (q) {
      float sr = lr, si = li;
#pragma unroll
      for (int t = 0; t < 5; ++t) { float nr2 = sr * sr - si * si; si = 2.f * sr * si; sr = nr2; }
      pr = sr; pi = si;
    }
    int p = q << 5;
    for (int s = 0; s < 32; ++s, ++p) {
      int col = 63 - p;
      unsigned short hr = f2b(pr);
      Uh[2 * n][col] = hr; Ul[2 * n][col] = f2b(pr - b2f(hr));
      unsigned short hm = f2b(pi);
      Uh[2 * n + 1][col] = hm; Ul[2 * n + 1][col] = f2b(pi - b2f(hm));
      float nr2 = pr * lr - pi * li;
      pi = pr * li + pi * lr;
      pr = nr2;
    }
  }

  int wv = tid >> 6, lane = tid & 63;
  int lrow = lane & 15, lk8 = (lane >> 4) << 3;
  int rt = wv >> 1;
  int ct0 = (wv & 1) << 3;
  int rsub = (lane >> 4) << 2;

  for (int half = 0; half < 2; ++half) {
    __syncthreads();
    {
      int colh = tid >> 1, j0 = (tid & 1) << 5;
      int b = (half << 3) + (colh >> 5), c = colh & 31;
      const float* src = hbuf + ((size_t)(b * H_SZ + h) << 11) + (c << 6) + j0;
      unsigned short* dh = &xbh[colh][j0];
      unsigned short* dl = &xbl[colh][j0];
#pragma unroll
      for (int jj = 0; jj < 8; ++jj) {
        float4 v = *(const float4*)(src + jj * 4);
        unsigned short h0 = f2b(v.x); dh[jj * 4 + 0] = h0; dl[jj * 4 + 0] = f2b(v.x - b2f(h0));
        unsigned short h1 = f2b(v.y); dh[jj * 4 + 1] = h1; dl[jj * 4 + 1] = f2b(v.y - b2f(h1));
        unsigned short h2 = f2b(v.z); dh[jj * 4 + 2] = h2; dl[jj * 4 + 2] = f2b(v.z - b2f(h2));
        unsigned short h3 = f2b(v.w); dh[jj * 4 + 3] = h3; dl[jj * 4 + 3] = f2b(v.w - b2f(h3));
      }
    }
    __syncthreads();
    {
      f32x4 uacc[8];
#pragma unroll
      for (int ct = 0; ct < 8; ++ct) uacc[ct] = (f32x4){0.f, 0.f, 0.f, 0.f};
#pragma unroll
      for (int kk = 0; kk < 2; ++kk) {
        bf16x8 ah = *(const bf16x8*)&Uh[(rt << 4) + lrow][(kk << 5) + lk8];
        bf16x8 al = *(const bf16x8*)&Ul[(rt << 4) + lrow][(kk << 5) + lk8];
#pragma unroll
        for (int ct = 0; ct < 8; ++ct) {
          int col = ((ct0 + ct) << 4) + lrow;
          bf16x8 bh = *(const bf16x8*)&xbh[col][(kk << 5) + lk8];
          bf16x8 bl = *(const bf16x8*)&xbl[col][(kk << 5) + lk8];
          uacc[ct] = __builtin_amdgcn_mfma_f32_16x16x32_bf16(ah, bh, uacc[ct], 0, 0, 0);
          uacc[ct] = __builtin_amdgcn_mfma_f32_16x16x32_bf16(ah, bl, uacc[ct], 0, 0, 0);
          uacc[ct] = __builtin_amdgcn_mfma_f32_16x16x32_bf16(al, bh, uacc[ct], 0, 0, 0);
        }
      }
      int n0 = (rt << 3) + ((lane >> 4) << 1);
#pragma unroll
      for (int ct = 0; ct < 8; ++ct) {
        int colg = (half << 8) + ((ct0 + ct) << 4) + lrow;
        float2* o = sF2 + (size_t)colg * (H_SZ * NH) + h * NH + n0;
        o[0] = make_float2(uacc[ct][0], uacc[ct][1]);
        o[1] = make_float2(uacc[ct][2], uacc[ct][3]);
      }
    }
    f32x4 acc[8];
#pragma unroll
    for (int ct = 0; ct < 8; ++ct) acc[ct] = (f32x4){0.f, 0.f, 0.f, 0.f};
#pragma unroll
    for (int kk = 0; kk < 2; ++kk) {
      bf16x8 ah = *(const bf16x8*)&Th[(rt << 4) + lrow][(kk << 5) + lk8];
      bf16x8 al = *(const bf16x8*)&Tl[(rt << 4) + lrow][(kk << 5) + lk8];
#pragma unroll
      for (int ct = 0; ct < 8; ++ct) {
        int col = ((ct0 + ct) << 4) + lrow;
        bf16x8 bh = *(const bf16x8*)&xbh[col][(kk << 5) + lk8];
        bf16x8 bl = *(const bf16x8*)&xbl[col][(kk << 5) + lk8];
        acc[ct] = __builtin_amdgcn_mfma_f32_16x16x32_bf16(ah, bh, acc[ct], 0, 0, 0);
        acc[ct] = __builtin_amdgcn_mfma_f32_16x16x32_bf16(ah, bl, acc[ct], 0, 0, 0);
        acc[ct] = __builtin_amdgcn_mfma_f32_16x16x32_bf16(al, bh, acc[ct], 0, 0, 0);
      }
    }
    __syncthreads();
    if (tid < 256) {
      int b = (half << 3) + (tid >> 5), n = tid & 31;
      const float* pb = par + (size_t)(h * NH + n) * 8;
      float lTr = pb[4], lTi = pb[5];
      float cr = 0.f, ci = 0.f;
      float2* p0 = sF2 + (size_t)(b << 5) * (H_SZ * NH) + h * NH + n;
      const size_t cstride = H_SZ * NH;
      float2 f = p0[0];
      for (int c = 0; c < NTC; ++c) {
        float2 fn = f;
        if (c + 1 < NTC) fn = p0[(size_t)(c + 1) * cstride];
        p0[(size_t)c * cstride] = make_float2(cr, ci);
        float nr = fmaf(lTr, cr, f.x); nr = fmaf(-lTi, ci, nr);
        float ni = fmaf(lTr, ci, f.y); ni = fmaf(lTi, cr, ni);
        cr = nr; ci = ni;
        f = fn;
      }
    }
    __syncthreads();
    {
      int colh = tid >> 1, n0 = (tid & 1) << 4;
      int colg = (half << 8) + colh;
      const float2* cp = sF2 + (size_t)colg * (H_SZ * NH) + h * NH;
#pragma unroll
      for (int n = 0; n < 16; ++n) {
        float2 s = cp[n0 + n];
        int k2 = 2 * (n0 + n);
        unsigned short hr = f2b(s.x);
        xbh[colh][k2] = hr; xbl[colh][k2] = f2b(s.x - b2f(hr));
        unsigned short hm = f2b(s.y);
        xbh[colh][k2 + 1] = hm; xbl[colh][k2 + 1] = f2b(s.y - b2f(hm));
      }
    }
    __syncthreads();
#pragma unroll
    for (int kk = 0; kk < 2; ++kk) {
      bf16x8 ah = *(const bf16x8*)&Wh[(rt << 4) + lrow][(kk << 5) + lk8];
      bf16x8 al = *(const bf16x8*)&Wl[(rt << 4) + lrow][(kk << 5) + lk8];
#pragma unroll
      for (int ct = 0; ct < 8; ++ct) {
        int col = ((ct0 + ct) << 4) + lrow;
        bf16x8 bh = *(const bf16x8*)&xbh[col][(kk << 5) + lk8];
        bf16x8 bl = *(const bf16x8*)&xbl[col][(kk << 5) + lk8];
        acc[ct] = __builtin_amdgcn_mfma_f32_16x16x32_bf16(ah, bh, acc[ct], 0, 0, 0);
        acc[ct] = __builtin_amdgcn_mfma_f32_16x16x32_bf16(ah, bl, acc[ct], 0, 0, 0);
        acc[ct] = __builtin_amdgcn_mfma_f32_16x16x32_bf16(al, bh, acc[ct], 0, 0, 0);
      }
    }
#pragma unroll
    for (int ct = 0; ct < 8; ++ct) {
      int colg = (half << 8) + ((ct0 + ct) << 4) + lrow;
      ushort4 o;
      o.x = f2b(acc[ct][0]); o.y = f2b(acc[ct][1]);
      o.z = f2b(acc[ct][2]); o.w = f2b(acc[ct][3]);
      *(ushort4*)(yloc + (size_t)h * (B_SZ * L_SZ) + (size_t)colg * 64 + (rt << 4) + rsub) = o;
    }
  }
}

// ---------------- post: fill(y+Dx)+GELU + GLU + LN (yt XOR-swizzled) ----------------
__launch_bounds__(1024, 4)
__global__ void k_layer2(float* __restrict__ hbuf, const unsigned short* __restrict__ yloc,
                         const float* __restrict__ D_skip,
                         const unsigned short* __restrict__ wbf,
                         const float* __restrict__ b_out,
                         const float* __restrict__ ln_g, const float* __restrict__ ln_b,
                         float* __restrict__ pooledPart, int last) {
  __shared__ __align__(16) unsigned short yt[TC * YROW];
  __shared__ float part[TC][16][2];
  __shared__ float stats[TC][2];
  int tid = threadIdx.x;
  int b = blockIdx.x >> 5;
  int c = blockIdx.x & 31;
  int l0 = c << 6;

  // ---- fill + gelu (scalar stores, swizzled: ~2-way) ----
  {
    int h = tid >> 2, q = tid & 3;
    float Dh = D_skip[h];
    const float* xp = hbuf + ((size_t)(b * H_SZ + h) << 11) + l0 + (q << 4);
    const unsigned short* yp2 = yloc + (size_t)h * (B_SZ * L_SZ) + b * L_SZ + l0 + (q << 4);
#pragma unroll
    for (int jj = 0; jj < 16; jj += 4) {
      float4 xv = *(const float4*)(xp + jj);
      ushort4 yv = *(const ushort4*)(yp2 + jj);
      int jb = (q << 4) + jj;
      yt[yswz(jb + 0, h)] = f2b(gelu_exact(fmaf(Dh, xv.x, b2f(yv.x))));
      yt[yswz(jb + 1, h)] = f2b(gelu_exact(fmaf(Dh, xv.y, b2f(yv.y))));
      yt[yswz(jb + 2, h)] = f2b(gelu_exact(fmaf(Dh, xv.z, b2f(yv.z))));
      yt[yswz(jb + 3, h)] = f2b(gelu_exact(fmaf(Dh, xv.w, b2f(yv.w))));
    }
  }
  __syncthreads();
  // ---- GLU: 1x1 conv via MFMA; z -> yt ----
  {
    int w = tid >> 6, lane = tid & 63;
    int lrow = lane & 15, lk8 = (lane >> 4) << 3;
    f32x4 accA[4], accG[4];
    f32x4 zed = {0.f, 0.f, 0.f, 0.f};
#pragma unroll
    for (int jt = 0; jt < 4; ++jt) { accA[jt] = zed; accG[jt] = zed; }
    const unsigned short* wA = wbf + ((w << 4) + lrow) * H_SZ;
    const unsigned short* wG = wA + 256 * H_SZ;
#pragma unroll
    for (int k0 = 0; k0 < H_SZ; k0 += 32) {
      bf16x8 a0 = *(const bf16x8*)(wA + k0 + lk8);
      bf16x8 a1 = *(const bf16x8*)(wG + k0 + lk8);
#pragma unroll
      for (int jt = 0; jt < 4; ++jt) {
        bf16x8 bb = *(const bf16x8*)&yt[yswz((jt << 4) + lrow, k0 + lk8)];
        accA[jt] = __builtin_amdgcn_mfma_f32_16x16x32_bf16(a0, bb, accA[jt], 0, 0, 0);
        accG[jt] = __builtin_amdgcn_mfma_f32_16x16x32_bf16(a1, bb, accG[jt], 0, 0, 0);
      }
    }
    __syncthreads();  // all y reads done before overwrite with z
    int rbase = (lane >> 4) << 2;
    float bA[4], bG[4];
#pragma unroll
    for (int r = 0; r < 4; ++r) {
      bA[r] = b_out[(w << 4) + rbase + r];
      bG[r] = b_out[256 + (w << 4) + rbase + r];
    }
#pragma unroll
    for (int jt = 0; jt < 4; ++jt) {
      ushort4 o;
      float a0 = accA[jt][0] + bA[0], g0 = accG[jt][0] + bG[0];
      float a1 = accA[jt][1] + bA[1], g1 = accG[jt][1] + bG[1];
      float a2 = accA[jt][2] + bA[2], g2 = accG[jt][2] + bG[2];
      float a3 = accA[jt][3] + bA[3], g3 = accG[jt][3] + bG[3];
      o.x = f2b(a0 / (1.f + expf(-g0)));
      o.y = f2b(a1 / (1.f + expf(-g1)));
      o.z = f2b(a2 / (1.f + expf(-g2)));
      o.w = f2b(a3 / (1.f + expf(-g3)));
      *(ushort4*)&yt[yswz((jt << 4) + lrow, (w << 4) + rbase)] = o;
    }
  }
  __syncthreads();
  // ---- LN stats; v = z + residual (vectorized yt reads: bank-uniform) ----
  int j = tid & 63, hg = tid >> 6;
  float vreg[16];
  {
    const float* xc = hbuf + (b * H_SZ + (hg << 4)) * L_SZ + l0 + j;
    float s = 0.f, sq = 0.f;
    ushort4 za = *(const ushort4*)&yt[yswz(j, (hg << 4) + 0)];
    ushort4 zb = *(const ushort4*)&yt[yswz(j, (hg << 4) + 4)];
    ushort4 zc = *(const ushort4*)&yt[yswz(j, (hg << 4) + 8)];
    ushort4 zd = *(const ushort4*)&yt[yswz(j, (hg << 4) + 12)];
    unsigned short zz[16] = {za.x, za.y, za.z, za.w, zb.x, zb.y, zb.z, zb.w,
                             zc.x, zc.y, zc.z, zc.w, zd.x, zd.y, zd.z, zd.w};
#pragma unroll
    for (int k = 0; k < 16; ++k) {
      float v = b2f(zz[k]) + xc[(size_t)k * L_SZ];
      vreg[k] = v;
      s += v; sq = fmaf(v, v, sq);
    }
    part[j][hg][0] = s; part[j][hg][1] = sq;
  }
  __syncthreads();
  if (tid < TC) {
    float s = 0.f, sq = 0.f;
#pragma unroll
    for (int g = 0; g < 16; ++g) { s += part[tid][g][0]; sq += part[tid][g][1]; }
    float mu = s * (1.f / 256.f);
    float var = sq * (1.f / 256.f) - mu * mu;
    stats[tid][0] = mu;
    stats[tid][1] = rsqrtf(var + 1e-5f);
  }
  __syncthreads();
  {
    float mu = stats[j][0], rs = stats[j][1];
    if (!last) {
      float* xo = hbuf + (b * H_SZ + (hg << 4)) * L_SZ + l0 + j;
#pragma unroll
      for (int k = 0; k < 16; ++k) {
        int hh = (hg << 4) + k;
        xo[(size_t)k * L_SZ] = (vreg[k] - mu) * rs * ln_g[hh] + ln_b[hh];
      }
    } else {
#pragma unroll
      for (int k = 0; k < 16; ++k) {
        int hh = (hg << 4) + k;
        yt[yswz(j, hh)] = f2b((vreg[k] - mu) * rs * ln_g[hh] + ln_b[hh]);
      }
      __syncthreads();
      if (tid < H_SZ) {
        float s = 0.f;
        for (int jj = 0; jj < TC; ++jj) s += b2f(yt[yswz(jj, tid)]);
        pooledPart[(((b << 5) + c) << 8) + tid] = s;
      }
    }
  }
}

// ---------------- pool: reduce 32 chunk-partials per (b,h) ----------------
__global__ void k_pool(const float* __restrict__ pooledPart, float* __restrict__ P) {
  int b = blockIdx.x, hh = threadIdx.x;
  float s = 0.f;
#pragma unroll
  for (int cpart = 0; cpart < 32; ++cpart)
    s += pooledPart[(((b << 5) + cpart) << 8) + hh];
  P[(b << 8) + hh] = s * (1.f / 2048.f);
}

// ---------------- decoder MLP: one block per batch row ----------------
__global__ void k_dec(const float* __restrict__ P,
                      const float* __restrict__ w1, const float* __restrict__ b1,
                      const float* __restrict__ w2, const float* __restrict__ b2,
                      const float* __restrict__ w3, const float* __restrict__ b3,
                      float* __restrict__ out) {
  __shared__ float Pr[256];
  __shared__ float O1[128];
  __shared__ float O2[64];
  int b = blockIdx.x, tid = threadIdx.x;
  Pr[tid] = P[(b << 8) + tid];
  __syncthreads();
  if (tid < 128) {
    float acc = b1[tid];
    for (int d = 0; d < 256; ++d) acc = fmaf(Pr[d], w1[(d << 7) + tid], acc);
    O1[tid] = fmaxf(acc, 0.f);
  }
  __syncthreads();
  if (tid < 64) {
    float acc = b2[tid];
    for (int d = 0; d < 128; ++d) acc = fmaf(O1[d], w2[(d << 6) + tid], acc);
    O2[tid] = fmaxf(acc, 0.f);
  }
  __syncthreads();
  if (tid < 32) {
    float acc = b3[tid];
    for (int d = 0; d < 64; ++d) acc = fmaf(O2[d], w3[(d << 5) + tid], acc);
    out[(b << 5) + tid] = acc;
  }
}

extern "C" void kernel_launch(void* const* d_in, const int* in_sizes, int n_in,
                              void* d_out, int out_size, void* d_ws, size_t ws_size,
                              hipStream_t stream) {
  const float* x          = (const float*)d_in[0];
  const float* enc_w      = (const float*)d_in[1];
  const float* enc_b      = (const float*)d_in[2];
  const float* log_dt     = (const float*)d_in[3];
  const float* C_re       = (const float*)d_in[4];
  const float* C_im       = (const float*)d_in[5];
  const float* log_A_real = (const float*)d_in[6];
  const float* A_imag     = (const float*)d_in[7];
  const float* D_skip     = (const float*)d_in[8];
  const float* w_out      = (const float*)d_in[9];
  const float* b_out      = (const float*)d_in[10];
  const float* ln_g       = (const float*)d_in[11];
  const float* ln_b       = (const float*)d_in[12];
  const float* dw1        = (const float*)d_in[13];
  const float* db1        = (const float*)d_in[14];
  const float* dw2        = (const float*)d_in[15];
  const float* db2        = (const float*)d_in[16];
  const float* dw3        = (const float*)d_in[17];
  const float* db3        = (const float*)d_in[18];

  char* ws = (char*)d_ws;
  float* hbuf = (float*)ws;                                  // 33,554,432 B
  float2* sF2 = (float2*)(ws + 33554432);                    // 33,554,432 B
  unsigned short* yloc = (unsigned short*)(ws + 67108864);   // 16,777,216 B (bf16)
  unsigned short* wbf = (unsigned short*)(ws + 83886080);    //  1,048,576 B
  float* par = (float*)(ws + 84934656);                      //  1,048,576 B
  float* pooledPart = (float*)(ws + 85983232);               //    524,288 B
  float* P = (float*)(ws + 86507520);                        //     16,384 B

  k_encoder<<<512, 512, 0, stream>>>(x, enc_w, enc_b, hbuf);
  k_cvtw<<<2048, 256, 0, stream>>>(w_out, wbf, NL * 512 * H_SZ);
  k_params<<<128, 256, 0, stream>>>(log_dt, log_A_real, A_imag, C_re, C_im, par);
  const size_t PAR_STRIDE = (size_t)H_SZ * NH * 8;
  for (int i = 0; i < NL; ++i) {
    const float* pari = par + i * PAR_STRIDE;
    k_ssm<<<256, 512, 0, stream>>>(hbuf, sF2, pari, yloc);
    k_layer2<<<512, 1024, 0, stream>>>(hbuf, yloc,
                                       D_skip + i * H_SZ, wbf + i * 512 * H_SZ,
                                       b_out + i * 512, ln_g + i * H_SZ, ln_b + i * H_SZ,
                                       pooledPart, (i == NL - 1) ? 1 : 0);
  }
  k_pool<<<16, 256, 0, stream>>>(pooledPart, P);
  k_dec<<<16, 256, 0, stream>>>(P, dw1, db1, dw2, db2, dw3, db3, (float*)d_out);
}

// Round 14
// 371.811 us; speedup vs baseline: 2.8154x; 1.0073x over previous
//
#include <hip/hip_runtime.h>

#define B_SZ 16
#define L_SZ 2048
#define DIN 64
#define H_SZ 256
#define NH 32
#define NL 4
#define TC 64
#define NTC 32
#define YROW (H_SZ + 8)

typedef __attribute__((ext_vector_type(8))) __bf16 bf16x8;
typedef __attribute__((ext_vector_type(4))) float f32x4;

__device__ __forceinline__ unsigned short f2b(float f) {
  unsigned int u = __builtin_bit_cast(unsigned int, f);
  unsigned int r = u + 0x7fffu + ((u >> 16) & 1u);  // RNE (no NaN inputs here)
  return (unsigned short)(r >> 16);
}
__device__ __forceinline__ float b2f(unsigned short u) {
  unsigned int v = ((unsigned int)u) << 16;
  return __builtin_bit_cast(float, v);
}
__device__ __forceinline__ float gelu_exact(float v) {
  return 0.5f * v * (1.f + erff(v * 0.70710678118654752f));
}
// 16B-granule XOR swizzle for yt
__device__ __forceinline__ int yswz(int row, int col) {
  return (row * YROW + col) ^ (((row >> 3) & 7) << 3);
}

// ---------------- encoder as compensated MFMA GEMM ----------------
__launch_bounds__(512, 4)
__global__ void k_encoder(const float* __restrict__ x, const float* __restrict__ w,
                          const float* __restrict__ bias, float* __restrict__ hbuf) {
  __shared__ __align__(16) unsigned short Wh[128][72];
  __shared__ __align__(16) unsigned short Wl[128][72];
  __shared__ __align__(16) unsigned short xh[128][72];
  __shared__ __align__(16) unsigned short xl[128][72];
  int tid = threadIdx.x;
  int blk = blockIdx.x;           // b(4b) lt(4b) hh(1b)
  int b = blk >> 5;
  int lt = (blk >> 1) & 15;
  int hh = blk & 1;

#pragma unroll
  for (int i = 0; i < 16; ++i) {
    int flat = i * 512 + tid;
    int d = flat >> 7, hl = flat & 127;
    float v = w[d * H_SZ + (hh << 7) + hl];
    unsigned short hv = f2b(v);
    Wh[hl][d] = hv; Wl[hl][d] = f2b(v - b2f(hv));
  }
  {
    int l = tid >> 2, d0 = (tid & 3) << 4;
    const float* src = x + ((size_t)(b * L_SZ + (lt << 7) + l) << 6) + d0;
    unsigned short* dh = &xh[l][d0];
    unsigned short* dl = &xl[l][d0];
#pragma unroll
    for (int jj = 0; jj < 4; ++jj) {
      float4 v = *(const float4*)(src + jj * 4);
      unsigned short h0 = f2b(v.x); dh[jj * 4 + 0] = h0; dl[jj * 4 + 0] = f2b(v.x - b2f(h0));
      unsigned short h1 = f2b(v.y); dh[jj * 4 + 1] = h1; dl[jj * 4 + 1] = f2b(v.y - b2f(h1));
      unsigned short h2 = f2b(v.z); dh[jj * 4 + 2] = h2; dl[jj * 4 + 2] = f2b(v.z - b2f(h2));
      unsigned short h3 = f2b(v.w); dh[jj * 4 + 3] = h3; dl[jj * 4 + 3] = f2b(v.w - b2f(h3));
    }
  }
  __syncthreads();

  int wv = tid >> 6, lane = tid & 63;
  int lrow = lane & 15, lk8 = (lane >> 4) << 3;
  int rsub = (lane >> 4) << 2;
  f32x4 acc[8];
#pragma unroll
  for (int ct = 0; ct < 8; ++ct) acc[ct] = (f32x4){0.f, 0.f, 0.f, 0.f};
#pragma unroll
  for (int kk = 0; kk < 2; ++kk) {
    bf16x8 ah = *(const bf16x8*)&Wh[(wv << 4) + lrow][(kk << 5) + lk8];
    bf16x8 al = *(const bf16x8*)&Wl[(wv << 4) + lrow][(kk << 5) + lk8];
#pragma unroll
    for (int ct = 0; ct < 8; ++ct) {
      bf16x8 bh = *(const bf16x8*)&xh[(ct << 4) + lrow][(kk << 5) + lk8];
      bf16x8 bl = *(const bf16x8*)&xl[(ct << 4) + lrow][(kk << 5) + lk8];
      acc[ct] = __builtin_amdgcn_mfma_f32_16x16x32_bf16(ah, bh, acc[ct], 0, 0, 0);
      acc[ct] = __builtin_amdgcn_mfma_f32_16x16x32_bf16(ah, bl, acc[ct], 0, 0, 0);
      acc[ct] = __builtin_amdgcn_mfma_f32_16x16x32_bf16(al, bh, acc[ct], 0, 0, 0);
    }
  }
  float bi[4];
#pragma unroll
  for (int r = 0; r < 4; ++r) bi[r] = bias[(hh << 7) + (wv << 4) + rsub + r];
#pragma unroll
  for (int ct = 0; ct < 8; ++ct) {
    int lglob = (lt << 7) + (ct << 4) + lrow;
#pragma unroll
    for (int r = 0; r < 4; ++r) {
      int hglob = (hh << 7) + (wv << 4) + rsub + r;
      hbuf[((size_t)(b * H_SZ + hglob) << 11) + lglob] = acc[ct][r] + bi[r];
    }
  }
}

// ---------------- convert w_out to bf16 ----------------
__global__ void k_cvtw(const float* __restrict__ w, unsigned short* __restrict__ wbf, int n) {
  int i = blockIdx.x * 256 + threadIdx.x;
  if (i < n) wbf[i] = f2b(w[i]);
}

// ---------------- precompute per-state params: lr, li, c2r, c2i, lTr, lTi ----------------
__global__ void k_params(const float* __restrict__ log_dt, const float* __restrict__ log_A_real,
                         const float* __restrict__ A_imag, const float* __restrict__ C_re,
                         const float* __restrict__ C_im, float* __restrict__ par) {
  int id = blockIdx.x * 256 + threadIdx.x;  // i*8192 + h*32 + n
  if (id >= NL * H_SZ * NH) return;
  int i = id >> 13;
  int hn = id & 8191;
  int h = hn >> 5;
  float dt = expf(log_dt[i * H_SZ + h]);
  float Ar = -expf(log_A_real[(size_t)i * H_SZ * NH + hn]);
  float Ai = A_imag[(size_t)i * H_SZ * NH + hn];
  float dr = dt * Ar, di = dt * Ai;
  float e = expf(dr), sn, cs;
  sincosf(di, &sn, &cs);
  float lr = e * cs, li = e * sn;
  float eT = expf((float)TC * dr), snT, csT;
  sincosf((float)TC * di, &snT, &csT);
  float Cr = C_re[(size_t)i * H_SZ * NH + hn], Ci = C_im[(size_t)i * H_SZ * NH + hn];
  float wr = lr - 1.f, wi = li;
  float pr = Cr * wr - Ci * wi;
  float pi = Cr * wi + Ci * wr;
  float inv = 2.f / fmaf(Ar, Ar, Ai * Ai);
  float4* p = (float4*)(par + (size_t)id * 8);
  p[0] = make_float4(lr, li, (pr * Ar + pi * Ai) * inv, (pi * Ar - pr * Ai) * inv);
  p[1] = make_float4(eT * csT, eT * snT, 0.f, 0.f);
}

// ---------------- merged SSM kernel: finals + prefix + conv + D-skip + GELU ----------------
__launch_bounds__(512, 1)
__global__ void k_ssm(const float* __restrict__ hbuf, float2* __restrict__ sF2,
                      const float* __restrict__ par, const float* __restrict__ D_skip,
                      unsigned short* __restrict__ yloc) {
  __shared__ __align__(16) unsigned short xbh[256][72];
  __shared__ __align__(16) unsigned short xbl[256][72];
  __shared__ __align__(16) unsigned short Uh[64][72];
  __shared__ __align__(16) unsigned short Ul[64][72];
  __shared__ __align__(16) unsigned short Th[64][72];
  __shared__ __align__(16) unsigned short Tl[64][72];
  __shared__ __align__(16) unsigned short Wh[64][72];
  __shared__ __align__(16) unsigned short Wl[64][72];
  __shared__ float Kc[64];
  int tid = threadIdx.x;
  int h = blockIdx.x;
  float* Wm = (float*)&xbh[0][0];  // [64][66] f32 scratch, dead before x staging

  if (tid < 64) {
    int n = tid >> 1, q = tid & 1;
    const float* pb = par + (size_t)(h * NH + n) * 8;
    float lr = pb[0], li = pb[1], c2r = pb[2], c2i = pb[3];
    float pr = lr, pi = li;  // lam^1
    if (q) {                 // lam^33
      float sr = lr, si = li;
#pragma unroll
      for (int t = 0; t < 5; ++t) { float nr2 = sr * sr - si * si; si = 2.f * sr * si; sr = nr2; }
      pr = sr * lr - si * li; pi = sr * li + si * lr;
    }
    int p = q << 5;
    for (int s = 0; s < 32; ++s, ++p) {
      Wm[p * 66 + 2 * n] = c2r * pr - c2i * pi;
      Wm[p * 66 + 2 * n + 1] = -(c2r * pi + c2i * pr);
      float nr2 = pr * lr - pi * li;
      pi = pr * li + pi * lr;
      pr = nr2;
    }
  }
  __syncthreads();
  if (tid < 64) {
    float kv = 0.f;
    if (tid == 0) {
      for (int n = 0; n < 32; ++n) kv += par[(size_t)(h * NH + n) * 8 + 2];
    } else {
      for (int n = 0; n < 32; ++n) kv += Wm[(tid - 1) * 66 + 2 * n];
    }
    Kc[tid] = kv;
  }
  {
    int base = tid * 8;
    int row = base >> 6, col0 = base & 63;
#pragma unroll
    for (int e = 0; e < 8; ++e) {
      float v = Wm[row * 66 + col0 + e];
      unsigned short hv = f2b(v);
      Wh[row][col0 + e] = hv; Wl[row][col0 + e] = f2b(v - b2f(hv));
    }
  }
  __syncthreads();
  {
    int base = tid * 8;
    int row = base >> 6, col0 = base & 63;
#pragma unroll
    for (int e = 0; e < 8; ++e) {
      int col = col0 + e;
      float v = (col <= row) ? Kc[row - col] : 0.f;
      unsigned short hv = f2b(v);
      Th[row][col] = hv; Tl[row][col] = f2b(v - b2f(hv));
    }
  }
  if (tid < 64) {
    int n = tid >> 1, q = tid & 1;
    const float* pb = par + (size_t)(h * NH + n) * 8;
    float lr = pb[0], li = pb[1];
    float pr = 1.f, pi = 0.f;
    if (q) {
      float sr = lr, si = li;
#pragma unroll
      for (int t = 0; t < 5; ++t) { float nr2 = sr * sr - si * si; si = 2.f * sr * si; sr = nr2; }
      pr = sr; pi = si;
    }
    int p = q << 5;
    for (int s = 0; s < 32; ++s, ++p) {
      int col = 63 - p;
      unsigned short hr = f2b(pr);
      Uh[2 * n][col] = hr; Ul[2 * n][col] = f2b(pr - b2f(hr));
      unsigned short hm = f2b(pi);
      Uh[2 * n + 1][col] = hm; Ul[2 * n + 1][col] = f2b(pi - b2f(hm));
      float nr2 = pr * lr - pi * li;
      pi = pr * li + pi * lr;
      pr = nr2;
    }
  }

  int wv = tid >> 6, lane = tid & 63;
  int lrow = lane & 15, lk8 = (lane >> 4) << 3;
  int rt = wv >> 1;
  int ct0 = (wv & 1) << 3;
  int rsub = (lane >> 4) << 2;
  float Dh = D_skip[h];

  for (int half = 0; half < 2; ++half) {
    __syncthreads();
    {
      int colh = tid >> 1, j0 = (tid & 1) << 5;
      int b = (half << 3) + (colh >> 5), c = colh & 31;
      const float* src = hbuf + ((size_t)(b * H_SZ + h) << 11) + (c << 6) + j0;
      unsigned short* dh = &xbh[colh][j0];
      unsigned short* dl = &xbl[colh][j0];
#pragma unroll
      for (int jj = 0; jj < 8; ++jj) {
        float4 v = *(const float4*)(src + jj * 4);
        unsigned short h0 = f2b(v.x); dh[jj * 4 + 0] = h0; dl[jj * 4 + 0] = f2b(v.x - b2f(h0));
        unsigned short h1 = f2b(v.y); dh[jj * 4 + 1] = h1; dl[jj * 4 + 1] = f2b(v.y - b2f(h1));
        unsigned short h2 = f2b(v.z); dh[jj * 4 + 2] = h2; dl[jj * 4 + 2] = f2b(v.z - b2f(h2));
        unsigned short h3 = f2b(v.w); dh[jj * 4 + 3] = h3; dl[jj * 4 + 3] = f2b(v.w - b2f(h3));
      }
    }
    __syncthreads();
    // ---- U-GEMM: chunk finals -> sF2 (f32) ----
    {
      f32x4 uacc[8];
#pragma unroll
      for (int ct = 0; ct < 8; ++ct) uacc[ct] = (f32x4){0.f, 0.f, 0.f, 0.f};
#pragma unroll
      for (int kk = 0; kk < 2; ++kk) {
        bf16x8 ah = *(const bf16x8*)&Uh[(rt << 4) + lrow][(kk << 5) + lk8];
        bf16x8 al = *(const bf16x8*)&Ul[(rt << 4) + lrow][(kk << 5) + lk8];
#pragma unroll
        for (int ct = 0; ct < 8; ++ct) {
          int col = ((ct0 + ct) << 4) + lrow;
          bf16x8 bh = *(const bf16x8*)&xbh[col][(kk << 5) + lk8];
          bf16x8 bl = *(const bf16x8*)&xbl[col][(kk << 5) + lk8];
          uacc[ct] = __builtin_amdgcn_mfma_f32_16x16x32_bf16(ah, bh, uacc[ct], 0, 0, 0);
          uacc[ct] = __builtin_amdgcn_mfma_f32_16x16x32_bf16(ah, bl, uacc[ct], 0, 0, 0);
          uacc[ct] = __builtin_amdgcn_mfma_f32_16x16x32_bf16(al, bh, uacc[ct], 0, 0, 0);
        }
      }
      int n0 = (rt << 3) + ((lane >> 4) << 1);
#pragma unroll
      for (int ct = 0; ct < 8; ++ct) {
        int colg = (half << 8) + ((ct0 + ct) << 4) + lrow;
        float2* o = sF2 + (size_t)colg * (H_SZ * NH) + h * NH + n0;
        o[0] = make_float2(uacc[ct][0], uacc[ct][1]);
        o[1] = make_float2(uacc[ct][2], uacc[ct][3]);
      }
    }
    // ---- T-GEMM (x still staged) ----
    f32x4 acc[8];
#pragma unroll
    for (int ct = 0; ct < 8; ++ct) acc[ct] = (f32x4){0.f, 0.f, 0.f, 0.f};
#pragma unroll
    for (int kk = 0; kk < 2; ++kk) {
      bf16x8 ah = *(const bf16x8*)&Th[(rt << 4) + lrow][(kk << 5) + lk8];
      bf16x8 al = *(const bf16x8*)&Tl[(rt << 4) + lrow][(kk << 5) + lk8];
#pragma unroll
      for (int ct = 0; ct < 8; ++ct) {
        int col = ((ct0 + ct) << 4) + lrow;
        bf16x8 bh = *(const bf16x8*)&xbh[col][(kk << 5) + lk8];
        bf16x8 bl = *(const bf16x8*)&xbl[col][(kk << 5) + lk8];
        acc[ct] = __builtin_amdgcn_mfma_f32_16x16x32_bf16(ah, bh, acc[ct], 0, 0, 0);
        acc[ct] = __builtin_amdgcn_mfma_f32_16x16x32_bf16(ah, bl, acc[ct], 0, 0, 0);
        acc[ct] = __builtin_amdgcn_mfma_f32_16x16x32_bf16(al, bh, acc[ct], 0, 0, 0);
      }
    }
    // ---- add D-skip term while x is still staged (x = hi + lo, ~exact) ----
    {
#pragma unroll
      for (int ct = 0; ct < 8; ++ct) {
        int col = ((ct0 + ct) << 4) + lrow;
        int row = (rt << 4) + rsub;
        ushort4 xh4 = *(const ushort4*)&xbh[col][row];
        ushort4 xl4 = *(const ushort4*)&xbl[col][row];
        acc[ct][0] = fmaf(Dh, b2f(xh4.x) + b2f(xl4.x), acc[ct][0]);
        acc[ct][1] = fmaf(Dh, b2f(xh4.y) + b2f(xl4.y), acc[ct][1]);
        acc[ct][2] = fmaf(Dh, b2f(xh4.z) + b2f(xl4.z), acc[ct][2]);
        acc[ct][3] = fmaf(Dh, b2f(xh4.w) + b2f(xl4.w), acc[ct][3]);
      }
    }
    __syncthreads();
    // ---- exclusive prefix over this half's 8 b (in place, f32 exact) ----
    if (tid < 256) {
      int b = (half << 3) + (tid >> 5), n = tid & 31;
      const float* pb = par + (size_t)(h * NH + n) * 8;
      float lTr = pb[4], lTi = pb[5];
      float cr = 0.f, ci = 0.f;
      float2* p0 = sF2 + (size_t)(b << 5) * (H_SZ * NH) + h * NH + n;
      const size_t cstride = H_SZ * NH;
      float2 f = p0[0];
      for (int c = 0; c < NTC; ++c) {
        float2 fn = f;
        if (c + 1 < NTC) fn = p0[(size_t)(c + 1) * cstride];
        p0[(size_t)c * cstride] = make_float2(cr, ci);
        float nr = fmaf(lTr, cr, f.x); nr = fmaf(-lTi, ci, nr);
        float ni = fmaf(lTr, ci, f.y); ni = fmaf(lTi, cr, ni);
        cr = nr; ci = ni;
        f = fn;
      }
    }
    __syncthreads();
    // ---- stage svec (carries) hi/lo into xbh/xbl ----
    {
      int colh = tid >> 1, n0 = (tid & 1) << 4;
      int colg = (half << 8) + colh;
      const float2* cp = sF2 + (size_t)colg * (H_SZ * NH) + h * NH;
#pragma unroll
      for (int n = 0; n < 16; ++n) {
        float2 s = cp[n0 + n];
        int k2 = 2 * (n0 + n);
        unsigned short hr = f2b(s.x);
        xbh[colh][k2] = hr; xbl[colh][k2] = f2b(s.x - b2f(hr));
        unsigned short hm = f2b(s.y);
        xbh[colh][k2 + 1] = hm; xbl[colh][k2 + 1] = f2b(s.y - b2f(hm));
      }
    }
    __syncthreads();
    // ---- W-GEMM (carry contribution), accumulate; gelu; write y bf16 ----
#pragma unroll
    for (int kk = 0; kk < 2; ++kk) {
      bf16x8 ah = *(const bf16x8*)&Wh[(rt << 4) + lrow][(kk << 5) + lk8];
      bf16x8 al = *(const bf16x8*)&Wl[(rt << 4) + lrow][(kk << 5) + lk8];
#pragma unroll
      for (int ct = 0; ct < 8; ++ct) {
        int col = ((ct0 + ct) << 4) + lrow;
        bf16x8 bh = *(const bf16x8*)&xbh[col][(kk << 5) + lk8];
        bf16x8 bl = *(const bf16x8*)&xbl[col][(kk << 5) + lk8];
        acc[ct] = __builtin_amdgcn_mfma_f32_16x16x32_bf16(ah, bh, acc[ct], 0, 0, 0);
        acc[ct] = __builtin_amdgcn_mfma_f32_16x16x32_bf16(ah, bl, acc[ct], 0, 0, 0);
        acc[ct] = __builtin_amdgcn_mfma_f32_16x16x32_bf16(al, bh, acc[ct], 0, 0, 0);
      }
    }
#pragma unroll
    for (int ct = 0; ct < 8; ++ct) {
      int colg = (half << 8) + ((ct0 + ct) << 4) + lrow;
      ushort4 o;
      o.x = f2b(gelu_exact(acc[ct][0]));
      o.y = f2b(gelu_exact(acc[ct][1]));
      o.z = f2b(gelu_exact(acc[ct][2]));
      o.w = f2b(gelu_exact(acc[ct][3]));
      *(ushort4*)(yloc + (size_t)h * (B_SZ * L_SZ) + (size_t)colg * 64 + (rt << 4) + rsub) = o;
    }
  }
}

// ---------------- post: yt copy + GLU + LN (yt XOR-swizzled) ----------------
__launch_bounds__(1024, 4)
__global__ void k_layer2(float* __restrict__ hbuf, const unsigned short* __restrict__ yloc,
                         const unsigned short* __restrict__ wbf,
                         const float* __restrict__ b_out,
                         const float* __restrict__ ln_g, const float* __restrict__ ln_b,
                         float* __restrict__ pooledPart, int last) {
  __shared__ __align__(16) unsigned short yt[TC * YROW];
  __shared__ float part[TC][16][2];
  __shared__ float stats[TC][2];
  int tid = threadIdx.x;
  int b = blockIdx.x >> 5;
  int c = blockIdx.x & 31;
  int l0 = c << 6;

  // ---- fill: yloc (already gelu'd) -> yt transpose copy ----
  {
    int h = tid >> 2, q = tid & 3;
    const unsigned short* yp2 = yloc + (size_t)h * (B_SZ * L_SZ) + b * L_SZ + l0 + (q << 4);
#pragma unroll
    for (int jj = 0; jj < 16; jj += 4) {
      ushort4 yv = *(const ushort4*)(yp2 + jj);
      int jb = (q << 4) + jj;
      yt[yswz(jb + 0, h)] = yv.x;
      yt[yswz(jb + 1, h)] = yv.y;
      yt[yswz(jb + 2, h)] = yv.z;
      yt[yswz(jb + 3, h)] = yv.w;
    }
  }
  __syncthreads();
  // ---- GLU: 1x1 conv via MFMA; z -> yt ----
  {
    int w = tid >> 6, lane = tid & 63;
    int lrow = lane & 15, lk8 = (lane >> 4) << 3;
    f32x4 accA[4], accG[4];
    f32x4 zed = {0.f, 0.f, 0.f, 0.f};
#pragma unroll
    for (int jt = 0; jt < 4; ++jt) { accA[jt] = zed; accG[jt] = zed; }
    const unsigned short* wA = wbf + ((w << 4) + lrow) * H_SZ;
    const unsigned short* wG = wA + 256 * H_SZ;
#pragma unroll
    for (int k0 = 0; k0 < H_SZ; k0 += 32) {
      bf16x8 a0 = *(const bf16x8*)(wA + k0 + lk8);
      bf16x8 a1 = *(const bf16x8*)(wG + k0 + lk8);
#pragma unroll
      for (int jt = 0; jt < 4; ++jt) {
        bf16x8 bb = *(const bf16x8*)&yt[yswz((jt << 4) + lrow, k0 + lk8)];
        accA[jt] = __builtin_amdgcn_mfma_f32_16x16x32_bf16(a0, bb, accA[jt], 0, 0, 0);
        accG[jt] = __builtin_amdgcn_mfma_f32_16x16x32_bf16(a1, bb, accG[jt], 0, 0, 0);
      }
    }
    __syncthreads();  // all y reads done before overwrite with z
    int rbase = (lane >> 4) << 2;
    float bA[4], bG[4];
#pragma unroll
    for (int r = 0; r < 4; ++r) {
      bA[r] = b_out[(w << 4) + rbase + r];
      bG[r] = b_out[256 + (w << 4) + rbase + r];
    }
#pragma unroll
    for (int jt = 0; jt < 4; ++jt) {
      ushort4 o;
      float a0 = accA[jt][0] + bA[0], g0 = accG[jt][0] + bG[0];
      float a1 = accA[jt][1] + bA[1], g1 = accG[jt][1] + bG[1];
      float a2 = accA[jt][2] + bA[2], g2 = accG[jt][2] + bG[2];
      float a3 = accA[jt][3] + bA[3], g3 = accG[jt][3] + bG[3];
      o.x = f2b(a0 / (1.f + expf(-g0)));
      o.y = f2b(a1 / (1.f + expf(-g1)));
      o.z = f2b(a2 / (1.f + expf(-g2)));
      o.w = f2b(a3 / (1.f + expf(-g3)));
      *(ushort4*)&yt[yswz((jt << 4) + lrow, (w << 4) + rbase)] = o;
    }
  }
  __syncthreads();
  // ---- LN stats; v = z + residual ----
  int j = tid & 63, hg = tid >> 6;
  float vreg[16];
  {
    const float* xc = hbuf + (b * H_SZ + (hg << 4)) * L_SZ + l0 + j;
    float s = 0.f, sq = 0.f;
    ushort4 za = *(const ushort4*)&yt[yswz(j, (hg << 4) + 0)];
    ushort4 zb = *(const ushort4*)&yt[yswz(j, (hg << 4) + 4)];
    ushort4 zc = *(const ushort4*)&yt[yswz(j, (hg << 4) + 8)];
    ushort4 zd = *(const ushort4*)&yt[yswz(j, (hg << 4) + 12)];
    unsigned short zz[16] = {za.x, za.y, za.z, za.w, zb.x, zb.y, zb.z, zb.w,
                             zc.x, zc.y, zc.z, zc.w, zd.x, zd.y, zd.z, zd.w};
#pragma unroll
    for (int k = 0; k < 16; ++k) {
      float v = b2f(zz[k]) + xc[(size_t)k * L_SZ];
      vreg[k] = v;
      s += v; sq = fmaf(v, v, sq);
    }
    part[j][hg][0] = s; part[j][hg][1] = sq;
  }
  __syncthreads();
  if (tid < TC) {
    float s = 0.f, sq = 0.f;
#pragma unroll
    for (int g = 0; g < 16; ++g) { s += part[tid][g][0]; sq += part[tid][g][1]; }
    float mu = s * (1.f / 256.f);
    float var = sq * (1.f / 256.f) - mu * mu;
    stats[tid][0] = mu;
    stats[tid][1] = rsqrtf(var + 1e-5f);
  }
  __syncthreads();
  {
    float mu = stats[j][0], rs = stats[j][1];
    if (!last) {
      float* xo = hbuf + (b * H_SZ + (hg << 4)) * L_SZ + l0 + j;
#pragma unroll
      for (int k = 0; k < 16; ++k) {
        int hh = (hg << 4) + k;
        xo[(size_t)k * L_SZ] = (vreg[k] - mu) * rs * ln_g[hh] + ln_b[hh];
      }
    } else {
#pragma unroll
      for (int k = 0; k < 16; ++k) {
        int hh = (hg << 4) + k;
        yt[yswz(j, hh)] = f2b((vreg[k] - mu) * rs * ln_g[hh] + ln_b[hh]);
      }
      __syncthreads();
      if (tid < H_SZ) {
        float s = 0.f;
        for (int jj = 0; jj < TC; ++jj) s += b2f(yt[yswz(jj, tid)]);
        pooledPart[(((b << 5) + c) << 8) + tid] = s;
      }
    }
  }
}

// ---------------- pool: reduce 32 chunk-partials per (b,h) ----------------
__global__ void k_pool(const float* __restrict__ pooledPart, float* __restrict__ P) {
  int b = blockIdx.x, hh = threadIdx.x;
  float s = 0.f;
#pragma unroll
  for (int cpart = 0; cpart < 32; ++cpart)
    s += pooledPart[(((b << 5) + cpart) << 8) + hh];
  P[(b << 8) + hh] = s * (1.f / 2048.f);
}

// ---------------- decoder MLP: one block per batch row ----------------
__global__ void k_dec(const float* __restrict__ P,
                      const float* __restrict__ w1, const float* __restrict__ b1,
                      const float* __restrict__ w2, const float* __restrict__ b2,
                      const float* __restrict__ w3, const float* __restrict__ b3,
                      float* __restrict__ out) {
  __shared__ float Pr[256];
  __shared__ float O1[128];
  __shared__ float O2[64];
  int b = blockIdx.x, tid = threadIdx.x;
  Pr[tid] = P[(b << 8) + tid];
  __syncthreads();
  if (tid < 128) {
    float acc = b1[tid];
    for (int d = 0; d < 256; ++d) acc = fmaf(Pr[d], w1[(d << 7) + tid], acc);
    O1[tid] = fmaxf(acc, 0.f);
  }
  __syncthreads();
  if (tid < 64) {
    float acc = b2[tid];
    for (int d = 0; d < 128; ++d) acc = fmaf(O1[d], w2[(d << 6) + tid], acc);
    O2[tid] = fmaxf(acc, 0.f);
  }
  __syncthreads();
  if (tid < 32) {
    float acc = b3[tid];
    for (int d = 0; d < 64; ++d) acc = fmaf(O2[d], w3[(d << 5) + tid], acc);
    out[(b << 5) + tid] = acc;
  }
}

extern "C" void kernel_launch(void* const* d_in, const int* in_sizes, int n_in,
                              void* d_out, int out_size, void* d_ws, size_t ws_size,
                              hipStream_t stream) {
  const float* x          = (const float*)d_in[0];
  const float* enc_w      = (const float*)d_in[1];
  const float* enc_b      = (const float*)d_in[2];
  const float* log_dt     = (const float*)d_in[3];
  const float* C_re       = (const float*)d_in[4];
  const float* C_im       = (const float*)d_in[5];
  const float* log_A_real = (const float*)d_in[6];
  const float* A_imag     = (const float*)d_in[7];
  const float* D_skip     = (const float*)d_in[8];
  const float* w_out      = (const float*)d_in[9];
  const float* b_out      = (const float*)d_in[10];
  const float* ln_g       = (const float*)d_in[11];
  const float* ln_b       = (const float*)d_in[12];
  const float* dw1        = (const float*)d_in[13];
  const float* db1        = (const float*)d_in[14];
  const float* dw2        = (const float*)d_in[15];
  const float* db2        = (const float*)d_in[16];
  const float* dw3        = (const float*)d_in[17];
  const float* db3        = (const float*)d_in[18];

  char* ws = (char*)d_ws;
  float* hbuf = (float*)ws;                                  // 33,554,432 B
  float2* sF2 = (float2*)(ws + 33554432);                    // 33,554,432 B
  unsigned short* yloc = (unsigned short*)(ws + 67108864);   // 16,777,216 B (bf16)
  unsigned short* wbf = (unsigned short*)(ws + 83886080);    //  1,048,576 B
  float* par = (float*)(ws + 84934656);                      //  1,048,576 B
  float* pooledPart = (float*)(ws + 85983232);               //    524,288 B
  float* P = (float*)(ws + 86507520);                        //     16,384 B

  k_encoder<<<512, 512, 0, stream>>>(x, enc_w, enc_b, hbuf);
  k_cvtw<<<2048, 256, 0, stream>>>(w_out, wbf, NL * 512 * H_SZ);
  k_params<<<128, 256, 0, stream>>>(log_dt, log_A_real, A_imag, C_re, C_im, par);
  const size_t PAR_STRIDE = (size_t)H_SZ * NH * 8;
  for (int i = 0; i < NL; ++i) {
    const float* pari = par + i * PAR_STRIDE;
    k_ssm<<<256, 512, 0, stream>>>(hbuf, sF2, pari, D_skip + i * H_SZ, yloc);
    k_layer2<<<512, 1024, 0, stream>>>(hbuf, yloc,
                                       wbf + i * 512 * H_SZ, b_out + i * 512,
                                       ln_g + i * H_SZ, ln_b + i * H_SZ,
                                       pooledPart, (i == NL - 1) ? 1 : 0);
  }
  k_pool<<<16, 256, 0, stream>>>(pooledPart, P);
  k_dec<<<16, 256, 0, stream>>>(P, dw1, db1, dw2, db2, dw3, db3, (float*)d_out);
}

// Round 15
// 321.169 us; speedup vs baseline: 3.2594x; 1.1577x over previous
//
#include <hip/hip_runtime.h>

#define B_SZ 16
#define L_SZ 2048
#define DIN 64
#define H_SZ 256
#define NH 32
#define NL 4
#define TC 64
#define NTC 32
#define YROW (H_SZ + 8)

typedef __attribute__((ext_vector_type(8))) __bf16 bf16x8;
typedef __attribute__((ext_vector_type(4))) float f32x4;

__device__ __forceinline__ unsigned short f2b(float f) {
  unsigned int u = __builtin_bit_cast(unsigned int, f);
  unsigned int r = u + 0x7fffu + ((u >> 16) & 1u);  // RNE (no NaN inputs here)
  return (unsigned short)(r >> 16);
}
__device__ __forceinline__ float b2f(unsigned short u) {
  unsigned int v = ((unsigned int)u) << 16;
  return __builtin_bit_cast(float, v);
}
__device__ __forceinline__ float gelu_exact(float v) {
  return 0.5f * v * (1.f + erff(v * 0.70710678118654752f));
}
// 16B-granule XOR swizzle for yt
__device__ __forceinline__ int yswz(int row, int col) {
  return (row * YROW + col) ^ (((row >> 3) & 7) << 3);
}

// ---------------- encoder as compensated MFMA GEMM ----------------
__launch_bounds__(512, 4)
__global__ void k_encoder(const float* __restrict__ x, const float* __restrict__ w,
                          const float* __restrict__ bias, float* __restrict__ hbuf) {
  __shared__ __align__(16) unsigned short Wh[128][72];
  __shared__ __align__(16) unsigned short Wl[128][72];
  __shared__ __align__(16) unsigned short xh[128][72];
  __shared__ __align__(16) unsigned short xl[128][72];
  int tid = threadIdx.x;
  int blk = blockIdx.x;           // b(4b) lt(4b) hh(1b)
  int b = blk >> 5;
  int lt = (blk >> 1) & 15;
  int hh = blk & 1;

#pragma unroll
  for (int i = 0; i < 16; ++i) {
    int flat = i * 512 + tid;
    int d = flat >> 7, hl = flat & 127;
    float v = w[d * H_SZ + (hh << 7) + hl];
    unsigned short hv = f2b(v);
    Wh[hl][d] = hv; Wl[hl][d] = f2b(v - b2f(hv));
  }
  {
    int l = tid >> 2, d0 = (tid & 3) << 4;
    const float* src = x + ((size_t)(b * L_SZ + (lt << 7) + l) << 6) + d0;
    unsigned short* dh = &xh[l][d0];
    unsigned short* dl = &xl[l][d0];
#pragma unroll
    for (int jj = 0; jj < 4; ++jj) {
      float4 v = *(const float4*)(src + jj * 4);
      unsigned short h0 = f2b(v.x); dh[jj * 4 + 0] = h0; dl[jj * 4 + 0] = f2b(v.x - b2f(h0));
      unsigned short h1 = f2b(v.y); dh[jj * 4 + 1] = h1; dl[jj * 4 + 1] = f2b(v.y - b2f(h1));
      unsigned short h2 = f2b(v.z); dh[jj * 4 + 2] = h2; dl[jj * 4 + 2] = f2b(v.z - b2f(h2));
      unsigned short h3 = f2b(v.w); dh[jj * 4 + 3] = h3; dl[jj * 4 + 3] = f2b(v.w - b2f(h3));
    }
  }
  __syncthreads();

  int wv = tid >> 6, lane = tid & 63;
  int lrow = lane & 15, lk8 = (lane >> 4) << 3;
  int rsub = (lane >> 4) << 2;
  f32x4 acc[8];
#pragma unroll
  for (int ct = 0; ct < 8; ++ct) acc[ct] = (f32x4){0.f, 0.f, 0.f, 0.f};
#pragma unroll
  for (int kk = 0; kk < 2; ++kk) {
    bf16x8 ah = *(const bf16x8*)&Wh[(wv << 4) + lrow][(kk << 5) + lk8];
    bf16x8 al = *(const bf16x8*)&Wl[(wv << 4) + lrow][(kk << 5) + lk8];
#pragma unroll
    for (int ct = 0; ct < 8; ++ct) {
      bf16x8 bh = *(const bf16x8*)&xh[(ct << 4) + lrow][(kk << 5) + lk8];
      bf16x8 bl = *(const bf16x8*)&xl[(ct << 4) + lrow][(kk << 5) + lk8];
      acc[ct] = __builtin_amdgcn_mfma_f32_16x16x32_bf16(ah, bh, acc[ct], 0, 0, 0);
      acc[ct] = __builtin_amdgcn_mfma_f32_16x16x32_bf16(ah, bl, acc[ct], 0, 0, 0);
      acc[ct] = __builtin_amdgcn_mfma_f32_16x16x32_bf16(al, bh, acc[ct], 0, 0, 0);
    }
  }
  float bi[4];
#pragma unroll
  for (int r = 0; r < 4; ++r) bi[r] = bias[(hh << 7) + (wv << 4) + rsub + r];
#pragma unroll
  for (int ct = 0; ct < 8; ++ct) {
    int lglob = (lt << 7) + (ct << 4) + lrow;
#pragma unroll
    for (int r = 0; r < 4; ++r) {
      int hglob = (hh << 7) + (wv << 4) + rsub + r;
      hbuf[((size_t)(b * H_SZ + hglob) << 11) + lglob] = acc[ct][r] + bi[r];
    }
  }
}

// ---------------- convert w_out to bf16 ----------------
__global__ void k_cvtw(const float* __restrict__ w, unsigned short* __restrict__ wbf, int n) {
  int i = blockIdx.x * 256 + threadIdx.x;
  if (i < n) wbf[i] = f2b(w[i]);
}

// ---------------- precompute per-state params: lr, li, c2r, c2i, lTr, lTi ----------------
__global__ void k_params(const float* __restrict__ log_dt, const float* __restrict__ log_A_real,
                         const float* __restrict__ A_imag, const float* __restrict__ C_re,
                         const float* __restrict__ C_im, float* __restrict__ par) {
  int id = blockIdx.x * 256 + threadIdx.x;  // i*8192 + h*32 + n
  if (id >= NL * H_SZ * NH) return;
  int i = id >> 13;
  int hn = id & 8191;
  int h = hn >> 5;
  float dt = expf(log_dt[i * H_SZ + h]);
  float Ar = -expf(log_A_real[(size_t)i * H_SZ * NH + hn]);
  float Ai = A_imag[(size_t)i * H_SZ * NH + hn];
  float dr = dt * Ar, di = dt * Ai;
  float e = expf(dr), sn, cs;
  sincosf(di, &sn, &cs);
  float lr = e * cs, li = e * sn;
  float eT = expf((float)TC * dr), snT, csT;
  sincosf((float)TC * di, &snT, &csT);
  float Cr = C_re[(size_t)i * H_SZ * NH + hn], Ci = C_im[(size_t)i * H_SZ * NH + hn];
  float wr = lr - 1.f, wi = li;
  float pr = Cr * wr - Ci * wi;
  float pi = Cr * wi + Ci * wr;
  float inv = 2.f / fmaf(Ar, Ar, Ai * Ai);
  float4* p = (float4*)(par + (size_t)id * 8);
  p[0] = make_float4(lr, li, (pr * Ar + pi * Ai) * inv, (pi * Ar - pr * Ai) * inv);
  p[1] = make_float4(eT * csT, eT * snT, 0.f, 0.f);
}

// ---------------- merged SSM kernel: finals + prefix (all in LDS) + conv + D-skip + GELU ----
__launch_bounds__(512, 1)
__global__ void k_ssm(const float* __restrict__ hbuf, const float* __restrict__ par,
                      const float* __restrict__ D_skip, unsigned short* __restrict__ yloc) {
  __shared__ __align__(16) unsigned short xbh[256][72];
  __shared__ __align__(16) unsigned short xbl[256][72];
  __shared__ __align__(16) unsigned short Uh[64][72];
  __shared__ __align__(16) unsigned short Ul[64][72];
  __shared__ __align__(16) unsigned short Th[64][72];
  __shared__ __align__(16) unsigned short Tl[64][72];
  __shared__ __align__(16) unsigned short Wh[64][72];
  __shared__ __align__(16) unsigned short Wl[64][72];
  __shared__ float Kc[64];
  int tid = threadIdx.x;
  int h = blockIdx.x;
  float* Wm = (float*)&xbh[0][0];  // [64][66] f32 scratch, dead before x staging

  if (tid < 64) {
    int n = tid >> 1, q = tid & 1;
    const float* pb = par + (size_t)(h * NH + n) * 8;
    float lr = pb[0], li = pb[1], c2r = pb[2], c2i = pb[3];
    float pr = lr, pi = li;  // lam^1
    if (q) {                 // lam^33
      float sr = lr, si = li;
#pragma unroll
      for (int t = 0; t < 5; ++t) { float nr2 = sr * sr - si * si; si = 2.f * sr * si; sr = nr2; }
      pr = sr * lr - si * li; pi = sr * li + si * lr;
    }
    int p = q << 5;
    for (int s = 0; s < 32; ++s, ++p) {
      Wm[p * 66 + 2 * n] = c2r * pr - c2i * pi;
      Wm[p * 66 + 2 * n + 1] = -(c2r * pi + c2i * pr);
      float nr2 = pr * lr - pi * li;
      pi = pr * li + pi * lr;
      pr = nr2;
    }
  }
  __syncthreads();
  if (tid < 64) {
    float kv = 0.f;
    if (tid == 0) {
      for (int n = 0; n < 32; ++n) kv += par[(size_t)(h * NH + n) * 8 + 2];
    } else {
      for (int n = 0; n < 32; ++n) kv += Wm[(tid - 1) * 66 + 2 * n];
    }
    Kc[tid] = kv;
  }
  {
    int base = tid * 8;
    int row = base >> 6, col0 = base & 63;
#pragma unroll
    for (int e = 0; e < 8; ++e) {
      float v = Wm[row * 66 + col0 + e];
      unsigned short hv = f2b(v);
      Wh[row][col0 + e] = hv; Wl[row][col0 + e] = f2b(v - b2f(hv));
    }
  }
  __syncthreads();
  {
    int base = tid * 8;
    int row = base >> 6, col0 = base & 63;
#pragma unroll
    for (int e = 0; e < 8; ++e) {
      int col = col0 + e;
      float v = (col <= row) ? Kc[row - col] : 0.f;
      unsigned short hv = f2b(v);
      Th[row][col] = hv; Tl[row][col] = f2b(v - b2f(hv));
    }
  }
  if (tid < 64) {
    int n = tid >> 1, q = tid & 1;
    const float* pb = par + (size_t)(h * NH + n) * 8;
    float lr = pb[0], li = pb[1];
    float pr = 1.f, pi = 0.f;
    if (q) {
      float sr = lr, si = li;
#pragma unroll
      for (int t = 0; t < 5; ++t) { float nr2 = sr * sr - si * si; si = 2.f * sr * si; sr = nr2; }
      pr = sr; pi = si;
    }
    int p = q << 5;
    for (int s = 0; s < 32; ++s, ++p) {
      int col = 63 - p;
      unsigned short hr = f2b(pr);
      Uh[2 * n][col] = hr; Ul[2 * n][col] = f2b(pr - b2f(hr));
      unsigned short hm = f2b(pi);
      Uh[2 * n + 1][col] = hm; Ul[2 * n + 1][col] = f2b(pi - b2f(hm));
      float nr2 = pr * lr - pi * li;
      pi = pr * li + pi * lr;
      pr = nr2;
    }
  }

  int wv = tid >> 6, lane = tid & 63;
  int lrow = lane & 15, lk8 = (lane >> 4) << 3;
  int rt = wv >> 1;
  int ct0 = (wv & 1) << 3;
  int rsub = (lane >> 4) << 2;
  float Dh = D_skip[h];

  for (int half = 0; half < 2; ++half) {
    __syncthreads();  // matrices ready / previous half's svec reads done
    // ---- stage x hi/lo ----
    {
      int colh = tid >> 1, j0 = (tid & 1) << 5;
      int b = (half << 3) + (colh >> 5), c = colh & 31;
      const float* src = hbuf + ((size_t)(b * H_SZ + h) << 11) + (c << 6) + j0;
      unsigned short* dh = &xbh[colh][j0];
      unsigned short* dl = &xbl[colh][j0];
#pragma unroll
      for (int jj = 0; jj < 8; ++jj) {
        float4 v = *(const float4*)(src + jj * 4);
        unsigned short h0 = f2b(v.x); dh[jj * 4 + 0] = h0; dl[jj * 4 + 0] = f2b(v.x - b2f(h0));
        unsigned short h1 = f2b(v.y); dh[jj * 4 + 1] = h1; dl[jj * 4 + 1] = f2b(v.y - b2f(h1));
        unsigned short h2 = f2b(v.z); dh[jj * 4 + 2] = h2; dl[jj * 4 + 2] = f2b(v.z - b2f(h2));
        unsigned short h3 = f2b(v.w); dh[jj * 4 + 3] = h3; dl[jj * 4 + 3] = f2b(v.w - b2f(h3));
      }
    }
    __syncthreads();
    // ---- U-GEMM: chunk finals (keep in registers) ----
    f32x4 uacc[8];
#pragma unroll
    for (int ct = 0; ct < 8; ++ct) uacc[ct] = (f32x4){0.f, 0.f, 0.f, 0.f};
#pragma unroll
    for (int kk = 0; kk < 2; ++kk) {
      bf16x8 ah = *(const bf16x8*)&Uh[(rt << 4) + lrow][(kk << 5) + lk8];
      bf16x8 al = *(const bf16x8*)&Ul[(rt << 4) + lrow][(kk << 5) + lk8];
#pragma unroll
      for (int ct = 0; ct < 8; ++ct) {
        int col = ((ct0 + ct) << 4) + lrow;
        bf16x8 bh = *(const bf16x8*)&xbh[col][(kk << 5) + lk8];
        bf16x8 bl = *(const bf16x8*)&xbl[col][(kk << 5) + lk8];
        uacc[ct] = __builtin_amdgcn_mfma_f32_16x16x32_bf16(ah, bh, uacc[ct], 0, 0, 0);
        uacc[ct] = __builtin_amdgcn_mfma_f32_16x16x32_bf16(ah, bl, uacc[ct], 0, 0, 0);
        uacc[ct] = __builtin_amdgcn_mfma_f32_16x16x32_bf16(al, bh, uacc[ct], 0, 0, 0);
      }
    }
    // ---- T-GEMM (x still staged) ----
    f32x4 acc[8];
#pragma unroll
    for (int ct = 0; ct < 8; ++ct) acc[ct] = (f32x4){0.f, 0.f, 0.f, 0.f};
#pragma unroll
    for (int kk = 0; kk < 2; ++kk) {
      bf16x8 ah = *(const bf16x8*)&Th[(rt << 4) + lrow][(kk << 5) + lk8];
      bf16x8 al = *(const bf16x8*)&Tl[(rt << 4) + lrow][(kk << 5) + lk8];
#pragma unroll
      for (int ct = 0; ct < 8; ++ct) {
        int col = ((ct0 + ct) << 4) + lrow;
        bf16x8 bh = *(const bf16x8*)&xbh[col][(kk << 5) + lk8];
        bf16x8 bl = *(const bf16x8*)&xbl[col][(kk << 5) + lk8];
        acc[ct] = __builtin_amdgcn_mfma_f32_16x16x32_bf16(ah, bh, acc[ct], 0, 0, 0);
        acc[ct] = __builtin_amdgcn_mfma_f32_16x16x32_bf16(ah, bl, acc[ct], 0, 0, 0);
        acc[ct] = __builtin_amdgcn_mfma_f32_16x16x32_bf16(al, bh, acc[ct], 0, 0, 0);
      }
    }
    // ---- add D-skip term while x is still staged (x = hi + lo, ~exact) ----
    {
#pragma unroll
      for (int ct = 0; ct < 8; ++ct) {
        int col = ((ct0 + ct) << 4) + lrow;
        int row = (rt << 4) + rsub;
        ushort4 xh4 = *(const ushort4*)&xbh[col][row];
        ushort4 xl4 = *(const ushort4*)&xbl[col][row];
        acc[ct][0] = fmaf(Dh, b2f(xh4.x) + b2f(xl4.x), acc[ct][0]);
        acc[ct][1] = fmaf(Dh, b2f(xh4.y) + b2f(xl4.y), acc[ct][1]);
        acc[ct][2] = fmaf(Dh, b2f(xh4.z) + b2f(xl4.z), acc[ct][2]);
        acc[ct][3] = fmaf(Dh, b2f(xh4.w) + b2f(xl4.w), acc[ct][3]);
      }
    }
    __syncthreads();  // all x reads done; xbh/xbl reusable
    // ---- write finals (hi/lo bf16) into xbh/xbl in svec layout [col][2n] ----
    {
      int n0 = (rt << 3) + ((lane >> 4) << 1);
#pragma unroll
      for (int ct = 0; ct < 8; ++ct) {
        int colh = ((ct0 + ct) << 4) + lrow;
        ushort4 oh, ol;
        oh.x = f2b(uacc[ct][0]); ol.x = f2b(uacc[ct][0] - b2f(oh.x));
        oh.y = f2b(uacc[ct][1]); ol.y = f2b(uacc[ct][1] - b2f(oh.y));
        oh.z = f2b(uacc[ct][2]); ol.z = f2b(uacc[ct][2] - b2f(oh.z));
        oh.w = f2b(uacc[ct][3]); ol.w = f2b(uacc[ct][3] - b2f(oh.w));
        *(ushort4*)&xbh[colh][2 * n0] = oh;
        *(ushort4*)&xbl[colh][2 * n0] = ol;
      }
    }
    __syncthreads();
    // ---- exclusive prefix in LDS: thread=(b,n); in-place finals -> carries ----
    if (tid < 256) {
      int bb = tid >> 5, n = tid & 31;
      const float* pb = par + (size_t)(h * NH + n) * 8;
      float lTr = pb[4], lTi = pb[5];
      float cr = 0.f, ci = 0.f;
      for (int c = 0; c < NTC; ++c) {
        int col = (bb << 5) + c;
        float fr = b2f(xbh[col][2 * n]) + b2f(xbl[col][2 * n]);
        float fi = b2f(xbh[col][2 * n + 1]) + b2f(xbl[col][2 * n + 1]);
        unsigned short hr = f2b(cr);
        xbh[col][2 * n] = hr; xbl[col][2 * n] = f2b(cr - b2f(hr));
        unsigned short hm = f2b(ci);
        xbh[col][2 * n + 1] = hm; xbl[col][2 * n + 1] = f2b(ci - b2f(hm));
        float nr = fmaf(lTr, cr, fr); nr = fmaf(-lTi, ci, nr);
        float ni = fmaf(lTr, ci, fi); ni = fmaf(lTi, cr, ni);
        cr = nr; ci = ni;
      }
    }
    __syncthreads();
    // ---- W-GEMM (carry contribution), accumulate; gelu; write y bf16 ----
#pragma unroll
    for (int kk = 0; kk < 2; ++kk) {
      bf16x8 ah = *(const bf16x8*)&Wh[(rt << 4) + lrow][(kk << 5) + lk8];
      bf16x8 al = *(const bf16x8*)&Wl[(rt << 4) + lrow][(kk << 5) + lk8];
#pragma unroll
      for (int ct = 0; ct < 8; ++ct) {
        int col = ((ct0 + ct) << 4) + lrow;
        bf16x8 bh = *(const bf16x8*)&xbh[col][(kk << 5) + lk8];
        bf16x8 bl = *(const bf16x8*)&xbl[col][(kk << 5) + lk8];
        acc[ct] = __builtin_amdgcn_mfma_f32_16x16x32_bf16(ah, bh, acc[ct], 0, 0, 0);
        acc[ct] = __builtin_amdgcn_mfma_f32_16x16x32_bf16(ah, bl, acc[ct], 0, 0, 0);
        acc[ct] = __builtin_amdgcn_mfma_f32_16x16x32_bf16(al, bh, acc[ct], 0, 0, 0);
      }
    }
#pragma unroll
    for (int ct = 0; ct < 8; ++ct) {
      int colg = (half << 8) + ((ct0 + ct) << 4) + lrow;
      ushort4 o;
      o.x = f2b(gelu_exact(acc[ct][0]));
      o.y = f2b(gelu_exact(acc[ct][1]));
      o.z = f2b(gelu_exact(acc[ct][2]));
      o.w = f2b(gelu_exact(acc[ct][3]));
      *(ushort4*)(yloc + (size_t)h * (B_SZ * L_SZ) + (size_t)colg * 64 + (rt << 4) + rsub) = o;
    }
  }
}

// ---------------- post: yt copy + GLU + LN (yt XOR-swizzled) ----------------
__launch_bounds__(1024, 4)
__global__ void k_layer2(float* __restrict__ hbuf, const unsigned short* __restrict__ yloc,
                         const unsigned short* __restrict__ wbf,
                         const float* __restrict__ b_out,
                         const float* __restrict__ ln_g, const float* __restrict__ ln_b,
                         float* __restrict__ pooledPart, int last) {
  __shared__ __align__(16) unsigned short yt[TC * YROW];
  __shared__ float part[TC][16][2];
  __shared__ float stats[TC][2];
  int tid = threadIdx.x;
  int b = blockIdx.x >> 5;
  int c = blockIdx.x & 31;
  int l0 = c << 6;

  // ---- fill: yloc (already gelu'd) -> yt transpose copy ----
  {
    int h = tid >> 2, q = tid & 3;
    const unsigned short* yp2 = yloc + (size_t)h * (B_SZ * L_SZ) + b * L_SZ + l0 + (q << 4);
#pragma unroll
    for (int jj = 0; jj < 16; jj += 4) {
      ushort4 yv = *(const ushort4*)(yp2 + jj);
      int jb = (q << 4) + jj;
      yt[yswz(jb + 0, h)] = yv.x;
      yt[yswz(jb + 1, h)] = yv.y;
      yt[yswz(jb + 2, h)] = yv.z;
      yt[yswz(jb + 3, h)] = yv.w;
    }
  }
  __syncthreads();
  // ---- GLU: 1x1 conv via MFMA; z -> yt ----
  {
    int w = tid >> 6, lane = tid & 63;
    int lrow = lane & 15, lk8 = (lane >> 4) << 3;
    f32x4 accA[4], accG[4];
    f32x4 zed = {0.f, 0.f, 0.f, 0.f};
#pragma unroll
    for (int jt = 0; jt < 4; ++jt) { accA[jt] = zed; accG[jt] = zed; }
    const unsigned short* wA = wbf + ((w << 4) + lrow) * H_SZ;
    const unsigned short* wG = wA + 256 * H_SZ;
#pragma unroll
    for (int k0 = 0; k0 < H_SZ; k0 += 32) {
      bf16x8 a0 = *(const bf16x8*)(wA + k0 + lk8);
      bf16x8 a1 = *(const bf16x8*)(wG + k0 + lk8);
#pragma unroll
      for (int jt = 0; jt < 4; ++jt) {
        bf16x8 bb = *(const bf16x8*)&yt[yswz((jt << 4) + lrow, k0 + lk8)];
        accA[jt] = __builtin_amdgcn_mfma_f32_16x16x32_bf16(a0, bb, accA[jt], 0, 0, 0);
        accG[jt] = __builtin_amdgcn_mfma_f32_16x16x32_bf16(a1, bb, accG[jt], 0, 0, 0);
      }
    }
    __syncthreads();  // all y reads done before overwrite with z
    int rbase = (lane >> 4) << 2;
    float bA[4], bG[4];
#pragma unroll
    for (int r = 0; r < 4; ++r) {
      bA[r] = b_out[(w << 4) + rbase + r];
      bG[r] = b_out[256 + (w << 4) + rbase + r];
    }
#pragma unroll
    for (int jt = 0; jt < 4; ++jt) {
      ushort4 o;
      float a0 = accA[jt][0] + bA[0], g0 = accG[jt][0] + bG[0];
      float a1 = accA[jt][1] + bA[1], g1 = accG[jt][1] + bG[1];
      float a2 = accA[jt][2] + bA[2], g2 = accG[jt][2] + bG[2];
      float a3 = accA[jt][3] + bA[3], g3 = accG[jt][3] + bG[3];
      o.x = f2b(a0 / (1.f + expf(-g0)));
      o.y = f2b(a1 / (1.f + expf(-g1)));
      o.z = f2b(a2 / (1.f + expf(-g2)));
      o.w = f2b(a3 / (1.f + expf(-g3)));
      *(ushort4*)&yt[yswz((jt << 4) + lrow, (w << 4) + rbase)] = o;
    }
  }
  __syncthreads();
  // ---- LN stats; v = z + residual ----
  int j = tid & 63, hg = tid >> 6;
  float vreg[16];
  {
    const float* xc = hbuf + (b * H_SZ + (hg << 4)) * L_SZ + l0 + j;
    float s = 0.f, sq = 0.f;
    ushort4 za = *(const ushort4*)&yt[yswz(j, (hg << 4) + 0)];
    ushort4 zb = *(const ushort4*)&yt[yswz(j, (hg << 4) + 4)];
    ushort4 zc = *(const ushort4*)&yt[yswz(j, (hg << 4) + 8)];
    ushort4 zd = *(const ushort4*)&yt[yswz(j, (hg << 4) + 12)];
    unsigned short zz[16] = {za.x, za.y, za.z, za.w, zb.x, zb.y, zb.z, zb.w,
                             zc.x, zc.y, zc.z, zc.w, zd.x, zd.y, zd.z, zd.w};
#pragma unroll
    for (int k = 0; k < 16; ++k) {
      float v = b2f(zz[k]) + xc[(size_t)k * L_SZ];
      vreg[k] = v;
      s += v; sq = fmaf(v, v, sq);
    }
    part[j][hg][0] = s; part[j][hg][1] = sq;
  }
  __syncthreads();
  if (tid < TC) {
    float s = 0.f, sq = 0.f;
#pragma unroll
    for (int g = 0; g < 16; ++g) { s += part[tid][g][0]; sq += part[tid][g][1]; }
    float mu = s * (1.f / 256.f);
    float var = sq * (1.f / 256.f) - mu * mu;
    stats[tid][0] = mu;
    stats[tid][1] = rsqrtf(var + 1e-5f);
  }
  __syncthreads();
  {
    float mu = stats[j][0], rs = stats[j][1];
    if (!last) {
      float* xo = hbuf + (b * H_SZ + (hg << 4)) * L_SZ + l0 + j;
#pragma unroll
      for (int k = 0; k < 16; ++k) {
        int hh = (hg << 4) + k;
        xo[(size_t)k * L_SZ] = (vreg[k] - mu) * rs * ln_g[hh] + ln_b[hh];
      }
    } else {
#pragma unroll
      for (int k = 0; k < 16; ++k) {
        int hh = (hg << 4) + k;
        yt[yswz(j, hh)] = f2b((vreg[k] - mu) * rs * ln_g[hh] + ln_b[hh]);
      }
      __syncthreads();
      if (tid < H_SZ) {
        float s = 0.f;
        for (int jj = 0; jj < TC; ++jj) s += b2f(yt[yswz(jj, tid)]);
        pooledPart[(((b << 5) + c) << 8) + tid] = s;
      }
    }
  }
}

// ---------------- pool: reduce 32 chunk-partials per (b,h) ----------------
__global__ void k_pool(const float* __restrict__ pooledPart, float* __restrict__ P) {
  int b = blockIdx.x, hh = threadIdx.x;
  float s = 0.f;
#pragma unroll
  for (int cpart = 0; cpart < 32; ++cpart)
    s += pooledPart[(((b << 5) + cpart) << 8) + hh];
  P[(b << 8) + hh] = s * (1.f / 2048.f);
}

// ---------------- decoder MLP: one block per batch row ----------------
__global__ void k_dec(const float* __restrict__ P,
                      const float* __restrict__ w1, const float* __restrict__ b1,
                      const float* __restrict__ w2, const float* __restrict__ b2,
                      const float* __restrict__ w3, const float* __restrict__ b3,
                      float* __restrict__ out) {
  __shared__ float Pr[256];
  __shared__ float O1[128];
  __shared__ float O2[64];
  int b = blockIdx.x, tid = threadIdx.x;
  Pr[tid] = P[(b << 8) + tid];
  __syncthreads();
  if (tid < 128) {
    float acc = b1[tid];
    for (int d = 0; d < 256; ++d) acc = fmaf(Pr[d], w1[(d << 7) + tid], acc);
    O1[tid] = fmaxf(acc, 0.f);
  }
  __syncthreads();
  if (tid < 64) {
    float acc = b2[tid];
    for (int d = 0; d < 128; ++d) acc = fmaf(O1[d], w2[(d << 6) + tid], acc);
    O2[tid] = fmaxf(acc, 0.f);
  }
  __syncthreads();
  if (tid < 32) {
    float acc = b3[tid];
    for (int d = 0; d < 64; ++d) acc = fmaf(O2[d], w3[(d << 5) + tid], acc);
    out[(b << 5) + tid] = acc;
  }
}

extern "C" void kernel_launch(void* const* d_in, const int* in_sizes, int n_in,
                              void* d_out, int out_size, void* d_ws, size_t ws_size,
                              hipStream_t stream) {
  const float* x          = (const float*)d_in[0];
  const float* enc_w      = (const float*)d_in[1];
  const float* enc_b      = (const float*)d_in[2];
  const float* log_dt     = (const float*)d_in[3];
  const float* C_re       = (const float*)d_in[4];
  const float* C_im       = (const float*)d_in[5];
  const float* log_A_real = (const float*)d_in[6];
  const float* A_imag     = (const float*)d_in[7];
  const float* D_skip     = (const float*)d_in[8];
  const float* w_out      = (const float*)d_in[9];
  const float* b_out      = (const float*)d_in[10];
  const float* ln_g       = (const float*)d_in[11];
  const float* ln_b       = (const float*)d_in[12];
  const float* dw1        = (const float*)d_in[13];
  const float* db1        = (const float*)d_in[14];
  const float* dw2        = (const float*)d_in[15];
  const float* db2        = (const float*)d_in[16];
  const float* dw3        = (const float*)d_in[17];
  const float* db3        = (const float*)d_in[18];

  char* ws = (char*)d_ws;
  float* hbuf = (float*)ws;                                  // 33,554,432 B
  unsigned short* yloc = (unsigned short*)(ws + 33554432);   // 16,777,216 B (bf16)
  unsigned short* wbf = (unsigned short*)(ws + 50331648);    //  1,048,576 B
  float* par = (float*)(ws + 51380224);                      //  1,048,576 B
  float* pooledPart = (float*)(ws + 52428800);               //    524,288 B
  float* P = (float*)(ws + 52953088);                        //     16,384 B

  k_encoder<<<512, 512, 0, stream>>>(x, enc_w, enc_b, hbuf);
  k_cvtw<<<2048, 256, 0, stream>>>(w_out, wbf, NL * 512 * H_SZ);
  k_params<<<128, 256, 0, stream>>>(log_dt, log_A_real, A_imag, C_re, C_im, par);
  const size_t PAR_STRIDE = (size_t)H_SZ * NH * 8;
  for (int i = 0; i < NL; ++i) {
    const float* pari = par + i * PAR_STRIDE;
    k_ssm<<<256, 512, 0, stream>>>(hbuf, pari, D_skip + i * H_SZ, yloc);
    k_layer2<<<512, 1024, 0, stream>>>(hbuf, yloc,
                                       wbf + i * 512 * H_SZ, b_out + i * 512,
                                       ln_g + i * H_SZ, ln_b + i * H_SZ,
                                       pooledPart, (i == NL - 1) ? 1 : 0);
  }
  k_pool<<<16, 256, 0, stream>>>(pooledPart, P);
  k_dec<<<16, 256, 0, stream>>>(P, dw1, db1, dw2, db2, dw3, db3, (float*)d_out);
}

// Round 16
// 307.954 us; speedup vs baseline: 3.3992x; 1.0429x over previous
//
#include <hip/hip_runtime.h>

#define B_SZ 16
#define L_SZ 2048
#define DIN 64
#define H_SZ 256
#define NH 32
#define NL 4
#define TC 64
#define NTC 32
#define YROW (H_SZ + 8)

typedef __attribute__((ext_vector_type(8))) __bf16 bf16x8;
typedef __attribute__((ext_vector_type(4))) float f32x4;

__device__ __forceinline__ unsigned short f2b(float f) {
  unsigned int u = __builtin_bit_cast(unsigned int, f);
  unsigned int r = u + 0x7fffu + ((u >> 16) & 1u);  // RNE (no NaN inputs here)
  return (unsigned short)(r >> 16);
}
__device__ __forceinline__ float b2f(unsigned short u) {
  unsigned int v = ((unsigned int)u) << 16;
  return __builtin_bit_cast(float, v);
}
__device__ __forceinline__ float gelu_exact(float v) {
  return 0.5f * v * (1.f + erff(v * 0.70710678118654752f));
}
// 16B-granule XOR swizzle for yt
__device__ __forceinline__ int yswz(int row, int col) {
  return (row * YROW + col) ^ (((row >> 3) & 7) << 3);
}

// ---------------- encoder as compensated MFMA GEMM ----------------
__launch_bounds__(512, 4)
__global__ void k_encoder(const float* __restrict__ x, const float* __restrict__ w,
                          const float* __restrict__ bias, float* __restrict__ hbuf) {
  __shared__ __align__(16) unsigned short Wh[128][72];
  __shared__ __align__(16) unsigned short Wl[128][72];
  __shared__ __align__(16) unsigned short xh[128][72];
  __shared__ __align__(16) unsigned short xl[128][72];
  int tid = threadIdx.x;
  int blk = blockIdx.x;           // b(4b) lt(4b) hh(1b)
  int b = blk >> 5;
  int lt = (blk >> 1) & 15;
  int hh = blk & 1;

#pragma unroll
  for (int i = 0; i < 16; ++i) {
    int flat = i * 512 + tid;
    int d = flat >> 7, hl = flat & 127;
    float v = w[d * H_SZ + (hh << 7) + hl];
    unsigned short hv = f2b(v);
    Wh[hl][d] = hv; Wl[hl][d] = f2b(v - b2f(hv));
  }
  {
    int l = tid >> 2, d0 = (tid & 3) << 4;
    const float* src = x + ((size_t)(b * L_SZ + (lt << 7) + l) << 6) + d0;
    unsigned short* dh = &xh[l][d0];
    unsigned short* dl = &xl[l][d0];
#pragma unroll
    for (int jj = 0; jj < 4; ++jj) {
      float4 v = *(const float4*)(src + jj * 4);
      unsigned short h0 = f2b(v.x); dh[jj * 4 + 0] = h0; dl[jj * 4 + 0] = f2b(v.x - b2f(h0));
      unsigned short h1 = f2b(v.y); dh[jj * 4 + 1] = h1; dl[jj * 4 + 1] = f2b(v.y - b2f(h1));
      unsigned short h2 = f2b(v.z); dh[jj * 4 + 2] = h2; dl[jj * 4 + 2] = f2b(v.z - b2f(h2));
      unsigned short h3 = f2b(v.w); dh[jj * 4 + 3] = h3; dl[jj * 4 + 3] = f2b(v.w - b2f(h3));
    }
  }
  __syncthreads();

  int wv = tid >> 6, lane = tid & 63;
  int lrow = lane & 15, lk8 = (lane >> 4) << 3;
  int rsub = (lane >> 4) << 2;
  f32x4 acc[8];
#pragma unroll
  for (int ct = 0; ct < 8; ++ct) acc[ct] = (f32x4){0.f, 0.f, 0.f, 0.f};
#pragma unroll
  for (int kk = 0; kk < 2; ++kk) {
    bf16x8 ah = *(const bf16x8*)&Wh[(wv << 4) + lrow][(kk << 5) + lk8];
    bf16x8 al = *(const bf16x8*)&Wl[(wv << 4) + lrow][(kk << 5) + lk8];
#pragma unroll
    for (int ct = 0; ct < 8; ++ct) {
      bf16x8 bh = *(const bf16x8*)&xh[(ct << 4) + lrow][(kk << 5) + lk8];
      bf16x8 bl = *(const bf16x8*)&xl[(ct << 4) + lrow][(kk << 5) + lk8];
      acc[ct] = __builtin_amdgcn_mfma_f32_16x16x32_bf16(ah, bh, acc[ct], 0, 0, 0);
      acc[ct] = __builtin_amdgcn_mfma_f32_16x16x32_bf16(ah, bl, acc[ct], 0, 0, 0);
      acc[ct] = __builtin_amdgcn_mfma_f32_16x16x32_bf16(al, bh, acc[ct], 0, 0, 0);
    }
  }
  float bi[4];
#pragma unroll
  for (int r = 0; r < 4; ++r) bi[r] = bias[(hh << 7) + (wv << 4) + rsub + r];
#pragma unroll
  for (int ct = 0; ct < 8; ++ct) {
    int lglob = (lt << 7) + (ct << 4) + lrow;
#pragma unroll
    for (int r = 0; r < 4; ++r) {
      int hglob = (hh << 7) + (wv << 4) + rsub + r;
      hbuf[((size_t)(b * H_SZ + hglob) << 11) + lglob] = acc[ct][r] + bi[r];
    }
  }
}

// ---------------- convert w_out to bf16 ----------------
__global__ void k_cvtw(const float* __restrict__ w, unsigned short* __restrict__ wbf, int n) {
  int i = blockIdx.x * 256 + threadIdx.x;
  if (i < n) wbf[i] = f2b(w[i]);
}

// ---------------- precompute per-state params: lr, li, c2r, c2i, lTr, lTi ----------------
__global__ void k_params(const float* __restrict__ log_dt, const float* __restrict__ log_A_real,
                         const float* __restrict__ A_imag, const float* __restrict__ C_re,
                         const float* __restrict__ C_im, float* __restrict__ par) {
  int id = blockIdx.x * 256 + threadIdx.x;  // i*8192 + h*32 + n
  if (id >= NL * H_SZ * NH) return;
  int i = id >> 13;
  int hn = id & 8191;
  int h = hn >> 5;
  float dt = expf(log_dt[i * H_SZ + h]);
  float Ar = -expf(log_A_real[(size_t)i * H_SZ * NH + hn]);
  float Ai = A_imag[(size_t)i * H_SZ * NH + hn];
  float dr = dt * Ar, di = dt * Ai;
  float e = expf(dr), sn, cs;
  sincosf(di, &sn, &cs);
  float lr = e * cs, li = e * sn;
  float eT = expf((float)TC * dr), snT, csT;
  sincosf((float)TC * di, &snT, &csT);
  float Cr = C_re[(size_t)i * H_SZ * NH + hn], Ci = C_im[(size_t)i * H_SZ * NH + hn];
  float wr = lr - 1.f, wi = li;
  float pr = Cr * wr - Ci * wi;
  float pi = Cr * wi + Ci * wr;
  float inv = 2.f / fmaf(Ar, Ar, Ai * Ai);
  float4* p = (float4*)(par + (size_t)id * 8);
  p[0] = make_float4(lr, li, (pr * Ar + pi * Ai) * inv, (pi * Ar - pr * Ai) * inv);
  p[1] = make_float4(eT * csT, eT * snT, 0.f, 0.f);
}

// ---------------- merged SSM kernel (1024 thr, 16 waves): finals+prefix in LDS+conv+GELU ----
__launch_bounds__(1024, 4)
__global__ void k_ssm(const float* __restrict__ hbuf, const float* __restrict__ par,
                      const float* __restrict__ D_skip, unsigned short* __restrict__ yloc) {
  __shared__ __align__(16) unsigned short xbh[256][72];
  __shared__ __align__(16) unsigned short xbl[256][72];
  __shared__ __align__(16) unsigned short Uh[64][72];
  __shared__ __align__(16) unsigned short Ul[64][72];
  __shared__ __align__(16) unsigned short Th[64][72];
  __shared__ __align__(16) unsigned short Tl[64][72];
  __shared__ __align__(16) unsigned short Wh[64][72];
  __shared__ __align__(16) unsigned short Wl[64][72];
  __shared__ float Kc[64];
  int tid = threadIdx.x;
  int h = blockIdx.x;
  float* Wm = (float*)&xbh[0][0];  // [64][66] f32 scratch, dead before x staging

  if (tid < 64) {
    int n = tid >> 1, q = tid & 1;
    const float* pb = par + (size_t)(h * NH + n) * 8;
    float lr = pb[0], li = pb[1], c2r = pb[2], c2i = pb[3];
    float pr = lr, pi = li;  // lam^1
    if (q) {                 // lam^33
      float sr = lr, si = li;
#pragma unroll
      for (int t = 0; t < 5; ++t) { float nr2 = sr * sr - si * si; si = 2.f * sr * si; sr = nr2; }
      pr = sr * lr - si * li; pi = sr * li + si * lr;
    }
    int p = q << 5;
    for (int s = 0; s < 32; ++s, ++p) {
      Wm[p * 66 + 2 * n] = c2r * pr - c2i * pi;
      Wm[p * 66 + 2 * n + 1] = -(c2r * pi + c2i * pr);
      float nr2 = pr * lr - pi * li;
      pi = pr * li + pi * lr;
      pr = nr2;
    }
  }
  __syncthreads();
  if (tid < 64) {
    float kv = 0.f;
    if (tid == 0) {
      for (int n = 0; n < 32; ++n) kv += par[(size_t)(h * NH + n) * 8 + 2];
    } else {
      for (int n = 0; n < 32; ++n) kv += Wm[(tid - 1) * 66 + 2 * n];
    }
    Kc[tid] = kv;
  }
  {
    int base = tid * 4;          // 1024 thr x 4 = 4096 = 64x64
    int row = base >> 6, col0 = base & 63;
#pragma unroll
    for (int e = 0; e < 4; ++e) {
      float v = Wm[row * 66 + col0 + e];
      unsigned short hv = f2b(v);
      Wh[row][col0 + e] = hv; Wl[row][col0 + e] = f2b(v - b2f(hv));
    }
  }
  __syncthreads();
  {
    int base = tid * 4;
    int row = base >> 6, col0 = base & 63;
#pragma unroll
    for (int e = 0; e < 4; ++e) {
      int col = col0 + e;
      float v = (col <= row) ? Kc[row - col] : 0.f;
      unsigned short hv = f2b(v);
      Th[row][col] = hv; Tl[row][col] = f2b(v - b2f(hv));
    }
  }
  if (tid < 64) {
    int n = tid >> 1, q = tid & 1;
    const float* pb = par + (size_t)(h * NH + n) * 8;
    float lr = pb[0], li = pb[1];
    float pr = 1.f, pi = 0.f;
    if (q) {
      float sr = lr, si = li;
#pragma unroll
      for (int t = 0; t < 5; ++t) { float nr2 = sr * sr - si * si; si = 2.f * sr * si; sr = nr2; }
      pr = sr; pi = si;
    }
    int p = q << 5;
    for (int s = 0; s < 32; ++s, ++p) {
      int col = 63 - p;
      unsigned short hr = f2b(pr);
      Uh[2 * n][col] = hr; Ul[2 * n][col] = f2b(pr - b2f(hr));
      unsigned short hm = f2b(pi);
      Uh[2 * n + 1][col] = hm; Ul[2 * n + 1][col] = f2b(pi - b2f(hm));
      float nr2 = pr * lr - pi * li;
      pi = pr * li + pi * lr;
      pr = nr2;
    }
  }

  int wv = tid >> 6, lane = tid & 63;
  int lrow = lane & 15, lk8 = (lane >> 4) << 3;
  int rt = wv >> 2;                // row-tile 0..3
  int cg = wv & 3;                 // col-group 0..3 (4 col-tiles each)
  int rsub = (lane >> 4) << 2;
  float Dh = D_skip[h];

  for (int half = 0; half < 2; ++half) {
    __syncthreads();  // matrices ready / previous half's svec reads done
    // ---- stage x hi/lo (1024 thr: 16 elems each) ----
    {
      int colh = tid >> 2, j0 = (tid & 3) << 4;
      int b = (half << 3) + (colh >> 5), c = colh & 31;
      const float* src = hbuf + ((size_t)(b * H_SZ + h) << 11) + (c << 6) + j0;
      unsigned short* dh = &xbh[colh][j0];
      unsigned short* dl = &xbl[colh][j0];
#pragma unroll
      for (int jj = 0; jj < 4; ++jj) {
        float4 v = *(const float4*)(src + jj * 4);
        unsigned short h0 = f2b(v.x); dh[jj * 4 + 0] = h0; dl[jj * 4 + 0] = f2b(v.x - b2f(h0));
        unsigned short h1 = f2b(v.y); dh[jj * 4 + 1] = h1; dl[jj * 4 + 1] = f2b(v.y - b2f(h1));
        unsigned short h2 = f2b(v.z); dh[jj * 4 + 2] = h2; dl[jj * 4 + 2] = f2b(v.z - b2f(h2));
        unsigned short h3 = f2b(v.w); dh[jj * 4 + 3] = h3; dl[jj * 4 + 3] = f2b(v.w - b2f(h3));
      }
    }
    __syncthreads();
    // ---- U-GEMM: chunk finals (keep in registers) ----
    f32x4 uacc[4];
#pragma unroll
    for (int ct = 0; ct < 4; ++ct) uacc[ct] = (f32x4){0.f, 0.f, 0.f, 0.f};
#pragma unroll
    for (int kk = 0; kk < 2; ++kk) {
      bf16x8 ah = *(const bf16x8*)&Uh[(rt << 4) + lrow][(kk << 5) + lk8];
      bf16x8 al = *(const bf16x8*)&Ul[(rt << 4) + lrow][(kk << 5) + lk8];
#pragma unroll
      for (int ct = 0; ct < 4; ++ct) {
        int col = (((cg << 2) + ct) << 4) + lrow;
        bf16x8 bh = *(const bf16x8*)&xbh[col][(kk << 5) + lk8];
        bf16x8 bl = *(const bf16x8*)&xbl[col][(kk << 5) + lk8];
        uacc[ct] = __builtin_amdgcn_mfma_f32_16x16x32_bf16(ah, bh, uacc[ct], 0, 0, 0);
        uacc[ct] = __builtin_amdgcn_mfma_f32_16x16x32_bf16(ah, bl, uacc[ct], 0, 0, 0);
        uacc[ct] = __builtin_amdgcn_mfma_f32_16x16x32_bf16(al, bh, uacc[ct], 0, 0, 0);
      }
    }
    // ---- T-GEMM (x still staged) ----
    f32x4 acc[4];
#pragma unroll
    for (int ct = 0; ct < 4; ++ct) acc[ct] = (f32x4){0.f, 0.f, 0.f, 0.f};
#pragma unroll
    for (int kk = 0; kk < 2; ++kk) {
      bf16x8 ah = *(const bf16x8*)&Th[(rt << 4) + lrow][(kk << 5) + lk8];
      bf16x8 al = *(const bf16x8*)&Tl[(rt << 4) + lrow][(kk << 5) + lk8];
#pragma unroll
      for (int ct = 0; ct < 4; ++ct) {
        int col = (((cg << 2) + ct) << 4) + lrow;
        bf16x8 bh = *(const bf16x8*)&xbh[col][(kk << 5) + lk8];
        bf16x8 bl = *(const bf16x8*)&xbl[col][(kk << 5) + lk8];
        acc[ct] = __builtin_amdgcn_mfma_f32_16x16x32_bf16(ah, bh, acc[ct], 0, 0, 0);
        acc[ct] = __builtin_amdgcn_mfma_f32_16x16x32_bf16(ah, bl, acc[ct], 0, 0, 0);
        acc[ct] = __builtin_amdgcn_mfma_f32_16x16x32_bf16(al, bh, acc[ct], 0, 0, 0);
      }
    }
    // ---- add D-skip term while x is still staged (x = hi + lo, ~exact) ----
    {
#pragma unroll
      for (int ct = 0; ct < 4; ++ct) {
        int col = (((cg << 2) + ct) << 4) + lrow;
        int row = (rt << 4) + rsub;
        ushort4 xh4 = *(const ushort4*)&xbh[col][row];
        ushort4 xl4 = *(const ushort4*)&xbl[col][row];
        acc[ct][0] = fmaf(Dh, b2f(xh4.x) + b2f(xl4.x), acc[ct][0]);
        acc[ct][1] = fmaf(Dh, b2f(xh4.y) + b2f(xl4.y), acc[ct][1]);
        acc[ct][2] = fmaf(Dh, b2f(xh4.z) + b2f(xl4.z), acc[ct][2]);
        acc[ct][3] = fmaf(Dh, b2f(xh4.w) + b2f(xl4.w), acc[ct][3]);
      }
    }
    __syncthreads();  // all x reads done; xbh/xbl reusable
    // ---- write finals (hi/lo bf16) into xbh/xbl in svec layout [col][2n] ----
    {
      int n0 = (rt << 3) + ((lane >> 4) << 1);
#pragma unroll
      for (int ct = 0; ct < 4; ++ct) {
        int colh = (((cg << 2) + ct) << 4) + lrow;
        ushort4 oh, ol;
        oh.x = f2b(uacc[ct][0]); ol.x = f2b(uacc[ct][0] - b2f(oh.x));
        oh.y = f2b(uacc[ct][1]); ol.y = f2b(uacc[ct][1] - b2f(oh.y));
        oh.z = f2b(uacc[ct][2]); ol.z = f2b(uacc[ct][2] - b2f(oh.z));
        oh.w = f2b(uacc[ct][3]); ol.w = f2b(uacc[ct][3] - b2f(oh.w));
        *(ushort4*)&xbh[colh][2 * n0] = oh;
        *(ushort4*)&xbl[colh][2 * n0] = ol;
      }
    }
    __syncthreads();
    // ---- exclusive prefix in LDS: thread=(b,n); in-place finals -> carries ----
    if (tid < 256) {
      int bb = tid >> 5, n = tid & 31;
      const float* pb = par + (size_t)(h * NH + n) * 8;
      float lTr = pb[4], lTi = pb[5];
      float cr = 0.f, ci = 0.f;
      for (int c = 0; c < NTC; ++c) {
        int col = (bb << 5) + c;
        float fr = b2f(xbh[col][2 * n]) + b2f(xbl[col][2 * n]);
        float fi = b2f(xbh[col][2 * n + 1]) + b2f(xbl[col][2 * n + 1]);
        unsigned short hr = f2b(cr);
        xbh[col][2 * n] = hr; xbl[col][2 * n] = f2b(cr - b2f(hr));
        unsigned short hm = f2b(ci);
        xbh[col][2 * n + 1] = hm; xbl[col][2 * n + 1] = f2b(ci - b2f(hm));
        float nr = fmaf(lTr, cr, fr); nr = fmaf(-lTi, ci, nr);
        float ni = fmaf(lTr, ci, fi); ni = fmaf(lTi, cr, ni);
        cr = nr; ci = ni;
      }
    }
    __syncthreads();
    // ---- W-GEMM (carry contribution), accumulate; gelu; write y bf16 ----
#pragma unroll
    for (int kk = 0; kk < 2; ++kk) {
      bf16x8 ah = *(const bf16x8*)&Wh[(rt << 4) + lrow][(kk << 5) + lk8];
      bf16x8 al = *(const bf16x8*)&Wl[(rt << 4) + lrow][(kk << 5) + lk8];
#pragma unroll
      for (int ct = 0; ct < 4; ++ct) {
        int col = (((cg << 2) + ct) << 4) + lrow;
        bf16x8 bh = *(const bf16x8*)&xbh[col][(kk << 5) + lk8];
        bf16x8 bl = *(const bf16x8*)&xbl[col][(kk << 5) + lk8];
        acc[ct] = __builtin_amdgcn_mfma_f32_16x16x32_bf16(ah, bh, acc[ct], 0, 0, 0);
        acc[ct] = __builtin_amdgcn_mfma_f32_16x16x32_bf16(ah, bl, acc[ct], 0, 0, 0);
        acc[ct] = __builtin_amdgcn_mfma_f32_16x16x32_bf16(al, bh, acc[ct], 0, 0, 0);
      }
    }
#pragma unroll
    for (int ct = 0; ct < 4; ++ct) {
      int colg = (half << 8) + (((cg << 2) + ct) << 4) + lrow;
      ushort4 o;
      o.x = f2b(gelu_exact(acc[ct][0]));
      o.y = f2b(gelu_exact(acc[ct][1]));
      o.z = f2b(gelu_exact(acc[ct][2]));
      o.w = f2b(gelu_exact(acc[ct][3]));
      *(ushort4*)(yloc + (size_t)h * (B_SZ * L_SZ) + (size_t)colg * 64 + (rt << 4) + rsub) = o;
    }
  }
}

// ---------------- post: yt copy + GLU + LN (yt XOR-swizzled) ----------------
__launch_bounds__(1024, 4)
__global__ void k_layer2(float* __restrict__ hbuf, const unsigned short* __restrict__ yloc,
                         const unsigned short* __restrict__ wbf,
                         const float* __restrict__ b_out,
                         const float* __restrict__ ln_g, const float* __restrict__ ln_b,
                         float* __restrict__ pooledPart, int last) {
  __shared__ __align__(16) unsigned short yt[TC * YROW];
  __shared__ float part[TC][16][2];
  __shared__ float stats[TC][2];
  int tid = threadIdx.x;
  int b = blockIdx.x >> 5;
  int c = blockIdx.x & 31;
  int l0 = c << 6;

  // ---- fill: yloc (already gelu'd) -> yt transpose copy ----
  {
    int h = tid >> 2, q = tid & 3;
    const unsigned short* yp2 = yloc + (size_t)h * (B_SZ * L_SZ) + b * L_SZ + l0 + (q << 4);
#pragma unroll
    for (int jj = 0; jj < 16; jj += 4) {
      ushort4 yv = *(const ushort4*)(yp2 + jj);
      int jb = (q << 4) + jj;
      yt[yswz(jb + 0, h)] = yv.x;
      yt[yswz(jb + 1, h)] = yv.y;
      yt[yswz(jb + 2, h)] = yv.z;
      yt[yswz(jb + 3, h)] = yv.w;
    }
  }
  __syncthreads();
  // ---- GLU: 1x1 conv via MFMA; z -> yt ----
  {
    int w = tid >> 6, lane = tid & 63;
    int lrow = lane & 15, lk8 = (lane >> 4) << 3;
    f32x4 accA[4], accG[4];
    f32x4 zed = {0.f, 0.f, 0.f, 0.f};
#pragma unroll
    for (int jt = 0; jt < 4; ++jt) { accA[jt] = zed; accG[jt] = zed; }
    const unsigned short* wA = wbf + ((w << 4) + lrow) * H_SZ;
    const unsigned short* wG = wA + 256 * H_SZ;
#pragma unroll
    for (int k0 = 0; k0 < H_SZ; k0 += 32) {
      bf16x8 a0 = *(const bf16x8*)(wA + k0 + lk8);
      bf16x8 a1 = *(const bf16x8*)(wG + k0 + lk8);
#pragma unroll
      for (int jt = 0; jt < 4; ++jt) {
        bf16x8 bb = *(const bf16x8*)&yt[yswz((jt << 4) + lrow, k0 + lk8)];
        accA[jt] = __builtin_amdgcn_mfma_f32_16x16x32_bf16(a0, bb, accA[jt], 0, 0, 0);
        accG[jt] = __builtin_amdgcn_mfma_f32_16x16x32_bf16(a1, bb, accG[jt], 0, 0, 0);
      }
    }
    __syncthreads();  // all y reads done before overwrite with z
    int rbase = (lane >> 4) << 2;
    float bA[4], bG[4];
#pragma unroll
    for (int r = 0; r < 4; ++r) {
      bA[r] = b_out[(w << 4) + rbase + r];
      bG[r] = b_out[256 + (w << 4) + rbase + r];
    }
#pragma unroll
    for (int jt = 0; jt < 4; ++jt) {
      ushort4 o;
      float a0 = accA[jt][0] + bA[0], g0 = accG[jt][0] + bG[0];
      float a1 = accA[jt][1] + bA[1], g1 = accG[jt][1] + bG[1];
      float a2 = accA[jt][2] + bA[2], g2 = accG[jt][2] + bG[2];
      float a3 = accA[jt][3] + bA[3], g3 = accG[jt][3] + bG[3];
      o.x = f2b(a0 / (1.f + expf(-g0)));
      o.y = f2b(a1 / (1.f + expf(-g1)));
      o.z = f2b(a2 / (1.f + expf(-g2)));
      o.w = f2b(a3 / (1.f + expf(-g3)));
      *(ushort4*)&yt[yswz((jt << 4) + lrow, (w << 4) + rbase)] = o;
    }
  }
  __syncthreads();
  // ---- LN stats; v = z + residual ----
  int j = tid & 63, hg = tid >> 6;
  float vreg[16];
  {
    const float* xc = hbuf + (b * H_SZ + (hg << 4)) * L_SZ + l0 + j;
    float s = 0.f, sq = 0.f;
    ushort4 za = *(const ushort4*)&yt[yswz(j, (hg << 4) + 0)];
    ushort4 zb = *(const ushort4*)&yt[yswz(j, (hg << 4) + 4)];
    ushort4 zc = *(const ushort4*)&yt[yswz(j, (hg << 4) + 8)];
    ushort4 zd = *(const ushort4*)&yt[yswz(j, (hg << 4) + 12)];
    unsigned short zz[16] = {za.x, za.y, za.z, za.w, zb.x, zb.y, zb.z, zb.w,
                             zc.x, zc.y, zc.z, zc.w, zd.x, zd.y, zd.z, zd.w};
#pragma unroll
    for (int k = 0; k < 16; ++k) {
      float v = b2f(zz[k]) + xc[(size_t)k * L_SZ];
      vreg[k] = v;
      s += v; sq = fmaf(v, v, sq);
    }
    part[j][hg][0] = s; part[j][hg][1] = sq;
  }
  __syncthreads();
  if (tid < TC) {
    float s = 0.f, sq = 0.f;
#pragma unroll
    for (int g = 0; g < 16; ++g) { s += part[tid][g][0]; sq += part[tid][g][1]; }
    float mu = s * (1.f / 256.f);
    float var = sq * (1.f / 256.f) - mu * mu;
    stats[tid][0] = mu;
    stats[tid][1] = rsqrtf(var + 1e-5f);
  }
  __syncthreads();
  {
    float mu = stats[j][0], rs = stats[j][1];
    if (!last) {
      float* xo = hbuf + (b * H_SZ + (hg << 4)) * L_SZ + l0 + j;
#pragma unroll
      for (int k = 0; k < 16; ++k) {
        int hh = (hg << 4) + k;
        xo[(size_t)k * L_SZ] = (vreg[k] - mu) * rs * ln_g[hh] + ln_b[hh];
      }
    } else {
#pragma unroll
      for (int k = 0; k < 16; ++k) {
        int hh = (hg << 4) + k;
        yt[yswz(j, hh)] = f2b((vreg[k] - mu) * rs * ln_g[hh] + ln_b[hh]);
      }
      __syncthreads();
      if (tid < H_SZ) {
        float s = 0.f;
        for (int jj = 0; jj < TC; ++jj) s += b2f(yt[yswz(jj, tid)]);
        pooledPart[(((b << 5) + c) << 8) + tid] = s;
      }
    }
  }
}

// ---------------- pool: reduce 32 chunk-partials per (b,h) ----------------
__global__ void k_pool(const float* __restrict__ pooledPart, float* __restrict__ P) {
  int b = blockIdx.x, hh = threadIdx.x;
  float s = 0.f;
#pragma unroll
  for (int cpart = 0; cpart < 32; ++cpart)
    s += pooledPart[(((b << 5) + cpart) << 8) + hh];
  P[(b << 8) + hh] = s * (1.f / 2048.f);
}

// ---------------- decoder MLP: one block per batch row ----------------
__global__ void k_dec(const float* __restrict__ P,
                      const float* __restrict__ w1, const float* __restrict__ b1,
                      const float* __restrict__ w2, const float* __restrict__ b2,
                      const float* __restrict__ w3, const float* __restrict__ b3,
                      float* __restrict__ out) {
  __shared__ float Pr[256];
  __shared__ float O1[128];
  __shared__ float O2[64];
  int b = blockIdx.x, tid = threadIdx.x;
  Pr[tid] = P[(b << 8) + tid];
  __syncthreads();
  if (tid < 128) {
    float acc = b1[tid];
    for (int d = 0; d < 256; ++d) acc = fmaf(Pr[d], w1[(d << 7) + tid], acc);
    O1[tid] = fmaxf(acc, 0.f);
  }
  __syncthreads();
  if (tid < 64) {
    float acc = b2[tid];
    for (int d = 0; d < 128; ++d) acc = fmaf(O1[d], w2[(d << 6) + tid], acc);
    O2[tid] = fmaxf(acc, 0.f);
  }
  __syncthreads();
  if (tid < 32) {
    float acc = b3[tid];
    for (int d = 0; d < 64; ++d) acc = fmaf(O2[d], w3[(d << 5) + tid], acc);
    out[(b << 5) + tid] = acc;
  }
}

extern "C" void kernel_launch(void* const* d_in, const int* in_sizes, int n_in,
                              void* d_out, int out_size, void* d_ws, size_t ws_size,
                              hipStream_t stream) {
  const float* x          = (const float*)d_in[0];
  const float* enc_w      = (const float*)d_in[1];
  const float* enc_b      = (const float*)d_in[2];
  const float* log_dt     = (const float*)d_in[3];
  const float* C_re       = (const float*)d_in[4];
  const float* C_im       = (const float*)d_in[5];
  const float* log_A_real = (const float*)d_in[6];
  const float* A_imag     = (const float*)d_in[7];
  const float* D_skip     = (const float*)d_in[8];
  const float* w_out      = (const float*)d_in[9];
  const float* b_out      = (const float*)d_in[10];
  const float* ln_g       = (const float*)d_in[11];
  const float* ln_b       = (const float*)d_in[12];
  const float* dw1        = (const float*)d_in[13];
  const float* db1        = (const float*)d_in[14];
  const float* dw2        = (const float*)d_in[15];
  const float* db2        = (const float*)d_in[16];
  const float* dw3        = (const float*)d_in[17];
  const float* db3        = (const float*)d_in[18];

  char* ws = (char*)d_ws;
  float* hbuf = (float*)ws;                                  // 33,554,432 B
  unsigned short* yloc = (unsigned short*)(ws + 33554432);   // 16,777,216 B (bf16)
  unsigned short* wbf = (unsigned short*)(ws + 50331648);    //  1,048,576 B
  float* par = (float*)(ws + 51380224);                      //  1,048,576 B
  float* pooledPart = (float*)(ws + 52428800);               //    524,288 B
  float* P = (float*)(ws + 52953088);                        //     16,384 B

  k_encoder<<<512, 512, 0, stream>>>(x, enc_w, enc_b, hbuf);
  k_cvtw<<<2048, 256, 0, stream>>>(w_out, wbf, NL * 512 * H_SZ);
  k_params<<<128, 256, 0, stream>>>(log_dt, log_A_real, A_imag, C_re, C_im, par);
  const size_t PAR_STRIDE = (size_t)H_SZ * NH * 8;
  for (int i = 0; i < NL; ++i) {
    const float* pari = par + i * PAR_STRIDE;
    k_ssm<<<256, 1024, 0, stream>>>(hbuf, pari, D_skip + i * H_SZ, yloc);
    k_layer2<<<512, 1024, 0, stream>>>(hbuf, yloc,
                                       wbf + i * 512 * H_SZ, b_out + i * 512,
                                       ln_g + i * H_SZ, ln_b + i * H_SZ,
                                       pooledPart, (i == NL - 1) ? 1 : 0);
  }
  k_pool<<<16, 256, 0, stream>>>(pooledPart, P);
  k_dec<<<16, 256, 0, stream>>>(P, dw1, db1, dw2, db2, dw3, db3, (float*)d_out);
}